// Round 3
// baseline (1897.399 us; speedup 1.0000x reference)
//
#include <hip/hip_runtime.h>
#include <hip/hip_bf16.h>

// ============================================================================
// HybridViT forward. Round 9: conv-MFMA staging pipeline (k2/k4 latency fix).
//  - k2_conv2 was the top dispatch (113.7us x4, MfmaUtil 11%, VALUBusy 11%,
//    occupancy 14% -> latency/barrier-bound; compute floor ~16us).
//  - pool1 layout changed to [n][4][103][103][8] so k2 staging is one int4
//    per item (was 2 scattered uint2). k1b writes same values, new indices.
//  - k2/k4: T14 async-STAGE pipeline — issue ky+1 staging loads into regs
//    (static-indexed pre[]) before compute of ky; LDS write after barrier.
//    Global latency hides under the MFMA phase.
// Rest unchanged from round 8.
// ============================================================================

typedef __hip_bfloat16 bf16;
typedef __attribute__((ext_vector_type(8))) short short8;
typedef __attribute__((ext_vector_type(4))) float floatx4;

#define CHUNK 64

union U8 { int4 v; unsigned short s[8]; };
__device__ inline void umax8(U8& a, const U8& b){
  #pragma unroll
  for (int j = 0; j < 8; j++) a.s[j] = (a.s[j] > b.s[j]) ? a.s[j] : b.s[j];
}
union U4 { uint2 v; unsigned short s[4]; };
__device__ inline void umax4(U4& a, const U4& b){
  #pragma unroll
  for (int j = 0; j < 4; j++) a.s[j] = (a.s[j] > b.s[j]) ? a.s[j] : b.s[j];
}

// ---------- weight prep: conv2_w fp32 [64][32][7][7] -> bf16 [ky*7+kx][64][32]
__global__ __launch_bounds__(256) void prep_w2(const float* __restrict__ w,
                                               bf16* __restrict__ w2b)
{
  int idx = blockIdx.x*256 + threadIdx.x;     // 49*64*32 = 100352
  if (idx >= 49*64*32) return;
  int ic = idx & 31; int t = idx >> 5; int oc = t & 63; int kk = t >> 6;
  int ky = kk/7, kx = kk - ky*7;
  w2b[idx] = __float2bfloat16(w[((oc*32+ic)*7+ky)*7+kx]);
}

// ---------- weight prep: conv3_w fp32 [64][64][7][7] -> bf16 [ky][kc][kx][64][32]
__global__ __launch_bounds__(256) void prep_w3(const float* __restrict__ w,
                                               bf16* __restrict__ w3b)
{
  int idx = blockIdx.x*256 + threadIdx.x;     // 49*2*64*32 = 200704
  if (idx >= 49*2*64*32) return;
  int ic_l = idx & 31; int t = idx >> 5; int oc = t & 63; int t2 = t >> 6;
  int kx = t2 % 7; int t3 = t2 / 7; int kc = t3 & 1; int ky = t3 >> 1;
  w3b[idx] = __float2bfloat16(w[((oc*64 + kc*32 + ic_l)*7+ky)*7+kx]);
}

// ---------- transformer weight pack: fp32 [L][K][N] -> bf16 [L][K/8][N][8]
__global__ __launch_bounds__(256) void prep_pack(
    const float* __restrict__ src, bf16* __restrict__ dst,
    int K8, int N, int total)
{
  int idx = blockIdx.x*256 + threadIdx.x;
  if (idx >= total) return;
  int n = idx % N; int t = idx / N; int k8 = t % K8; int l = t / K8;
  const float* s = src + ((size_t)l*K8*8 + (size_t)k8*8)*N + n;
  union { bf16 h[8]; int4 v; } pk;
  #pragma unroll
  for (int j = 0; j < 8; j++) pk.h[j] = __float2bfloat16(s[(size_t)j*N]);
  *(int4*)(dst + (((size_t)l*K8 + k8)*N + n)*8) = pk.v;
}

// ---------- flat_w pack: fp32 [16384][512] -> hi/lo bf16 [2048][512][8]
__global__ __launch_bounds__(256) void prep_pack_flat(
    const float* __restrict__ src, bf16* __restrict__ hi, bf16* __restrict__ lo)
{
  int idx = blockIdx.x*256 + threadIdx.x;   // 2048*512 = 1048576
  if (idx >= 2048*512) return;
  int n = idx & 511; int k8 = idx >> 9;
  const float* s = src + (size_t)k8*8*512 + n;
  union { bf16 h[8]; int4 v; } ph, pl;
  #pragma unroll
  for (int j = 0; j < 8; j++){
    float w = s[(size_t)j*512];
    bf16 h = __float2bfloat16(w);
    ph.h[j] = h;
    pl.h[j] = __float2bfloat16(w - __bfloat162float(h));
  }
  size_t o = (size_t)idx*8;
  *(int4*)(hi + o) = ph.v;
  *(int4*)(lo + o) = pl.v;
}

// ---------- K1a: patchify + conv1(1->32,7x7,s2) + ReLU
//   -> cbuf [SUB][8grp][107][107][4ch] bf16
__global__ __launch_bounds__(256) void k1a_conv1(
    const float* __restrict__ img, const float* __restrict__ w,
    bf16* __restrict__ cbuf, int n_base)
{
  __shared__ __align__(16) float in_s[15*224];  // input rows 2*r0 .. 2*r0+14
  __shared__ float w_s[32*58];                  // stride 58: 2-way-conflict reads
  const int band = blockIdx.x;                  // 0..21
  const int n = blockIdx.y;                     // 0..SUB-1 (cbuf-local)
  const int ng = n_base + n;                    // global patch for img
  const int r0 = band*5;                        // conv rows r0..r0+4
  const int ir0 = 2*r0;
  const int b = ng>>4, gh = (ng>>2)&3, gw = ng&3;
  const float* ibase = img + b*774400 + (gh*220)*880 + gw*220;

  for (int idx = threadIdx.x; idx < 15*56; idx += 256){
    int r = idx/56, cq = idx - r*56; int c = cq*4;
    int gr = ir0 + r;
    float4 v = (c < 220 && gr < 220) ? *(const float4*)(ibase + gr*880 + c)
                                     : make_float4(0.f,0.f,0.f,0.f);
    *(float4*)&in_s[r*224 + c] = v;
  }
  for (int idx = threadIdx.x; idx < 32*56; idx += 256){
    int oc = idx/56, k = idx - oc*56; int ky = k>>3, kx = k&7;
    w_s[oc*58 + k] = (kx < 7) ? w[oc*49 + ky*7 + kx] : 0.f;
  }
  __syncthreads();

  const int grp = threadIdx.x & 7;
  const int sp  = threadIdx.x >> 3;   // 0..31 col-group (cols 4sp..4sp+3)
  const int cgc = (sp < 26) ? sp : 26;
  const int nrows = (107 - r0 < 5) ? (107 - r0) : 5;

  float acc[5][4][4] = {};            // [row-item][oc][col]
  #pragma unroll 1
  for (int ky = 0; ky < 7; ky++){
    float wk[4][7];
    #pragma unroll
    for (int oc = 0; oc < 4; oc++)
      #pragma unroll
      for (int kx = 0; kx < 7; kx++)
        wk[oc][kx] = w_s[(grp*4+oc)*58 + ky*8 + kx];
    #pragma unroll
    for (int i = 0; i < 5; i++){
      if (i < nrows){
        const float* ip = &in_s[(2*i+ky)*224 + 8*cgc];
        float iv[13];
        *(float4*)&iv[0] = *(const float4*)ip;
        *(float4*)&iv[4] = *(const float4*)(ip+4);
        *(float4*)&iv[8] = *(const float4*)(ip+8);
        iv[12] = ip[12];
        #pragma unroll
        for (int oc = 0; oc < 4; oc++)
          #pragma unroll
          for (int kx = 0; kx < 7; kx++)
            #pragma unroll
            for (int j = 0; j < 4; j++)
              acc[i][oc][j] += iv[2*j+kx]*wk[oc][kx];
      }
    }
  }

  #pragma unroll
  for (int i = 0; i < 5; i++){
    if (i < nrows){
      int y = r0 + i;
      #pragma unroll
      for (int j = 0; j < 4; j++){
        int col = 4*sp + j;
        if (col < 107){
          union { unsigned short s[4]; uint2 u; } pk;
          #pragma unroll
          for (int oc = 0; oc < 4; oc++){
            bf16 hv = __float2bfloat16(fmaxf(acc[i][oc][j], 0.f));
            pk.s[oc] = *(unsigned short*)&hv;
          }
          *(uint2*)(cbuf + (((size_t)(n*8+grp)*107 + y)*107 + col)*4) = pk.u;
        }
      }
    }
  }
}

// ---------- K1b: separable 7x7 s1 p1 max-pool. cbuf -> pool1
//   NEW layout: [n][q=4][103][103][8ch]; grp g -> plane q=g>>1, half h=g&1.
__global__ __launch_bounds__(256) void k1b_pool1(
    const bf16* __restrict__ cbuf, bf16* __restrict__ pool1, int n_pool_base)
{
  __shared__ uint2 in4[19*107];   // conv rows p0-1..p0+17 (clamped)
  __shared__ uint2 ht4[19*103];   // after horizontal 7-max
  const int s = blockIdx.x, g = blockIdx.y, n = blockIdx.z;
  const int p0 = s*13;
  const int PR = (103 - p0 < 13) ? (103 - p0) : 13;
  const int NR = PR + 6;
  const uint2* src = (const uint2*)cbuf + (size_t)(n*8+g)*107*107;

  for (int t = threadIdx.x; t < NR*107; t += 256){
    int r = t/107, c = t - r*107;
    int gr = p0 - 1 + r;
    gr = (gr < 0) ? 0 : ((gr > 106) ? 106 : gr);
    in4[t] = src[gr*107 + c];
  }
  __syncthreads();
  for (int t = threadIdx.x; t < NR*103; t += 256){
    int r = t/103, c = t - r*103;
    U4 m; m.v = in4[r*107 + ((c > 0) ? c-1 : 0)];
    #pragma unroll
    for (int d = 0; d < 6; d++){
      U4 v; v.v = in4[r*107 + ((c+d < 106) ? c+d : 106)];
      umax4(m, v);
    }
    ht4[r*103 + c] = m.v;
  }
  __syncthreads();
  // dst uint2 index = (plane_pix)*2 + h, plane = ((n)*4 + q)*10609
  uint2* dst = (uint2*)pool1;
  const size_t plane = ((size_t)(n_pool_base + n)*4 + (g>>1))*10609;
  const int h = g & 1;
  for (int t = threadIdx.x; t < PR*103; t += 256){
    int pr = t/103, c = t - pr*103;
    U4 m; m.v = ht4[pr*103 + c];
    #pragma unroll
    for (int d = 1; d < 7; d++){
      U4 v; v.v = ht4[(pr+d)*103 + c];
      umax4(m, v);
    }
    dst[(plane + (size_t)(p0+pr)*103 + c)*2 + h] = m.v;
  }
}

// ---------- K2: conv2 MFMA implicit GEMM, pipelined staging.
// pool1 [CHUNK][4][103][103][8] -> conv2out NHWC [CHUNK,49,49,64]
__global__ __launch_bounds__(256) void k2_conv2(
    const bf16* __restrict__ pool1,
    const bf16* __restrict__ w2b,     // [49][64][32]
    bf16* __restrict__ conv2out)
{
  __shared__ __align__(16) bf16 in_s[7*2*52*40];   // 58240 B
  const int n = blockIdx.y, pb = blockIdx.x;       // pb 0..9
  const int wv = threadIdx.x >> 6, lane = threadIdx.x & 63;
  const int li = lane & 15, lg = lane >> 4;
  const int p0 = pb*256;
  const int y0 = p0/49;

  int pyv[4], pxv[4], poff[4]; bool pmask[4];
  #pragma unroll
  for (int t = 0; t < 4; t++){
    int p = p0 + wv*64 + t*16 + li;
    pmask[t] = (p <= 2400);
    int pc = min(p, 2400);
    int yy = pc/49, xx = pc - yy*49;
    pyv[t] = yy; pxv[t] = xx;
    poff[t] = ((yy - y0)*2*52 + xx)*40;
  }
  floatx4 acc[4][4];
  #pragma unroll
  for (int a = 0; a < 4; a++)
    #pragma unroll
    for (int t = 0; t < 4; t++) acc[a][t] = (floatx4){0.f,0.f,0.f,0.f};

  const unsigned short* pbase = (const unsigned short*)pool1;
  int4 pre[12];

  auto stage_load = [&](int ky){
    #pragma unroll
    for (int i = 0; i < 12; i++){
      int idx = threadIdx.x + i*256;
      if (idx < 7*103*4){
        int q = idx & 3; int t2 = idx >> 2; int c = t2 % 103; int r = t2/103;
        int gr = min(2*(y0+r)+ky, 102);
        pre[i] = *(const int4*)(pbase + (((size_t)n*4 + q)*10609 + (size_t)gr*103 + c)*8);
      }
    }
  };
  auto stage_write = [&](){
    #pragma unroll
    for (int i = 0; i < 12; i++){
      int idx = threadIdx.x + i*256;
      if (idx < 7*103*4){
        int q = idx & 3; int t2 = idx >> 2; int c = t2 % 103; int r = t2/103;
        *(int4*)&in_s[((r*2 + (c&1))*52 + (c>>1))*40 + q*8] = pre[i];
      }
    }
  };

  stage_load(0);
  for (int ky = 0; ky < 7; ky++){
    __syncthreads();               // previous compute done reading in_s
    stage_write();                 // regs -> LDS (waits vmcnt for pre)
    if (ky < 6) stage_load(ky+1);  // issue next loads; hide under compute
    __syncthreads();               // in_s ready
    #pragma unroll
    for (int kx = 0; kx < 7; kx++){
      short8 a[4];
      const bf16* wp = w2b + (ky*7+kx)*64*32;
      #pragma unroll
      for (int ot = 0; ot < 4; ot++)
        a[ot] = *(const short8*)(wp + (ot*16 + li)*32 + lg*8);
      int koff = ((kx&1)*52 + (kx>>1))*40 + lg*8;
      #pragma unroll
      for (int t = 0; t < 4; t++){
        short8 bfr = *(const short8*)(&in_s[poff[t] + koff]);
        #pragma unroll
        for (int ot = 0; ot < 4; ot++)
          acc[ot][t] = __builtin_amdgcn_mfma_f32_16x16x32_bf16(a[ot], bfr, acc[ot][t], 0, 0, 0);
      }
    }
  }
  #pragma unroll
  for (int t = 0; t < 4; t++){
    if (!pmask[t]) continue;
    bf16* dst = conv2out + (((long)n*49 + pyv[t])*49 + pxv[t])*64 + lg*4;
    #pragma unroll
    for (int ot = 0; ot < 4; ot++){
      union { bf16 h[4]; uint2 u; } pk;
      #pragma unroll
      for (int v = 0; v < 4; v++)
        pk.h[v] = __float2bfloat16(fmaxf(acc[ot][t][v], 0.f));
      *(uint2*)(dst + ot*16) = pk.u;
    }
  }
}

// ---------- K3a: horizontal 7-max: conv2out [CHUNK,49,49,64] -> tmp [CHUNK,49,45,64]
__global__ __launch_bounds__(256) void k3a_hmax(
    const bf16* __restrict__ cin, bf16* __restrict__ tmp)
{
  int idx = blockIdx.x*256 + threadIdx.x;
  int cg = idx & 7; int t = idx >> 3; int x = t % 45; int t2 = t / 45;
  int y = t2 % 49; int n = t2 / 49;
  const int4* row = (const int4*)(cin + ((long)(n*49 + y)*49)*64) + cg;
  U8 m; m.v = make_int4(0,0,0,0);
  int lo = max(x-1, 0), hi = min(x+5, 48);
  for (int cx = lo; cx <= hi; cx++){ U8 v; v.v = row[cx*8]; umax8(m, v); }
  *((int4*)(tmp + ((long)(n*49 + y)*45 + x)*64) + cg) = m.v;
}

// ---------- K3b: vertical 7-max: tmp -> pool2 [256,45,45,64] at n_base
__global__ __launch_bounds__(256) void k3b_vmax(
    const bf16* __restrict__ tmp, bf16* __restrict__ pout, int n_base)
{
  int idx = blockIdx.x*256 + threadIdx.x;
  int cg = idx & 7; int t = idx >> 3; int x = t % 45; int t2 = t / 45;
  int y = t2 % 45; int n = t2 / 45;
  U8 m; m.v = make_int4(0,0,0,0);
  int lo = max(y-1, 0), hi = min(y+5, 48);
  for (int cy = lo; cy <= hi; cy++){
    U8 v; v.v = *((const int4*)(tmp + ((long)(n*49 + cy)*45 + x)*64) + cg);
    umax8(m, v);
  }
  *((int4*)(pout + (long)(n_base+n)*129600 + (y*45 + x)*64) + cg) = m.v;
}

// ---------- K4: conv3 MFMA implicit GEMM, pipelined staging.
// pool2 NHWC -> conv3out NHWC [256,20,20,64]
__global__ __launch_bounds__(256) void k4_conv3(
    const bf16* __restrict__ pool2,
    const bf16* __restrict__ w3b,     // [ky][kc][kx][64][32]
    bf16* __restrict__ conv3out)
{
  __shared__ __align__(16) bf16 in_s[10*2*24*40];  // 38400 B
  const int n = blockIdx.y, pb = blockIdx.x;       // pb 0..1
  const int wv = threadIdx.x >> 6, lane = threadIdx.x & 63;
  const int li = lane & 15, lg = lane >> 4;
  const int y0 = pb*10;

  int pyv[4], pxv[4], poff[4]; bool pmask[4];
  #pragma unroll
  for (int t = 0; t < 4; t++){
    int pl = wv*64 + t*16 + li;
    pmask[t] = (pl < 200);
    int p = pb*200 + min(pl, 199);
    int yy = p/20, xx = p - yy*20;
    pyv[t] = yy; pxv[t] = xx;
    poff[t] = ((yy - y0)*2*24 + xx)*40;
  }
  floatx4 acc[4][4];
  #pragma unroll
  for (int a = 0; a < 4; a++)
    #pragma unroll
    for (int t = 0; t < 4; t++) acc[a][t] = (floatx4){0.f,0.f,0.f,0.f};

  int4 pre[8];
  auto stage_load = [&](int ph){
    int ky = ph >> 1, kc = ph & 1;
    #pragma unroll
    for (int i = 0; i < 8; i++){
      int idx = threadIdx.x + i*256;
      if (idx < 10*45*4){
        int q = idx & 3; int t2 = idx >> 2; int c = t2 % 45; int r = t2/45;
        int gr = 2*(y0+r)+ky;
        pre[i] = *(const int4*)(pool2 + (((long)n*45 + gr)*45 + c)*64 + kc*32 + q*8);
      }
    }
  };
  auto stage_write = [&](){
    #pragma unroll
    for (int i = 0; i < 8; i++){
      int idx = threadIdx.x + i*256;
      if (idx < 10*45*4){
        int q = idx & 3; int t2 = idx >> 2; int c = t2 % 45; int r = t2/45;
        *(int4*)&in_s[((r*2 + (c&1))*24 + (c>>1))*40 + q*8] = pre[i];
      }
    }
  };

  stage_load(0);
  for (int ph = 0; ph < 14; ph++){
    __syncthreads();
    stage_write();
    if (ph < 13) stage_load(ph+1);
    __syncthreads();
    #pragma unroll
    for (int kx = 0; kx < 7; kx++){
      short8 a[4];
      const bf16* wp = w3b + (ph*7 + kx)*64*32;
      #pragma unroll
      for (int ot = 0; ot < 4; ot++)
        a[ot] = *(const short8*)(wp + (ot*16 + li)*32 + lg*8);
      int koff = ((kx&1)*24 + (kx>>1))*40 + lg*8;
      #pragma unroll
      for (int t = 0; t < 4; t++){
        short8 bfr = *(const short8*)(&in_s[poff[t] + koff]);
        #pragma unroll
        for (int ot = 0; ot < 4; ot++)
          acc[ot][t] = __builtin_amdgcn_mfma_f32_16x16x32_bf16(a[ot], bfr, acc[ot][t], 0, 0, 0);
      }
    }
  }
  #pragma unroll
  for (int t = 0; t < 4; t++){
    if (!pmask[t]) continue;
    bf16* dst = conv3out + (((long)n*20 + pyv[t])*20 + pxv[t])*64 + lg*4;
    #pragma unroll
    for (int ot = 0; ot < 4; ot++){
      union { bf16 h[4]; uint2 u; } pk;
      #pragma unroll
      for (int v = 0; v < 4; v++)
        pk.h[v] = __float2bfloat16(fmaxf(acc[ot][t][v], 0.f));
      *(uint2*)(dst + ot*16) = pk.u;
    }
  }
}

// ---------- K5: in-LDS separable pool3. conv3out [256,20,20,64] -> feat [256,16384]
__global__ __launch_bounds__(256) void k5_pool3(
    const bf16* __restrict__ cin, bf16* __restrict__ feat)
{
  __shared__ int4 in_p[3200];
  __shared__ int4 ht[2560];
  const int n = blockIdx.x;
  const int4* src = (const int4*)(cin + (long)n*25600);
  for (int i = threadIdx.x; i < 3200; i += 256) in_p[i] = src[i];
  __syncthreads();
  for (int i = threadIdx.x; i < 2560; i += 256){
    int cg = i & 7; int t = i >> 3; int x = t & 15; int y = t >> 4;
    U8 m; m.v = make_int4(0,0,0,0);
    int lo = max(x-1, 0), hi = min(x+5, 19);
    for (int cx = lo; cx <= hi; cx++){ U8 v; v.v = in_p[(y*20+cx)*8 + cg]; umax8(m, v); }
    ht[(y*16+x)*8 + cg] = m.v;
  }
  __syncthreads();
  unsigned short* dst = (unsigned short*)(feat + (long)n*16384);
  for (int i = threadIdx.x; i < 2048; i += 256){
    int px = i & 15; int py = (i >> 4) & 15; int cg = i >> 8;
    U8 m; m.v = make_int4(0,0,0,0);
    int lo = max(py-1, 0), hi = min(py+5, 19);
    for (int cy = lo; cy <= hi; cy++){ U8 v; v.v = ht[(cy*16+px)*8 + cg]; umax8(m, v); }
    #pragma unroll
    for (int j = 0; j < 8; j++)
      dst[(cg*8+j)*256 + py*16 + px] = m.s[j];
  }
}

// ---------- K6a: init x[272,512]
__global__ __launch_bounds__(256) void k6_init_x(
    const float* __restrict__ cls, const float* __restrict__ pos,
    const float* __restrict__ flat_b, float* __restrict__ x)
{
  int idx = blockIdx.x*256 + threadIdx.x;
  int d = idx & 511; int row = idx >> 9;
  int tt = row % 17;
  x[idx] = (tt == 0) ? (cls[d] + pos[d]) : (flat_b[d] + pos[tt*512 + d]);
}

// ---------- K6b: feat @ flat_w via MFMA (hi+lo bf16 W). atomicAdd into x.
__global__ __launch_bounds__(256) void k6_flat_mfma(
    const bf16* __restrict__ feat, const bf16* __restrict__ Whi,
    const bf16* __restrict__ Wlo, float* __restrict__ x)
{
  const int wv = threadIdx.x >> 6, lane = threadIdx.x & 63;
  const int li = lane & 15, lg = lane >> 4;
  const int m0 = blockIdx.x*64 + wv*16;     // wave's 16-row tile
  const int nb = blockIdx.y*64;             // block's 64 cols
  const int kb = blockIdx.z*2048;           // k-range
  floatx4 acc[4];
  #pragma unroll
  for (int t = 0; t < 4; t++) acc[t] = (floatx4){0.f,0.f,0.f,0.f};

  const bf16* arow = feat + (size_t)(m0+li)*16384 + kb + lg*8;
  for (int k0 = 0; k0 < 2048; k0 += 32){
    short8 a = *(const short8*)(arow + k0);
    size_t wo = ((size_t)((kb + k0) >> 3) + lg)*512 + nb + li;  // in 8-elt units
    const bf16* wh = Whi + wo*8;
    const bf16* wl = Wlo + wo*8;
    #pragma unroll
    for (int t = 0; t < 4; t++){
      short8 bh = *(const short8*)(wh + t*128);
      acc[t] = __builtin_amdgcn_mfma_f32_16x16x32_bf16(a, bh, acc[t], 0, 0, 0);
    }
    #pragma unroll
    for (int t = 0; t < 4; t++){
      short8 bl = *(const short8*)(wl + t*128);
      acc[t] = __builtin_amdgcn_mfma_f32_16x16x32_bf16(a, bl, acc[t], 0, 0, 0);
    }
  }
  #pragma unroll
  for (int t = 0; t < 4; t++){
    int col = nb + t*16 + li;
    #pragma unroll
    for (int v = 0; v < 4; v++){
      int m = m0 + lg*4 + v;
      int row = (m>>4)*17 + 1 + (m&15);
      atomicAdd(&x[row*512 + col], acc[t][v]);
    }
  }
}

// ---------- LayerNorm over 512, fp32 out (head path)
__global__ __launch_bounds__(256) void ln_kernel(
    const float* __restrict__ in, const float* __restrict__ g,
    const float* __restrict__ b, float* __restrict__ out,
    int in_stride, int out_stride)
{
  int row = blockIdx.x;
  const float* p = in + (long)row*in_stride;
  float v0 = p[threadIdx.x], v1 = p[threadIdx.x+256];
  __shared__ float red[4]; __shared__ float stat;
  float s = v0+v1;
  #pragma unroll
  for (int o = 32; o >= 1; o >>= 1) s += __shfl_down(s, o);
  int lane = threadIdx.x & 63, wv = threadIdx.x >> 6;
  if (lane == 0) red[wv] = s;
  __syncthreads();
  if (threadIdx.x == 0) stat = (red[0]+red[1]+red[2]+red[3])*(1.0f/512.0f);
  __syncthreads();
  float m = stat;
  float d0 = v0-m, d1 = v1-m;
  float q = d0*d0 + d1*d1;
  #pragma unroll
  for (int o = 32; o >= 1; o >>= 1) q += __shfl_down(q, o);
  __syncthreads();
  if (lane == 0) red[wv] = q;
  __syncthreads();
  if (threadIdx.x == 0) stat = rsqrtf((red[0]+red[1]+red[2]+red[3])*(1.0f/512.0f) + 1e-5f);
  __syncthreads();
  float rstd = stat;
  out[(long)row*out_stride + threadIdx.x]     = d0*rstd*g[threadIdx.x]     + b[threadIdx.x];
  out[(long)row*out_stride + threadIdx.x+256] = d1*rstd*g[threadIdx.x+256] + b[threadIdx.x+256];
}

// ---------- LayerNorm over 512, bf16 out (MFMA tail activations)
__global__ __launch_bounds__(256) void ln_bf16(
    const float* __restrict__ in, const float* __restrict__ g,
    const float* __restrict__ b, bf16* __restrict__ out)
{
  int row = blockIdx.x;
  const float* p = in + (long)row*512;
  float v0 = p[threadIdx.x], v1 = p[threadIdx.x+256];
  __shared__ float red[4]; __shared__ float stat;
  float s = v0+v1;
  #pragma unroll
  for (int o = 32; o >= 1; o >>= 1) s += __shfl_down(s, o);
  int lane = threadIdx.x & 63, wv = threadIdx.x >> 6;
  if (lane == 0) red[wv] = s;
  __syncthreads();
  if (threadIdx.x == 0) stat = (red[0]+red[1]+red[2]+red[3])*(1.0f/512.0f);
  __syncthreads();
  float m = stat;
  float d0 = v0-m, d1 = v1-m;
  float q = d0*d0 + d1*d1;
  #pragma unroll
  for (int o = 32; o >= 1; o >>= 1) q += __shfl_down(q, o);
  __syncthreads();
  if (lane == 0) red[wv] = q;
  __syncthreads();
  if (threadIdx.x == 0) stat = rsqrtf((red[0]+red[1]+red[2]+red[3])*(1.0f/512.0f) + 1e-5f);
  __syncthreads();
  float rstd = stat;
  out[(long)row*512 + threadIdx.x]     = __float2bfloat16(d0*rstd*g[threadIdx.x]     + b[threadIdx.x]);
  out[(long)row*512 + threadIdx.x+256] = __float2bfloat16(d1*rstd*g[threadIdx.x+256] + b[threadIdx.x+256]);
}

// ---------- MFMA tail GEMM: out = [res +] act(A@W + bias)
template<int NT>
__global__ __launch_bounds__(256) void tail_gemm(
    const bf16* __restrict__ A, const bf16* __restrict__ Wp,
    const float* __restrict__ bias, const float* res,
    float* outf, bf16* outb, int N, int K, int dogelu)
{
  const int wv = threadIdx.x >> 6, lane = threadIdx.x & 63;
  const int li = lane & 15, lg = lane >> 4;
  const int m0 = blockIdx.x * 16;
  const int nb = blockIdx.y * (64*NT) + wv * (16*NT);
  floatx4 acc[NT];
  #pragma unroll
  for (int t = 0; t < NT; t++) acc[t] = (floatx4){0.f,0.f,0.f,0.f};
  const bf16* arow = A + (size_t)(m0+li)*K + lg*8;
  for (int k0 = 0; k0 < K; k0 += 32){
    short8 a = *(const short8*)(arow + k0);
    const bf16* wrow = Wp + ((size_t)((k0>>3) + lg) * N + nb + li) * 8;
    #pragma unroll
    for (int t = 0; t < NT; t++){
      short8 bfr = *(const short8*)(wrow + t*128);
      acc[t] = __builtin_amdgcn_mfma_f32_16x16x32_bf16(a, bfr, acc[t], 0, 0, 0);
    }
  }
  #pragma unroll
  for (int t = 0; t < NT; t++){
    int col = nb + t*16 + li;
    #pragma unroll
    for (int v = 0; v < 4; v++){
      int row = m0 + lg*4 + v;
      float val = acc[t][v];
      if (bias) val += bias[col];
      if (dogelu) val = 0.5f*val*(1.0f + erff(val*0.70710678118654752f));
      if (res) val += res[(size_t)row*N + col];
      if (outf) outf[(size_t)row*N + col] = val;
      else      outb[(size_t)row*N + col] = __float2bfloat16(val);
    }
  }
}

// ---------- Generic small GEMM (head only): out = act(A@W + bias)
__global__ __launch_bounds__(256) void gemm_rows(
    const float* __restrict__ A, const float* __restrict__ W,
    const float* __restrict__ bias, const float* __restrict__ res,
    float* __restrict__ out, int M, int N, int K, int dogelu)
{
  __shared__ float A_s[16][33];
  __shared__ __align__(16) float W_s[32][68];
  const int m0 = blockIdx.x*16, n0 = blockIdx.y*64;
  const int r = threadIdx.x>>4, c0 = (threadIdx.x&15)*4;
  float acc[4] = {};
  for (int k0 = 0; k0 < K; k0 += 32){
    __syncthreads();
    for (int i = 0; i < 2; i++){ int id = threadIdx.x + i*256; int rr = id>>5, kk = id&31;
      A_s[rr][kk] = (m0+rr < M) ? A[(long)(m0+rr)*K + k0+kk] : 0.f; }
    for (int i = 0; i < 8; i++){ int id = threadIdx.x + i*256; int kk = id>>6, c = id&63;
      W_s[kk][c] = (n0+c < N) ? W[(long)(k0+kk)*N + n0+c] : 0.f; }
    __syncthreads();
    #pragma unroll
    for (int kk = 0; kk < 32; kk++){
      float a = A_s[r][kk];
      float4 w4 = *(const float4*)&W_s[kk][c0];
      acc[0]+=a*w4.x; acc[1]+=a*w4.y; acc[2]+=a*w4.z; acc[3]+=a*w4.w;
    }
  }
  if (m0+r < M){
    int row = m0+r;
    for (int j = 0; j < 4; j++){
      int c = n0+c0+j;
      if (c < N){
        float v = acc[j];
        if (bias) v += bias[c];
        if (dogelu) v = 0.5f*v*(1.0f + erff(v*0.70710678118654752f));
        if (res) v += res[(long)row*N + c];
        out[(long)row*N + c] = v;
      }
    }
  }
}

// ---------- Attention: one block per (b,h). N=17, DH=64. Writes bf16 O.
__global__ __launch_bounds__(128) void attn_kernel(
    const float* __restrict__ qkv, bf16* __restrict__ obuf)
{
  const int b = blockIdx.x >> 3, h = blockIdx.x & 7;
  __shared__ float q_s[17][65], k_s[17][65], v_s[17][65], s_s[17][18];
  for (int idx = threadIdx.x; idx < 17*64; idx += 128){
    int i = idx>>6, d = idx&63;
    const float* base = qkv + (long)(b*17+i)*1536 + h*64 + d;
    q_s[i][d] = base[0]; k_s[i][d] = base[512]; v_s[i][d] = base[1024];
  }
  __syncthreads();
  for (int idx = threadIdx.x; idx < 289; idx += 128){
    int i = idx/17, j = idx - i*17;
    float s = 0.f;
    for (int d = 0; d < 64; d++) s += q_s[i][d]*k_s[j][d];
    s_s[i][j] = s*0.125f;
  }
  __syncthreads();
  if (threadIdx.x < 17){
    int i = threadIdx.x;
    float m = -1e30f;
    for (int j = 0; j < 17; j++) m = fmaxf(m, s_s[i][j]);
    float sum = 0.f;
    for (int j = 0; j < 17; j++){ float e = expf(s_s[i][j]-m); s_s[i][j] = e; sum += e; }
    float inv = 1.0f/sum;
    for (int j = 0; j < 17; j++) s_s[i][j] *= inv;
  }
  __syncthreads();
  for (int idx = threadIdx.x; idx < 17*64; idx += 128){
    int i = idx>>6, d = idx&63;
    float o = 0.f;
    for (int j = 0; j < 17; j++) o += s_s[i][j]*v_s[j][d];
    obuf[(long)(b*17+i)*512 + h*64 + d] = __float2bfloat16(o);
  }
}

// ============================================================================
extern "C" void kernel_launch(void* const* d_in, const int* in_sizes, int n_in,
                              void* d_out, int out_size, void* d_ws, size_t ws_size,
                              hipStream_t stream) {
  const float* img      = (const float*)d_in[0];
  const float* conv1_w  = (const float*)d_in[1];
  const float* conv2_w  = (const float*)d_in[2];
  const float* conv3_w  = (const float*)d_in[3];
  const float* flat_w   = (const float*)d_in[4];
  const float* flat_b   = (const float*)d_in[5];
  const float* cls_tok  = (const float*)d_in[6];
  const float* pos_emb  = (const float*)d_in[7];
  const float* ln1_g    = (const float*)d_in[8];
  const float* ln1_b    = (const float*)d_in[9];
  const float* qkv_w    = (const float*)d_in[10];
  const float* out_w    = (const float*)d_in[11];
  const float* out_b    = (const float*)d_in[12];
  const float* ln2_g    = (const float*)d_in[13];
  const float* ln2_b    = (const float*)d_in[14];
  const float* ff1_w    = (const float*)d_in[15];
  const float* ff1_b    = (const float*)d_in[16];
  const float* ff2_w    = (const float*)d_in[17];
  const float* ff2_b    = (const float*)d_in[18];
  const float* hln_g    = (const float*)d_in[19];
  const float* hln_b    = (const float*)d_in[20];
  const float* head_w   = (const float*)d_in[21];
  const float* head_b   = (const float*)d_in[22];

  char* ws = (char*)d_ws;
  size_t off = 0;
  auto alloc = [&](size_t bytes) -> void* {
    void* p = ws + off; off += (bytes + 255) & ~(size_t)255; return p;
  };
  bf16* pool1    = (bf16*)alloc((size_t)CHUNK*8*103*103*4*2); // 43.5 MB (chunk, [n][4][103][103][8])
  bf16* conv2out = (bf16*)alloc((size_t)CHUNK*49*49*64*2);    // 19.7 MB (chunk, NHWC)
  bf16* pool2    = (bf16*)alloc((size_t)256*45*45*64*2);      // 66.4 MB (full, NHWC)
  bf16* feat     = (bf16*)alloc((size_t)256*16384*2);         //  8.4 MB
  bf16* w2b      = (bf16*)alloc((size_t)49*64*32*2);
  bf16* w3b      = (bf16*)alloc((size_t)49*2*64*32*2);
  float* x       = (float*)alloc((size_t)139264*4);           // 272x512 fp32
  bf16*  hb      = (bf16*)alloc((size_t)139264*2);            // 272x512 bf16 (LN out)
  float* qkvb    = (float*)alloc((size_t)417792*4);           // 272x1536 fp32
  bf16*  obufb   = (bf16*)alloc((size_t)139264*2);            // 272x512 bf16
  bf16*  ffbufb  = (bf16*)alloc((size_t)557056*2);            // 272x2048 bf16
  float* hcls    = (float*)alloc((size_t)8192*4);             // 16x512
  // pool1 region reuse (dead at the noted points):
  bf16* tmp3     = pool1;            // k3 horizontal tmp (within chunk loop)
  bf16* conv3out = pool1;            // k4 output (after chunk loop)
  // packed transformer weights alias pool1 AFTER k5 (pool1 fully dead):
  bf16* qkvp  = pool1;               //  9.44 MB
  bf16* outwp = qkvp  + (size_t)6*512*1536;   // 3.15 MB
  bf16* ff1p  = outwp + (size_t)6*512*512;    // 12.58 MB
  bf16* ff2p  = ff1p  + (size_t)6*512*2048;   // 12.58 MB  (total 37.75 <= 43.5)
  // flat_w hi/lo packs alias conv2out (hi) and pool2 (lo) — dead after k5.
  bf16* fwhi  = conv2out;
  bf16* fwlo  = pool2;

  // conv1 intermediate (k1a -> k1b), sized adaptively against ws_size.
  const size_t cb_per_n = (size_t)8*107*107*4*2;   // 733,136 B per patch
  int SUB; bf16* cbuf;
  if (ws_size >= off + 64*cb_per_n)      { SUB = 64; cbuf = (bf16*)alloc(64*cb_per_n); }
  else if (ws_size >= off + 32*cb_per_n) { SUB = 32; cbuf = (bf16*)alloc(32*cb_per_n); }
  else { SUB = 16; cbuf = conv2out; }  // dead-region fallback (see round 7)
  (void)in_sizes; (void)n_in; (void)out_size;

  prep_w2<<<392, 256, 0, stream>>>(conv2_w, w2b);
  prep_w3<<<784, 256, 0, stream>>>(conv3_w, w3b);

  for (int cb = 0; cb < 256; cb += CHUNK){
    for (int sb = 0; sb < CHUNK; sb += SUB){
      k1a_conv1<<<dim3(22, SUB), 256, 0, stream>>>(img, conv1_w, cbuf, cb + sb);
      k1b_pool1<<<dim3(8, 8, SUB), 256, 0, stream>>>(cbuf, pool1, sb);
    }
    k2_conv2     <<<dim3(10,CHUNK), 256, 0, stream>>>(pool1, w2b, conv2out);
    k3a_hmax     <<<(CHUNK*49*45*8)/256, 256, 0, stream>>>(conv2out, tmp3);
    k3b_vmax     <<<(CHUNK*45*45*8)/256, 256, 0, stream>>>(tmp3, pool2, cb);
  }
  k4_conv3<<<dim3(2,256), 256, 0, stream>>>(pool2, w3b, conv3out);
  k5_pool3<<<256, 256, 0, stream>>>(conv3out, feat);

  // packs into dead regions (pool1 / conv2out / pool2 all dead after k5)
  prep_pack_flat<<<4096, 256, 0, stream>>>(flat_w, fwhi, fwlo);
  prep_pack<<<(6*64*1536+255)/256, 256, 0, stream>>>(qkv_w, qkvp, 64, 1536, 6*64*1536);
  prep_pack<<<(6*64*512 +255)/256, 256, 0, stream>>>(out_w, outwp, 64, 512,  6*64*512);
  prep_pack<<<(6*64*2048+255)/256, 256, 0, stream>>>(ff1_w, ff1p, 64, 2048, 6*64*2048);
  prep_pack<<<(6*256*512+255)/256, 256, 0, stream>>>(ff2_w, ff2p, 256, 512, 6*256*512);

  k6_init_x    <<<544,         256, 0, stream>>>(cls_tok, pos_emb, flat_b, x);
  k6_flat_mfma <<<dim3(4,8,8), 256, 0, stream>>>(feat, fwhi, fwlo, x);

  for (int l = 0; l < 6; l++){
    ln_bf16<<<272, 256, 0, stream>>>(x, ln1_g + l*512, ln1_b + l*512, hb);
    tail_gemm<4><<<dim3(17,6), 256, 0, stream>>>(hb, qkvp + (size_t)l*786432,
                                                 nullptr, nullptr, qkvb, nullptr, 1536, 512, 0);
    attn_kernel<<<128, 128, 0, stream>>>(qkvb, obufb);
    tail_gemm<1><<<dim3(17,8), 256, 0, stream>>>(obufb, outwp + (size_t)l*262144,
                                                 out_b + l*512, x, x, nullptr, 512, 512, 0);
    ln_bf16<<<272, 256, 0, stream>>>(x, ln2_g + l*512, ln2_b + l*512, hb);
    tail_gemm<4><<<dim3(17,8), 256, 0, stream>>>(hb, ff1p + (size_t)l*1048576,
                                                 ff1_b + l*2048, nullptr, nullptr, ffbufb, 2048, 512, 1);
    tail_gemm<1><<<dim3(17,8), 256, 0, stream>>>(ffbufb, ff2p + (size_t)l*1048576,
                                                 ff2_b + l*512, x, x, nullptr, 512, 2048, 0);
  }

  ln_kernel<<<16, 256, 0, stream>>>(x, hln_g, hln_b, hcls, 17*512, 512);
  gemm_rows<<<dim3(1,16), 256, 0, stream>>>(hcls, head_w, head_b, nullptr,
                                            (float*)d_out, 16, 1000, 512, 0);
}

// Round 4
// 1701.036 us; speedup vs baseline: 1.1154x; 1.1154x over previous
//
#include <hip/hip_runtime.h>
#include <hip/hip_bf16.h>

// ============================================================================
// HybridViT forward. Round 10: recover from round-9 spill regression.
//  - Round-9 post-mortem: k2/k4 reg-prefetch (pre[12] = 48 VGPRs held across
//    the MFMA phase) spilled to scratch -> WRITE_SIZE 19->190MB, k2 113->165us.
//  - This round: k2/k4 staging back to DIRECT global->LDS (load + immediate
//    ds_write, no regs held), keeping round-9's real wins:
//      * pool1 [n][4][103][103][8] layout: staging = 2884 coalesced int4
//        loads (was 5768 scattered uint2 in round 8).
//      * k2 LDS stride 40->36 elems: 52416 B -> 3 blocks/CU (was 2).
//        Bank check: b-read lane stride 72B = 18 banks -> <=2-way (free).
//  - k4: direct staging, stride 40 kept (38.4KB -> 4 blocks/CU already).
// Rest unchanged from round 9.
// ============================================================================

typedef __hip_bfloat16 bf16;
typedef __attribute__((ext_vector_type(8))) short short8;
typedef __attribute__((ext_vector_type(4))) float floatx4;

#define CHUNK 64

union U8 { int4 v; unsigned short s[8]; };
__device__ inline void umax8(U8& a, const U8& b){
  #pragma unroll
  for (int j = 0; j < 8; j++) a.s[j] = (a.s[j] > b.s[j]) ? a.s[j] : b.s[j];
}
union U4 { uint2 v; unsigned short s[4]; };
__device__ inline void umax4(U4& a, const U4& b){
  #pragma unroll
  for (int j = 0; j < 4; j++) a.s[j] = (a.s[j] > b.s[j]) ? a.s[j] : b.s[j];
}

// ---------- weight prep: conv2_w fp32 [64][32][7][7] -> bf16 [ky*7+kx][64][32]
__global__ __launch_bounds__(256) void prep_w2(const float* __restrict__ w,
                                               bf16* __restrict__ w2b)
{
  int idx = blockIdx.x*256 + threadIdx.x;     // 49*64*32 = 100352
  if (idx >= 49*64*32) return;
  int ic = idx & 31; int t = idx >> 5; int oc = t & 63; int kk = t >> 6;
  int ky = kk/7, kx = kk - ky*7;
  w2b[idx] = __float2bfloat16(w[((oc*32+ic)*7+ky)*7+kx]);
}

// ---------- weight prep: conv3_w fp32 [64][64][7][7] -> bf16 [ky][kc][kx][64][32]
__global__ __launch_bounds__(256) void prep_w3(const float* __restrict__ w,
                                               bf16* __restrict__ w3b)
{
  int idx = blockIdx.x*256 + threadIdx.x;     // 49*2*64*32 = 200704
  if (idx >= 49*2*64*32) return;
  int ic_l = idx & 31; int t = idx >> 5; int oc = t & 63; int t2 = t >> 6;
  int kx = t2 % 7; int t3 = t2 / 7; int kc = t3 & 1; int ky = t3 >> 1;
  w3b[idx] = __float2bfloat16(w[((oc*64 + kc*32 + ic_l)*7+ky)*7+kx]);
}

// ---------- transformer weight pack: fp32 [L][K][N] -> bf16 [L][K/8][N][8]
__global__ __launch_bounds__(256) void prep_pack(
    const float* __restrict__ src, bf16* __restrict__ dst,
    int K8, int N, int total)
{
  int idx = blockIdx.x*256 + threadIdx.x;
  if (idx >= total) return;
  int n = idx % N; int t = idx / N; int k8 = t % K8; int l = t / K8;
  const float* s = src + ((size_t)l*K8*8 + (size_t)k8*8)*N + n;
  union { bf16 h[8]; int4 v; } pk;
  #pragma unroll
  for (int j = 0; j < 8; j++) pk.h[j] = __float2bfloat16(s[(size_t)j*N]);
  *(int4*)(dst + (((size_t)l*K8 + k8)*N + n)*8) = pk.v;
}

// ---------- flat_w pack: fp32 [16384][512] -> hi/lo bf16 [2048][512][8]
__global__ __launch_bounds__(256) void prep_pack_flat(
    const float* __restrict__ src, bf16* __restrict__ hi, bf16* __restrict__ lo)
{
  int idx = blockIdx.x*256 + threadIdx.x;   // 2048*512 = 1048576
  if (idx >= 2048*512) return;
  int n = idx & 511; int k8 = idx >> 9;
  const float* s = src + (size_t)k8*8*512 + n;
  union { bf16 h[8]; int4 v; } ph, pl;
  #pragma unroll
  for (int j = 0; j < 8; j++){
    float w = s[(size_t)j*512];
    bf16 h = __float2bfloat16(w);
    ph.h[j] = h;
    pl.h[j] = __float2bfloat16(w - __bfloat162float(h));
  }
  size_t o = (size_t)idx*8;
  *(int4*)(hi + o) = ph.v;
  *(int4*)(lo + o) = pl.v;
}

// ---------- K1a: patchify + conv1(1->32,7x7,s2) + ReLU
//   -> cbuf [SUB][8grp][107][107][4ch] bf16
__global__ __launch_bounds__(256) void k1a_conv1(
    const float* __restrict__ img, const float* __restrict__ w,
    bf16* __restrict__ cbuf, int n_base)
{
  __shared__ __align__(16) float in_s[15*224];  // input rows 2*r0 .. 2*r0+14
  __shared__ float w_s[32*58];                  // stride 58: 2-way-conflict reads
  const int band = blockIdx.x;                  // 0..21
  const int n = blockIdx.y;                     // 0..SUB-1 (cbuf-local)
  const int ng = n_base + n;                    // global patch for img
  const int r0 = band*5;                        // conv rows r0..r0+4
  const int ir0 = 2*r0;
  const int b = ng>>4, gh = (ng>>2)&3, gw = ng&3;
  const float* ibase = img + b*774400 + (gh*220)*880 + gw*220;

  for (int idx = threadIdx.x; idx < 15*56; idx += 256){
    int r = idx/56, cq = idx - r*56; int c = cq*4;
    int gr = ir0 + r;
    float4 v = (c < 220 && gr < 220) ? *(const float4*)(ibase + gr*880 + c)
                                     : make_float4(0.f,0.f,0.f,0.f);
    *(float4*)&in_s[r*224 + c] = v;
  }
  for (int idx = threadIdx.x; idx < 32*56; idx += 256){
    int oc = idx/56, k = idx - oc*56; int ky = k>>3, kx = k&7;
    w_s[oc*58 + k] = (kx < 7) ? w[oc*49 + ky*7 + kx] : 0.f;
  }
  __syncthreads();

  const int grp = threadIdx.x & 7;
  const int sp  = threadIdx.x >> 3;   // 0..31 col-group (cols 4sp..4sp+3)
  const int cgc = (sp < 26) ? sp : 26;
  const int nrows = (107 - r0 < 5) ? (107 - r0) : 5;

  float acc[5][4][4] = {};            // [row-item][oc][col]
  #pragma unroll 1
  for (int ky = 0; ky < 7; ky++){
    float wk[4][7];
    #pragma unroll
    for (int oc = 0; oc < 4; oc++)
      #pragma unroll
      for (int kx = 0; kx < 7; kx++)
        wk[oc][kx] = w_s[(grp*4+oc)*58 + ky*8 + kx];
    #pragma unroll
    for (int i = 0; i < 5; i++){
      if (i < nrows){
        const float* ip = &in_s[(2*i+ky)*224 + 8*cgc];
        float iv[13];
        *(float4*)&iv[0] = *(const float4*)ip;
        *(float4*)&iv[4] = *(const float4*)(ip+4);
        *(float4*)&iv[8] = *(const float4*)(ip+8);
        iv[12] = ip[12];
        #pragma unroll
        for (int oc = 0; oc < 4; oc++)
          #pragma unroll
          for (int kx = 0; kx < 7; kx++)
            #pragma unroll
            for (int j = 0; j < 4; j++)
              acc[i][oc][j] += iv[2*j+kx]*wk[oc][kx];
      }
    }
  }

  #pragma unroll
  for (int i = 0; i < 5; i++){
    if (i < nrows){
      int y = r0 + i;
      #pragma unroll
      for (int j = 0; j < 4; j++){
        int col = 4*sp + j;
        if (col < 107){
          union { unsigned short s[4]; uint2 u; } pk;
          #pragma unroll
          for (int oc = 0; oc < 4; oc++){
            bf16 hv = __float2bfloat16(fmaxf(acc[i][oc][j], 0.f));
            pk.s[oc] = *(unsigned short*)&hv;
          }
          *(uint2*)(cbuf + (((size_t)(n*8+grp)*107 + y)*107 + col)*4) = pk.u;
        }
      }
    }
  }
}

// ---------- K1b: separable 7x7 s1 p1 max-pool. cbuf -> pool1
//   layout: [n][q=4][103][103][8ch]; grp g -> plane q=g>>1, half h=g&1.
__global__ __launch_bounds__(256) void k1b_pool1(
    const bf16* __restrict__ cbuf, bf16* __restrict__ pool1, int n_pool_base)
{
  __shared__ uint2 in4[19*107];   // conv rows p0-1..p0+17 (clamped)
  __shared__ uint2 ht4[19*103];   // after horizontal 7-max
  const int s = blockIdx.x, g = blockIdx.y, n = blockIdx.z;
  const int p0 = s*13;
  const int PR = (103 - p0 < 13) ? (103 - p0) : 13;
  const int NR = PR + 6;
  const uint2* src = (const uint2*)cbuf + (size_t)(n*8+g)*107*107;

  for (int t = threadIdx.x; t < NR*107; t += 256){
    int r = t/107, c = t - r*107;
    int gr = p0 - 1 + r;
    gr = (gr < 0) ? 0 : ((gr > 106) ? 106 : gr);
    in4[t] = src[gr*107 + c];
  }
  __syncthreads();
  for (int t = threadIdx.x; t < NR*103; t += 256){
    int r = t/103, c = t - r*103;
    U4 m; m.v = in4[r*107 + ((c > 0) ? c-1 : 0)];
    #pragma unroll
    for (int d = 0; d < 6; d++){
      U4 v; v.v = in4[r*107 + ((c+d < 106) ? c+d : 106)];
      umax4(m, v);
    }
    ht4[r*103 + c] = m.v;
  }
  __syncthreads();
  uint2* dst = (uint2*)pool1;
  const size_t plane = ((size_t)(n_pool_base + n)*4 + (g>>1))*10609;
  const int h = g & 1;
  for (int t = threadIdx.x; t < PR*103; t += 256){
    int pr = t/103, c = t - pr*103;
    U4 m; m.v = ht4[pr*103 + c];
    #pragma unroll
    for (int d = 1; d < 7; d++){
      U4 v; v.v = ht4[(pr+d)*103 + c];
      umax4(m, v);
    }
    dst[(plane + (size_t)(p0+pr)*103 + c)*2 + h] = m.v;
  }
}

// ---------- K2: conv2 MFMA implicit GEMM, direct LDS staging.
// pool1 [CHUNK][4][103][103][8] -> conv2out NHWC [CHUNK,49,49,64]
// LDS stride 36 elems: 52416 B -> 3 blocks/CU.
__global__ __launch_bounds__(256) void k2_conv2(
    const bf16* __restrict__ pool1,
    const bf16* __restrict__ w2b,     // [49][64][32]
    bf16* __restrict__ conv2out)
{
  __shared__ __align__(16) bf16 in_s[7*2*52*36];   // 52416 B
  const int n = blockIdx.y, pb = blockIdx.x;       // pb 0..9
  const int wv = threadIdx.x >> 6, lane = threadIdx.x & 63;
  const int li = lane & 15, lg = lane >> 4;
  const int p0 = pb*256;
  const int y0 = p0/49;

  int pyv[4], pxv[4], poff[4]; bool pmask[4];
  #pragma unroll
  for (int t = 0; t < 4; t++){
    int p = p0 + wv*64 + t*16 + li;
    pmask[t] = (p <= 2400);
    int pc = min(p, 2400);
    int yy = pc/49, xx = pc - yy*49;
    pyv[t] = yy; pxv[t] = xx;
    poff[t] = ((yy - y0)*2*52 + xx)*36;
  }
  floatx4 acc[4][4];
  #pragma unroll
  for (int a = 0; a < 4; a++)
    #pragma unroll
    for (int t = 0; t < 4; t++) acc[a][t] = (floatx4){0.f,0.f,0.f,0.f};

  const unsigned short* pbase = (const unsigned short*)pool1;
  for (int ky = 0; ky < 7; ky++){
    __syncthreads();
    for (int idx = threadIdx.x; idx < 7*103*4; idx += 256){
      int q = idx & 3; int t2 = idx >> 2; int c = t2 % 103; int r = t2/103;
      int gr = min(2*(y0+r)+ky, 102);
      *(int4*)&in_s[((r*2 + (c&1))*52 + (c>>1))*36 + q*8] =
        *(const int4*)(pbase + (((size_t)n*4 + q)*10609 + (size_t)gr*103 + c)*8);
    }
    __syncthreads();
    #pragma unroll
    for (int kx = 0; kx < 7; kx++){
      short8 a[4];
      const bf16* wp = w2b + (ky*7+kx)*64*32;
      #pragma unroll
      for (int ot = 0; ot < 4; ot++)
        a[ot] = *(const short8*)(wp + (ot*16 + li)*32 + lg*8);
      int koff = ((kx&1)*52 + (kx>>1))*36 + lg*8;
      #pragma unroll
      for (int t = 0; t < 4; t++){
        short8 bfr = *(const short8*)(&in_s[poff[t] + koff]);
        #pragma unroll
        for (int ot = 0; ot < 4; ot++)
          acc[ot][t] = __builtin_amdgcn_mfma_f32_16x16x32_bf16(a[ot], bfr, acc[ot][t], 0, 0, 0);
      }
    }
  }
  #pragma unroll
  for (int t = 0; t < 4; t++){
    if (!pmask[t]) continue;
    bf16* dst = conv2out + (((long)n*49 + pyv[t])*49 + pxv[t])*64 + lg*4;
    #pragma unroll
    for (int ot = 0; ot < 4; ot++){
      union { bf16 h[4]; uint2 u; } pk;
      #pragma unroll
      for (int v = 0; v < 4; v++)
        pk.h[v] = __float2bfloat16(fmaxf(acc[ot][t][v], 0.f));
      *(uint2*)(dst + ot*16) = pk.u;
    }
  }
}

// ---------- K3a: horizontal 7-max: conv2out [CHUNK,49,49,64] -> tmp [CHUNK,49,45,64]
__global__ __launch_bounds__(256) void k3a_hmax(
    const bf16* __restrict__ cin, bf16* __restrict__ tmp)
{
  int idx = blockIdx.x*256 + threadIdx.x;
  int cg = idx & 7; int t = idx >> 3; int x = t % 45; int t2 = t / 45;
  int y = t2 % 49; int n = t2 / 49;
  const int4* row = (const int4*)(cin + ((long)(n*49 + y)*49)*64) + cg;
  U8 m; m.v = make_int4(0,0,0,0);
  int lo = max(x-1, 0), hi = min(x+5, 48);
  for (int cx = lo; cx <= hi; cx++){ U8 v; v.v = row[cx*8]; umax8(m, v); }
  *((int4*)(tmp + ((long)(n*49 + y)*45 + x)*64) + cg) = m.v;
}

// ---------- K3b: vertical 7-max: tmp -> pool2 [256,45,45,64] at n_base
__global__ __launch_bounds__(256) void k3b_vmax(
    const bf16* __restrict__ tmp, bf16* __restrict__ pout, int n_base)
{
  int idx = blockIdx.x*256 + threadIdx.x;
  int cg = idx & 7; int t = idx >> 3; int x = t % 45; int t2 = t / 45;
  int y = t2 % 45; int n = t2 / 45;
  U8 m; m.v = make_int4(0,0,0,0);
  int lo = max(y-1, 0), hi = min(y+5, 48);
  for (int cy = lo; cy <= hi; cy++){
    U8 v; v.v = *((const int4*)(tmp + ((long)(n*49 + cy)*45 + x)*64) + cg);
    umax8(m, v);
  }
  *((int4*)(pout + (long)(n_base+n)*129600 + (y*45 + x)*64) + cg) = m.v;
}

// ---------- K4: conv3 MFMA implicit GEMM, direct LDS staging.
// pool2 NHWC -> conv3out NHWC [256,20,20,64]
__global__ __launch_bounds__(256) void k4_conv3(
    const bf16* __restrict__ pool2,
    const bf16* __restrict__ w3b,     // [ky][kc][kx][64][32]
    bf16* __restrict__ conv3out)
{
  __shared__ __align__(16) bf16 in_s[10*2*24*40];  // 38400 B -> 4 blocks/CU
  const int n = blockIdx.y, pb = blockIdx.x;       // pb 0..1
  const int wv = threadIdx.x >> 6, lane = threadIdx.x & 63;
  const int li = lane & 15, lg = lane >> 4;
  const int y0 = pb*10;

  int pyv[4], pxv[4], poff[4]; bool pmask[4];
  #pragma unroll
  for (int t = 0; t < 4; t++){
    int pl = wv*64 + t*16 + li;
    pmask[t] = (pl < 200);
    int p = pb*200 + min(pl, 199);
    int yy = p/20, xx = p - yy*20;
    pyv[t] = yy; pxv[t] = xx;
    poff[t] = ((yy - y0)*2*24 + xx)*40;
  }
  floatx4 acc[4][4];
  #pragma unroll
  for (int a = 0; a < 4; a++)
    #pragma unroll
    for (int t = 0; t < 4; t++) acc[a][t] = (floatx4){0.f,0.f,0.f,0.f};

  for (int ky = 0; ky < 7; ky++){
    for (int kc = 0; kc < 2; kc++){
      __syncthreads();
      for (int idx = threadIdx.x; idx < 10*45*4; idx += 256){
        int q = idx & 3; int t2 = idx >> 2; int c = t2 % 45; int r = t2/45;
        int gr = 2*(y0+r)+ky;
        const bf16* src = pool2 + (((long)n*45 + gr)*45 + c)*64 + kc*32 + q*8;
        bf16* dst = &in_s[((r*2 + (c&1))*24 + (c>>1))*40 + q*8];
        *(int4*)dst = *(const int4*)src;
      }
      __syncthreads();
      #pragma unroll
      for (int kx = 0; kx < 7; kx++){
        short8 a[4];
        const bf16* wp = w3b + ((ky*2+kc)*7 + kx)*64*32;
        #pragma unroll
        for (int ot = 0; ot < 4; ot++)
          a[ot] = *(const short8*)(wp + (ot*16 + li)*32 + lg*8);
        int koff = ((kx&1)*24 + (kx>>1))*40 + lg*8;
        #pragma unroll
        for (int t = 0; t < 4; t++){
          short8 bfr = *(const short8*)(&in_s[poff[t] + koff]);
          #pragma unroll
          for (int ot = 0; ot < 4; ot++)
            acc[ot][t] = __builtin_amdgcn_mfma_f32_16x16x32_bf16(a[ot], bfr, acc[ot][t], 0, 0, 0);
        }
      }
    }
  }
  #pragma unroll
  for (int t = 0; t < 4; t++){
    if (!pmask[t]) continue;
    bf16* dst = conv3out + (((long)n*20 + pyv[t])*20 + pxv[t])*64 + lg*4;
    #pragma unroll
    for (int ot = 0; ot < 4; ot++){
      union { bf16 h[4]; uint2 u; } pk;
      #pragma unroll
      for (int v = 0; v < 4; v++)
        pk.h[v] = __float2bfloat16(fmaxf(acc[ot][t][v], 0.f));
      *(uint2*)(dst + ot*16) = pk.u;
    }
  }
}

// ---------- K5: in-LDS separable pool3. conv3out [256,20,20,64] -> feat [256,16384]
__global__ __launch_bounds__(256) void k5_pool3(
    const bf16* __restrict__ cin, bf16* __restrict__ feat)
{
  __shared__ int4 in_p[3200];
  __shared__ int4 ht[2560];
  const int n = blockIdx.x;
  const int4* src = (const int4*)(cin + (long)n*25600);
  for (int i = threadIdx.x; i < 3200; i += 256) in_p[i] = src[i];
  __syncthreads();
  for (int i = threadIdx.x; i < 2560; i += 256){
    int cg = i & 7; int t = i >> 3; int x = t & 15; int y = t >> 4;
    U8 m; m.v = make_int4(0,0,0,0);
    int lo = max(x-1, 0), hi = min(x+5, 19);
    for (int cx = lo; cx <= hi; cx++){ U8 v; v.v = in_p[(y*20+cx)*8 + cg]; umax8(m, v); }
    ht[(y*16+x)*8 + cg] = m.v;
  }
  __syncthreads();
  unsigned short* dst = (unsigned short*)(feat + (long)n*16384);
  for (int i = threadIdx.x; i < 2048; i += 256){
    int px = i & 15; int py = (i >> 4) & 15; int cg = i >> 8;
    U8 m; m.v = make_int4(0,0,0,0);
    int lo = max(py-1, 0), hi = min(py+5, 19);
    for (int cy = lo; cy <= hi; cy++){ U8 v; v.v = ht[(cy*16+px)*8 + cg]; umax8(m, v); }
    #pragma unroll
    for (int j = 0; j < 8; j++)
      dst[(cg*8+j)*256 + py*16 + px] = m.s[j];
  }
}

// ---------- K6a: init x[272,512]
__global__ __launch_bounds__(256) void k6_init_x(
    const float* __restrict__ cls, const float* __restrict__ pos,
    const float* __restrict__ flat_b, float* __restrict__ x)
{
  int idx = blockIdx.x*256 + threadIdx.x;
  int d = idx & 511; int row = idx >> 9;
  int tt = row % 17;
  x[idx] = (tt == 0) ? (cls[d] + pos[d]) : (flat_b[d] + pos[tt*512 + d]);
}

// ---------- K6b: feat @ flat_w via MFMA (hi+lo bf16 W). atomicAdd into x.
__global__ __launch_bounds__(256) void k6_flat_mfma(
    const bf16* __restrict__ feat, const bf16* __restrict__ Whi,
    const bf16* __restrict__ Wlo, float* __restrict__ x)
{
  const int wv = threadIdx.x >> 6, lane = threadIdx.x & 63;
  const int li = lane & 15, lg = lane >> 4;
  const int m0 = blockIdx.x*64 + wv*16;     // wave's 16-row tile
  const int nb = blockIdx.y*64;             // block's 64 cols
  const int kb = blockIdx.z*2048;           // k-range
  floatx4 acc[4];
  #pragma unroll
  for (int t = 0; t < 4; t++) acc[t] = (floatx4){0.f,0.f,0.f,0.f};

  const bf16* arow = feat + (size_t)(m0+li)*16384 + kb + lg*8;
  for (int k0 = 0; k0 < 2048; k0 += 32){
    short8 a = *(const short8*)(arow + k0);
    size_t wo = ((size_t)((kb + k0) >> 3) + lg)*512 + nb + li;  // in 8-elt units
    const bf16* wh = Whi + wo*8;
    const bf16* wl = Wlo + wo*8;
    #pragma unroll
    for (int t = 0; t < 4; t++){
      short8 bh = *(const short8*)(wh + t*128);
      acc[t] = __builtin_amdgcn_mfma_f32_16x16x32_bf16(a, bh, acc[t], 0, 0, 0);
    }
    #pragma unroll
    for (int t = 0; t < 4; t++){
      short8 bl = *(const short8*)(wl + t*128);
      acc[t] = __builtin_amdgcn_mfma_f32_16x16x32_bf16(a, bl, acc[t], 0, 0, 0);
    }
  }
  #pragma unroll
  for (int t = 0; t < 4; t++){
    int col = nb + t*16 + li;
    #pragma unroll
    for (int v = 0; v < 4; v++){
      int m = m0 + lg*4 + v;
      int row = (m>>4)*17 + 1 + (m&15);
      atomicAdd(&x[row*512 + col], acc[t][v]);
    }
  }
}

// ---------- LayerNorm over 512, fp32 out (head path)
__global__ __launch_bounds__(256) void ln_kernel(
    const float* __restrict__ in, const float* __restrict__ g,
    const float* __restrict__ b, float* __restrict__ out,
    int in_stride, int out_stride)
{
  int row = blockIdx.x;
  const float* p = in + (long)row*in_stride;
  float v0 = p[threadIdx.x], v1 = p[threadIdx.x+256];
  __shared__ float red[4]; __shared__ float stat;
  float s = v0+v1;
  #pragma unroll
  for (int o = 32; o >= 1; o >>= 1) s += __shfl_down(s, o);
  int lane = threadIdx.x & 63, wv = threadIdx.x >> 6;
  if (lane == 0) red[wv] = s;
  __syncthreads();
  if (threadIdx.x == 0) stat = (red[0]+red[1]+red[2]+red[3])*(1.0f/512.0f);
  __syncthreads();
  float m = stat;
  float d0 = v0-m, d1 = v1-m;
  float q = d0*d0 + d1*d1;
  #pragma unroll
  for (int o = 32; o >= 1; o >>= 1) q += __shfl_down(q, o);
  __syncthreads();
  if (lane == 0) red[wv] = q;
  __syncthreads();
  if (threadIdx.x == 0) stat = rsqrtf((red[0]+red[1]+red[2]+red[3])*(1.0f/512.0f) + 1e-5f);
  __syncthreads();
  float rstd = stat;
  out[(long)row*out_stride + threadIdx.x]     = d0*rstd*g[threadIdx.x]     + b[threadIdx.x];
  out[(long)row*out_stride + threadIdx.x+256] = d1*rstd*g[threadIdx.x+256] + b[threadIdx.x+256];
}

// ---------- LayerNorm over 512, bf16 out (MFMA tail activations)
__global__ __launch_bounds__(256) void ln_bf16(
    const float* __restrict__ in, const float* __restrict__ g,
    const float* __restrict__ b, bf16* __restrict__ out)
{
  int row = blockIdx.x;
  const float* p = in + (long)row*512;
  float v0 = p[threadIdx.x], v1 = p[threadIdx.x+256];
  __shared__ float red[4]; __shared__ float stat;
  float s = v0+v1;
  #pragma unroll
  for (int o = 32; o >= 1; o >>= 1) s += __shfl_down(s, o);
  int lane = threadIdx.x & 63, wv = threadIdx.x >> 6;
  if (lane == 0) red[wv] = s;
  __syncthreads();
  if (threadIdx.x == 0) stat = (red[0]+red[1]+red[2]+red[3])*(1.0f/512.0f);
  __syncthreads();
  float m = stat;
  float d0 = v0-m, d1 = v1-m;
  float q = d0*d0 + d1*d1;
  #pragma unroll
  for (int o = 32; o >= 1; o >>= 1) q += __shfl_down(q, o);
  __syncthreads();
  if (lane == 0) red[wv] = q;
  __syncthreads();
  if (threadIdx.x == 0) stat = rsqrtf((red[0]+red[1]+red[2]+red[3])*(1.0f/512.0f) + 1e-5f);
  __syncthreads();
  float rstd = stat;
  out[(long)row*512 + threadIdx.x]     = __float2bfloat16(d0*rstd*g[threadIdx.x]     + b[threadIdx.x]);
  out[(long)row*512 + threadIdx.x+256] = __float2bfloat16(d1*rstd*g[threadIdx.x+256] + b[threadIdx.x+256]);
}

// ---------- MFMA tail GEMM: out = [res +] act(A@W + bias)
template<int NT>
__global__ __launch_bounds__(256) void tail_gemm(
    const bf16* __restrict__ A, const bf16* __restrict__ Wp,
    const float* __restrict__ bias, const float* res,
    float* outf, bf16* outb, int N, int K, int dogelu)
{
  const int wv = threadIdx.x >> 6, lane = threadIdx.x & 63;
  const int li = lane & 15, lg = lane >> 4;
  const int m0 = blockIdx.x * 16;
  const int nb = blockIdx.y * (64*NT) + wv * (16*NT);
  floatx4 acc[NT];
  #pragma unroll
  for (int t = 0; t < NT; t++) acc[t] = (floatx4){0.f,0.f,0.f,0.f};
  const bf16* arow = A + (size_t)(m0+li)*K + lg*8;
  for (int k0 = 0; k0 < K; k0 += 32){
    short8 a = *(const short8*)(arow + k0);
    const bf16* wrow = Wp + ((size_t)((k0>>3) + lg) * N + nb + li) * 8;
    #pragma unroll
    for (int t = 0; t < NT; t++){
      short8 bfr = *(const short8*)(wrow + t*128);
      acc[t] = __builtin_amdgcn_mfma_f32_16x16x32_bf16(a, bfr, acc[t], 0, 0, 0);
    }
  }
  #pragma unroll
  for (int t = 0; t < NT; t++){
    int col = nb + t*16 + li;
    #pragma unroll
    for (int v = 0; v < 4; v++){
      int row = m0 + lg*4 + v;
      float val = acc[t][v];
      if (bias) val += bias[col];
      if (dogelu) val = 0.5f*val*(1.0f + erff(val*0.70710678118654752f));
      if (res) val += res[(size_t)row*N + col];
      if (outf) outf[(size_t)row*N + col] = val;
      else      outb[(size_t)row*N + col] = __float2bfloat16(val);
    }
  }
}

// ---------- Generic small GEMM (head only): out = act(A@W + bias)
__global__ __launch_bounds__(256) void gemm_rows(
    const float* __restrict__ A, const float* __restrict__ W,
    const float* __restrict__ bias, const float* __restrict__ res,
    float* __restrict__ out, int M, int N, int K, int dogelu)
{
  __shared__ float A_s[16][33];
  __shared__ __align__(16) float W_s[32][68];
  const int m0 = blockIdx.x*16, n0 = blockIdx.y*64;
  const int r = threadIdx.x>>4, c0 = (threadIdx.x&15)*4;
  float acc[4] = {};
  for (int k0 = 0; k0 < K; k0 += 32){
    __syncthreads();
    for (int i = 0; i < 2; i++){ int id = threadIdx.x + i*256; int rr = id>>5, kk = id&31;
      A_s[rr][kk] = (m0+rr < M) ? A[(long)(m0+rr)*K + k0+kk] : 0.f; }
    for (int i = 0; i < 8; i++){ int id = threadIdx.x + i*256; int kk = id>>6, c = id&63;
      W_s[kk][c] = (n0+c < N) ? W[(long)(k0+kk)*N + n0+c] : 0.f; }
    __syncthreads();
    #pragma unroll
    for (int kk = 0; kk < 32; kk++){
      float a = A_s[r][kk];
      float4 w4 = *(const float4*)&W_s[kk][c0];
      acc[0]+=a*w4.x; acc[1]+=a*w4.y; acc[2]+=a*w4.z; acc[3]+=a*w4.w;
    }
  }
  if (m0+r < M){
    int row = m0+r;
    for (int j = 0; j < 4; j++){
      int c = n0+c0+j;
      if (c < N){
        float v = acc[j];
        if (bias) v += bias[c];
        if (dogelu) v = 0.5f*v*(1.0f + erff(v*0.70710678118654752f));
        if (res) v += res[(long)row*N + c];
        out[(long)row*N + c] = v;
      }
    }
  }
}

// ---------- Attention: one block per (b,h). N=17, DH=64. Writes bf16 O.
__global__ __launch_bounds__(128) void attn_kernel(
    const float* __restrict__ qkv, bf16* __restrict__ obuf)
{
  const int b = blockIdx.x >> 3, h = blockIdx.x & 7;
  __shared__ float q_s[17][65], k_s[17][65], v_s[17][65], s_s[17][18];
  for (int idx = threadIdx.x; idx < 17*64; idx += 128){
    int i = idx>>6, d = idx&63;
    const float* base = qkv + (long)(b*17+i)*1536 + h*64 + d;
    q_s[i][d] = base[0]; k_s[i][d] = base[512]; v_s[i][d] = base[1024];
  }
  __syncthreads();
  for (int idx = threadIdx.x; idx < 289; idx += 128){
    int i = idx/17, j = idx - i*17;
    float s = 0.f;
    for (int d = 0; d < 64; d++) s += q_s[i][d]*k_s[j][d];
    s_s[i][j] = s*0.125f;
  }
  __syncthreads();
  if (threadIdx.x < 17){
    int i = threadIdx.x;
    float m = -1e30f;
    for (int j = 0; j < 17; j++) m = fmaxf(m, s_s[i][j]);
    float sum = 0.f;
    for (int j = 0; j < 17; j++){ float e = expf(s_s[i][j]-m); s_s[i][j] = e; sum += e; }
    float inv = 1.0f/sum;
    for (int j = 0; j < 17; j++) s_s[i][j] *= inv;
  }
  __syncthreads();
  for (int idx = threadIdx.x; idx < 17*64; idx += 128){
    int i = idx>>6, d = idx&63;
    float o = 0.f;
    for (int j = 0; j < 17; j++) o += s_s[i][j]*v_s[j][d];
    obuf[(long)(b*17+i)*512 + h*64 + d] = __float2bfloat16(o);
  }
}

// ============================================================================
extern "C" void kernel_launch(void* const* d_in, const int* in_sizes, int n_in,
                              void* d_out, int out_size, void* d_ws, size_t ws_size,
                              hipStream_t stream) {
  const float* img      = (const float*)d_in[0];
  const float* conv1_w  = (const float*)d_in[1];
  const float* conv2_w  = (const float*)d_in[2];
  const float* conv3_w  = (const float*)d_in[3];
  const float* flat_w   = (const float*)d_in[4];
  const float* flat_b   = (const float*)d_in[5];
  const float* cls_tok  = (const float*)d_in[6];
  const float* pos_emb  = (const float*)d_in[7];
  const float* ln1_g    = (const float*)d_in[8];
  const float* ln1_b    = (const float*)d_in[9];
  const float* qkv_w    = (const float*)d_in[10];
  const float* out_w    = (const float*)d_in[11];
  const float* out_b    = (const float*)d_in[12];
  const float* ln2_g    = (const float*)d_in[13];
  const float* ln2_b    = (const float*)d_in[14];
  const float* ff1_w    = (const float*)d_in[15];
  const float* ff1_b    = (const float*)d_in[16];
  const float* ff2_w    = (const float*)d_in[17];
  const float* ff2_b    = (const float*)d_in[18];
  const float* hln_g    = (const float*)d_in[19];
  const float* hln_b    = (const float*)d_in[20];
  const float* head_w   = (const float*)d_in[21];
  const float* head_b   = (const float*)d_in[22];

  char* ws = (char*)d_ws;
  size_t off = 0;
  auto alloc = [&](size_t bytes) -> void* {
    void* p = ws + off; off += (bytes + 255) & ~(size_t)255; return p;
  };
  bf16* pool1    = (bf16*)alloc((size_t)CHUNK*8*103*103*4*2); // 43.5 MB (chunk, [n][4][103][103][8])
  bf16* conv2out = (bf16*)alloc((size_t)CHUNK*49*49*64*2);    // 19.7 MB (chunk, NHWC)
  bf16* pool2    = (bf16*)alloc((size_t)256*45*45*64*2);      // 66.4 MB (full, NHWC)
  bf16* feat     = (bf16*)alloc((size_t)256*16384*2);         //  8.4 MB
  bf16* w2b      = (bf16*)alloc((size_t)49*64*32*2);
  bf16* w3b      = (bf16*)alloc((size_t)49*2*64*32*2);
  float* x       = (float*)alloc((size_t)139264*4);           // 272x512 fp32
  bf16*  hb      = (bf16*)alloc((size_t)139264*2);            // 272x512 bf16 (LN out)
  float* qkvb    = (float*)alloc((size_t)417792*4);           // 272x1536 fp32
  bf16*  obufb   = (bf16*)alloc((size_t)139264*2);            // 272x512 bf16
  bf16*  ffbufb  = (bf16*)alloc((size_t)557056*2);            // 272x2048 bf16
  float* hcls    = (float*)alloc((size_t)8192*4);             // 16x512
  // pool1 region reuse (dead at the noted points):
  bf16* tmp3     = pool1;            // k3 horizontal tmp (within chunk loop)
  bf16* conv3out = pool1;            // k4 output (after chunk loop)
  // packed transformer weights alias pool1 AFTER k5 (pool1 fully dead):
  bf16* qkvp  = pool1;               //  9.44 MB
  bf16* outwp = qkvp  + (size_t)6*512*1536;   // 3.15 MB
  bf16* ff1p  = outwp + (size_t)6*512*512;    // 12.58 MB
  bf16* ff2p  = ff1p  + (size_t)6*512*2048;   // 12.58 MB  (total 37.75 <= 43.5)
  // flat_w hi/lo packs alias conv2out (hi) and pool2 (lo) — dead after k5.
  bf16* fwhi  = conv2out;
  bf16* fwlo  = pool2;

  // conv1 intermediate (k1a -> k1b), sized adaptively against ws_size.
  const size_t cb_per_n = (size_t)8*107*107*4*2;   // 733,136 B per patch
  int SUB; bf16* cbuf;
  if (ws_size >= off + 64*cb_per_n)      { SUB = 64; cbuf = (bf16*)alloc(64*cb_per_n); }
  else if (ws_size >= off + 32*cb_per_n) { SUB = 32; cbuf = (bf16*)alloc(32*cb_per_n); }
  else { SUB = 16; cbuf = conv2out; }  // dead-region fallback (see round 7)
  (void)in_sizes; (void)n_in; (void)out_size;

  prep_w2<<<392, 256, 0, stream>>>(conv2_w, w2b);
  prep_w3<<<784, 256, 0, stream>>>(conv3_w, w3b);

  for (int cb = 0; cb < 256; cb += CHUNK){
    for (int sb = 0; sb < CHUNK; sb += SUB){
      k1a_conv1<<<dim3(22, SUB), 256, 0, stream>>>(img, conv1_w, cbuf, cb + sb);
      k1b_pool1<<<dim3(8, 8, SUB), 256, 0, stream>>>(cbuf, pool1, sb);
    }
    k2_conv2     <<<dim3(10,CHUNK), 256, 0, stream>>>(pool1, w2b, conv2out);
    k3a_hmax     <<<(CHUNK*49*45*8)/256, 256, 0, stream>>>(conv2out, tmp3);
    k3b_vmax     <<<(CHUNK*45*45*8)/256, 256, 0, stream>>>(tmp3, pool2, cb);
  }
  k4_conv3<<<dim3(2,256), 256, 0, stream>>>(pool2, w3b, conv3out);
  k5_pool3<<<256, 256, 0, stream>>>(conv3out, feat);

  // packs into dead regions (pool1 / conv2out / pool2 all dead after k5)
  prep_pack_flat<<<4096, 256, 0, stream>>>(flat_w, fwhi, fwlo);
  prep_pack<<<(6*64*1536+255)/256, 256, 0, stream>>>(qkv_w, qkvp, 64, 1536, 6*64*1536);
  prep_pack<<<(6*64*512 +255)/256, 256, 0, stream>>>(out_w, outwp, 64, 512,  6*64*512);
  prep_pack<<<(6*64*2048+255)/256, 256, 0, stream>>>(ff1_w, ff1p, 64, 2048, 6*64*2048);
  prep_pack<<<(6*256*512+255)/256, 256, 0, stream>>>(ff2_w, ff2p, 256, 512, 6*256*512);

  k6_init_x    <<<544,         256, 0, stream>>>(cls_tok, pos_emb, flat_b, x);
  k6_flat_mfma <<<dim3(4,8,8), 256, 0, stream>>>(feat, fwhi, fwlo, x);

  for (int l = 0; l < 6; l++){
    ln_bf16<<<272, 256, 0, stream>>>(x, ln1_g + l*512, ln1_b + l*512, hb);
    tail_gemm<4><<<dim3(17,6), 256, 0, stream>>>(hb, qkvp + (size_t)l*786432,
                                                 nullptr, nullptr, qkvb, nullptr, 1536, 512, 0);
    attn_kernel<<<128, 128, 0, stream>>>(qkvb, obufb);
    tail_gemm<1><<<dim3(17,8), 256, 0, stream>>>(obufb, outwp + (size_t)l*262144,
                                                 out_b + l*512, x, x, nullptr, 512, 512, 0);
    ln_bf16<<<272, 256, 0, stream>>>(x, ln2_g + l*512, ln2_b + l*512, hb);
    tail_gemm<4><<<dim3(17,8), 256, 0, stream>>>(hb, ff1p + (size_t)l*1048576,
                                                 ff1_b + l*2048, nullptr, nullptr, ffbufb, 2048, 512, 1);
    tail_gemm<1><<<dim3(17,8), 256, 0, stream>>>(ffbufb, ff2p + (size_t)l*1048576,
                                                 ff2_b + l*512, x, x, nullptr, 512, 2048, 0);
  }

  ln_kernel<<<16, 256, 0, stream>>>(x, hln_g, hln_b, hcls, 17*512, 512);
  gemm_rows<<<dim3(1,16), 256, 0, stream>>>(hcls, head_w, head_b, nullptr,
                                            (float*)d_out, 16, 1000, 512, 0);
}

// Round 5
// 1598.649 us; speedup vs baseline: 1.1869x; 1.0640x over previous
//
#include <hip/hip_runtime.h>
#include <hip/hip_bf16.h>

// ============================================================================
// HybridViT forward. Round 11: k2 parity-ordered circular row staging.
//  - Round-10 state: k2 = 105us x4, MfmaUtil 12%, latency-bound; 49 row-loads
//    per block vs 19 distinct rows (stride-2 conv: consecutive ky disjoint
//    parity, ky/ky+2 share 6/7 rows).
//  - This round: ky order {0,2,4,6,1,3,5}; 7-slot circular LDS row buffer,
//    slot = (yy + (ky>>1)) % 7. Full stage only at ky=0 and ky=1; other 5
//    phases stage ONE row (1.6 loads/thread, hidden under 112-MFMA compute).
//    19 row-loads/block (minimum). Same LDS (52416B, 3 blk/CU), same barrier
//    count, identical numerics (same values & accumulation order).
//  - WRITE_SIZE is the spill canary: must stay ~19MB (round-9 lesson).
// Rest unchanged from round 10.
// ============================================================================

typedef __hip_bfloat16 bf16;
typedef __attribute__((ext_vector_type(8))) short short8;
typedef __attribute__((ext_vector_type(4))) float floatx4;

#define CHUNK 64

union U8 { int4 v; unsigned short s[8]; };
__device__ inline void umax8(U8& a, const U8& b){
  #pragma unroll
  for (int j = 0; j < 8; j++) a.s[j] = (a.s[j] > b.s[j]) ? a.s[j] : b.s[j];
}
union U4 { uint2 v; unsigned short s[4]; };
__device__ inline void umax4(U4& a, const U4& b){
  #pragma unroll
  for (int j = 0; j < 4; j++) a.s[j] = (a.s[j] > b.s[j]) ? a.s[j] : b.s[j];
}

// ---------- weight prep: conv2_w fp32 [64][32][7][7] -> bf16 [ky*7+kx][64][32]
__global__ __launch_bounds__(256) void prep_w2(const float* __restrict__ w,
                                               bf16* __restrict__ w2b)
{
  int idx = blockIdx.x*256 + threadIdx.x;     // 49*64*32 = 100352
  if (idx >= 49*64*32) return;
  int ic = idx & 31; int t = idx >> 5; int oc = t & 63; int kk = t >> 6;
  int ky = kk/7, kx = kk - ky*7;
  w2b[idx] = __float2bfloat16(w[((oc*32+ic)*7+ky)*7+kx]);
}

// ---------- weight prep: conv3_w fp32 [64][64][7][7] -> bf16 [ky][kc][kx][64][32]
__global__ __launch_bounds__(256) void prep_w3(const float* __restrict__ w,
                                               bf16* __restrict__ w3b)
{
  int idx = blockIdx.x*256 + threadIdx.x;     // 49*2*64*32 = 200704
  if (idx >= 49*2*64*32) return;
  int ic_l = idx & 31; int t = idx >> 5; int oc = t & 63; int t2 = t >> 6;
  int kx = t2 % 7; int t3 = t2 / 7; int kc = t3 & 1; int ky = t3 >> 1;
  w3b[idx] = __float2bfloat16(w[((oc*64 + kc*32 + ic_l)*7+ky)*7+kx]);
}

// ---------- transformer weight pack: fp32 [L][K][N] -> bf16 [L][K/8][N][8]
__global__ __launch_bounds__(256) void prep_pack(
    const float* __restrict__ src, bf16* __restrict__ dst,
    int K8, int N, int total)
{
  int idx = blockIdx.x*256 + threadIdx.x;
  if (idx >= total) return;
  int n = idx % N; int t = idx / N; int k8 = t % K8; int l = t / K8;
  const float* s = src + ((size_t)l*K8*8 + (size_t)k8*8)*N + n;
  union { bf16 h[8]; int4 v; } pk;
  #pragma unroll
  for (int j = 0; j < 8; j++) pk.h[j] = __float2bfloat16(s[(size_t)j*N]);
  *(int4*)(dst + (((size_t)l*K8 + k8)*N + n)*8) = pk.v;
}

// ---------- flat_w pack: fp32 [16384][512] -> hi/lo bf16 [2048][512][8]
__global__ __launch_bounds__(256) void prep_pack_flat(
    const float* __restrict__ src, bf16* __restrict__ hi, bf16* __restrict__ lo)
{
  int idx = blockIdx.x*256 + threadIdx.x;   // 2048*512 = 1048576
  if (idx >= 2048*512) return;
  int n = idx & 511; int k8 = idx >> 9;
  const float* s = src + (size_t)k8*8*512 + n;
  union { bf16 h[8]; int4 v; } ph, pl;
  #pragma unroll
  for (int j = 0; j < 8; j++){
    float w = s[(size_t)j*512];
    bf16 h = __float2bfloat16(w);
    ph.h[j] = h;
    pl.h[j] = __float2bfloat16(w - __bfloat162float(h));
  }
  size_t o = (size_t)idx*8;
  *(int4*)(hi + o) = ph.v;
  *(int4*)(lo + o) = pl.v;
}

// ---------- K1a: patchify + conv1(1->32,7x7,s2) + ReLU
//   -> cbuf [SUB][8grp][107][107][4ch] bf16
__global__ __launch_bounds__(256) void k1a_conv1(
    const float* __restrict__ img, const float* __restrict__ w,
    bf16* __restrict__ cbuf, int n_base)
{
  __shared__ __align__(16) float in_s[15*224];  // input rows 2*r0 .. 2*r0+14
  __shared__ float w_s[32*58];                  // stride 58: 2-way-conflict reads
  const int band = blockIdx.x;                  // 0..21
  const int n = blockIdx.y;                     // 0..SUB-1 (cbuf-local)
  const int ng = n_base + n;                    // global patch for img
  const int r0 = band*5;                        // conv rows r0..r0+4
  const int ir0 = 2*r0;
  const int b = ng>>4, gh = (ng>>2)&3, gw = ng&3;
  const float* ibase = img + b*774400 + (gh*220)*880 + gw*220;

  for (int idx = threadIdx.x; idx < 15*56; idx += 256){
    int r = idx/56, cq = idx - r*56; int c = cq*4;
    int gr = ir0 + r;
    float4 v = (c < 220 && gr < 220) ? *(const float4*)(ibase + gr*880 + c)
                                     : make_float4(0.f,0.f,0.f,0.f);
    *(float4*)&in_s[r*224 + c] = v;
  }
  for (int idx = threadIdx.x; idx < 32*56; idx += 256){
    int oc = idx/56, k = idx - oc*56; int ky = k>>3, kx = k&7;
    w_s[oc*58 + k] = (kx < 7) ? w[oc*49 + ky*7 + kx] : 0.f;
  }
  __syncthreads();

  const int grp = threadIdx.x & 7;
  const int sp  = threadIdx.x >> 3;   // 0..31 col-group (cols 4sp..4sp+3)
  const int cgc = (sp < 26) ? sp : 26;
  const int nrows = (107 - r0 < 5) ? (107 - r0) : 5;

  float acc[5][4][4] = {};            // [row-item][oc][col]
  #pragma unroll 1
  for (int ky = 0; ky < 7; ky++){
    float wk[4][7];
    #pragma unroll
    for (int oc = 0; oc < 4; oc++)
      #pragma unroll
      for (int kx = 0; kx < 7; kx++)
        wk[oc][kx] = w_s[(grp*4+oc)*58 + ky*8 + kx];
    #pragma unroll
    for (int i = 0; i < 5; i++){
      if (i < nrows){
        const float* ip = &in_s[(2*i+ky)*224 + 8*cgc];
        float iv[13];
        *(float4*)&iv[0] = *(const float4*)ip;
        *(float4*)&iv[4] = *(const float4*)(ip+4);
        *(float4*)&iv[8] = *(const float4*)(ip+8);
        iv[12] = ip[12];
        #pragma unroll
        for (int oc = 0; oc < 4; oc++)
          #pragma unroll
          for (int kx = 0; kx < 7; kx++)
            #pragma unroll
            for (int j = 0; j < 4; j++)
              acc[i][oc][j] += iv[2*j+kx]*wk[oc][kx];
      }
    }
  }

  #pragma unroll
  for (int i = 0; i < 5; i++){
    if (i < nrows){
      int y = r0 + i;
      #pragma unroll
      for (int j = 0; j < 4; j++){
        int col = 4*sp + j;
        if (col < 107){
          union { unsigned short s[4]; uint2 u; } pk;
          #pragma unroll
          for (int oc = 0; oc < 4; oc++){
            bf16 hv = __float2bfloat16(fmaxf(acc[i][oc][j], 0.f));
            pk.s[oc] = *(unsigned short*)&hv;
          }
          *(uint2*)(cbuf + (((size_t)(n*8+grp)*107 + y)*107 + col)*4) = pk.u;
        }
      }
    }
  }
}

// ---------- K1b: separable 7x7 s1 p1 max-pool. cbuf -> pool1
//   layout: [n][q=4][103][103][8ch]; grp g -> plane q=g>>1, half h=g&1.
__global__ __launch_bounds__(256) void k1b_pool1(
    const bf16* __restrict__ cbuf, bf16* __restrict__ pool1, int n_pool_base)
{
  __shared__ uint2 in4[19*107];   // conv rows p0-1..p0+17 (clamped)
  __shared__ uint2 ht4[19*103];   // after horizontal 7-max
  const int s = blockIdx.x, g = blockIdx.y, n = blockIdx.z;
  const int p0 = s*13;
  const int PR = (103 - p0 < 13) ? (103 - p0) : 13;
  const int NR = PR + 6;
  const uint2* src = (const uint2*)cbuf + (size_t)(n*8+g)*107*107;

  for (int t = threadIdx.x; t < NR*107; t += 256){
    int r = t/107, c = t - r*107;
    int gr = p0 - 1 + r;
    gr = (gr < 0) ? 0 : ((gr > 106) ? 106 : gr);
    in4[t] = src[gr*107 + c];
  }
  __syncthreads();
  for (int t = threadIdx.x; t < NR*103; t += 256){
    int r = t/103, c = t - r*103;
    U4 m; m.v = in4[r*107 + ((c > 0) ? c-1 : 0)];
    #pragma unroll
    for (int d = 0; d < 6; d++){
      U4 v; v.v = in4[r*107 + ((c+d < 106) ? c+d : 106)];
      umax4(m, v);
    }
    ht4[r*103 + c] = m.v;
  }
  __syncthreads();
  uint2* dst = (uint2*)pool1;
  const size_t plane = ((size_t)(n_pool_base + n)*4 + (g>>1))*10609;
  const int h = g & 1;
  for (int t = threadIdx.x; t < PR*103; t += 256){
    int pr = t/103, c = t - pr*103;
    U4 m; m.v = ht4[pr*103 + c];
    #pragma unroll
    for (int d = 1; d < 7; d++){
      U4 v; v.v = ht4[(pr+d)*103 + c];
      umax4(m, v);
    }
    dst[(plane + (size_t)(p0+pr)*103 + c)*2 + h] = m.v;
  }
}

// ---------- K2: conv2 MFMA implicit GEMM, circular row staging.
// pool1 [CHUNK][4][103][103][8] -> conv2out NHWC [CHUNK,49,49,64]
// ky order {0,2,4,6,1,3,5}; 7-slot circular row buffer, slot=(yy+(ky>>1))%7.
__global__ __launch_bounds__(256) void k2_conv2(
    const bf16* __restrict__ pool1,
    const bf16* __restrict__ w2b,     // [49][64][32]
    bf16* __restrict__ conv2out)
{
  __shared__ __align__(16) bf16 in_s[7*2*52*36];   // 52416 B, 7 row-slots
  const int n = blockIdx.y, pb = blockIdx.x;       // pb 0..9
  const int wv = threadIdx.x >> 6, lane = threadIdx.x & 63;
  const int li = lane & 15, lg = lane >> 4;
  const int p0 = pb*256;
  const int y0 = p0/49;

  int pyv[4], pxv[4]; bool pmask[4];
  #pragma unroll
  for (int t = 0; t < 4; t++){
    int p = p0 + wv*64 + t*16 + li;
    pmask[t] = (p <= 2400);
    int pc = min(p, 2400);
    int yy = pc/49, xx = pc - yy*49;
    pyv[t] = yy; pxv[t] = xx;
  }
  floatx4 acc[4][4];
  #pragma unroll
  for (int a = 0; a < 4; a++)
    #pragma unroll
    for (int t = 0; t < 4; t++) acc[a][t] = (floatx4){0.f,0.f,0.f,0.f};

  const unsigned short* pbase = (const unsigned short*)pool1;

  // stage rows e0..e0+cnt-1 of parity par into circular slots (e % 7)
  auto stage_rows = [&](int e0, int cnt, int par){
    for (int idx = threadIdx.x; idx < cnt*103*4; idx += 256){
      int q = idx & 3; int t2 = idx >> 2; int ri = t2/103; int c = t2 - ri*103;
      int e = e0 + ri;
      int slot = e % 7;
      int gr = min(2*e + par, 102);
      *(int4*)&in_s[((slot*2 + (c&1))*52 + (c>>1))*36 + q*8] =
        *(const int4*)(pbase + (((size_t)n*4 + q)*10609 + (size_t)gr*103 + c)*8);
    }
  };

  const int kyseq[7] = {0,2,4,6,1,3,5};
  #pragma unroll 1
  for (int ks = 0; ks < 7; ks++){
    int ky = kyseq[ks];
    int kyh = ky >> 1, par = ky & 1;
    __syncthreads();               // previous compute done reading in_s
    if (ks == 0 || ks == 4) stage_rows(y0, 7, par);        // full restage
    else                    stage_rows(y0 + 6 + kyh, 1, par); // one new row
    __syncthreads();               // in_s ready
    int poff[4];
    #pragma unroll
    for (int t = 0; t < 4; t++){
      int e = pyv[t] + kyh;
      int slot = e % 7;
      poff[t] = (slot*2*52 + pxv[t])*36;
    }
    #pragma unroll
    for (int kx = 0; kx < 7; kx++){
      short8 a[4];
      const bf16* wp = w2b + (ky*7+kx)*64*32;
      #pragma unroll
      for (int ot = 0; ot < 4; ot++)
        a[ot] = *(const short8*)(wp + (ot*16 + li)*32 + lg*8);
      int koff = ((kx&1)*52 + (kx>>1))*36 + lg*8;
      #pragma unroll
      for (int t = 0; t < 4; t++){
        short8 bfr = *(const short8*)(&in_s[poff[t] + koff]);
        #pragma unroll
        for (int ot = 0; ot < 4; ot++)
          acc[ot][t] = __builtin_amdgcn_mfma_f32_16x16x32_bf16(a[ot], bfr, acc[ot][t], 0, 0, 0);
      }
    }
  }
  #pragma unroll
  for (int t = 0; t < 4; t++){
    if (!pmask[t]) continue;
    bf16* dst = conv2out + (((long)n*49 + pyv[t])*49 + pxv[t])*64 + lg*4;
    #pragma unroll
    for (int ot = 0; ot < 4; ot++){
      union { bf16 h[4]; uint2 u; } pk;
      #pragma unroll
      for (int v = 0; v < 4; v++)
        pk.h[v] = __float2bfloat16(fmaxf(acc[ot][t][v], 0.f));
      *(uint2*)(dst + ot*16) = pk.u;
    }
  }
}

// ---------- K3a: horizontal 7-max: conv2out [CHUNK,49,49,64] -> tmp [CHUNK,49,45,64]
__global__ __launch_bounds__(256) void k3a_hmax(
    const bf16* __restrict__ cin, bf16* __restrict__ tmp)
{
  int idx = blockIdx.x*256 + threadIdx.x;
  int cg = idx & 7; int t = idx >> 3; int x = t % 45; int t2 = t / 45;
  int y = t2 % 49; int n = t2 / 49;
  const int4* row = (const int4*)(cin + ((long)(n*49 + y)*49)*64) + cg;
  U8 m; m.v = make_int4(0,0,0,0);
  int lo = max(x-1, 0), hi = min(x+5, 48);
  for (int cx = lo; cx <= hi; cx++){ U8 v; v.v = row[cx*8]; umax8(m, v); }
  *((int4*)(tmp + ((long)(n*49 + y)*45 + x)*64) + cg) = m.v;
}

// ---------- K3b: vertical 7-max: tmp -> pool2 [256,45,45,64] at n_base
__global__ __launch_bounds__(256) void k3b_vmax(
    const bf16* __restrict__ tmp, bf16* __restrict__ pout, int n_base)
{
  int idx = blockIdx.x*256 + threadIdx.x;
  int cg = idx & 7; int t = idx >> 3; int x = t % 45; int t2 = t / 45;
  int y = t2 % 45; int n = t2 / 45;
  U8 m; m.v = make_int4(0,0,0,0);
  int lo = max(y-1, 0), hi = min(y+5, 48);
  for (int cy = lo; cy <= hi; cy++){
    U8 v; v.v = *((const int4*)(tmp + ((long)(n*49 + cy)*45 + x)*64) + cg);
    umax8(m, v);
  }
  *((int4*)(pout + (long)(n_base+n)*129600 + (y*45 + x)*64) + cg) = m.v;
}

// ---------- K4: conv3 MFMA implicit GEMM, direct LDS staging.
// pool2 NHWC -> conv3out NHWC [256,20,20,64]
__global__ __launch_bounds__(256) void k4_conv3(
    const bf16* __restrict__ pool2,
    const bf16* __restrict__ w3b,     // [ky][kc][kx][64][32]
    bf16* __restrict__ conv3out)
{
  __shared__ __align__(16) bf16 in_s[10*2*24*40];  // 38400 B -> 4 blocks/CU
  const int n = blockIdx.y, pb = blockIdx.x;       // pb 0..1
  const int wv = threadIdx.x >> 6, lane = threadIdx.x & 63;
  const int li = lane & 15, lg = lane >> 4;
  const int y0 = pb*10;

  int pyv[4], pxv[4], poff[4]; bool pmask[4];
  #pragma unroll
  for (int t = 0; t < 4; t++){
    int pl = wv*64 + t*16 + li;
    pmask[t] = (pl < 200);
    int p = pb*200 + min(pl, 199);
    int yy = p/20, xx = p - yy*20;
    pyv[t] = yy; pxv[t] = xx;
    poff[t] = ((yy - y0)*2*24 + xx)*40;
  }
  floatx4 acc[4][4];
  #pragma unroll
  for (int a = 0; a < 4; a++)
    #pragma unroll
    for (int t = 0; t < 4; t++) acc[a][t] = (floatx4){0.f,0.f,0.f,0.f};

  for (int ky = 0; ky < 7; ky++){
    for (int kc = 0; kc < 2; kc++){
      __syncthreads();
      for (int idx = threadIdx.x; idx < 10*45*4; idx += 256){
        int q = idx & 3; int t2 = idx >> 2; int c = t2 % 45; int r = t2/45;
        int gr = 2*(y0+r)+ky;
        const bf16* src = pool2 + (((long)n*45 + gr)*45 + c)*64 + kc*32 + q*8;
        bf16* dst = &in_s[((r*2 + (c&1))*24 + (c>>1))*40 + q*8];
        *(int4*)dst = *(const int4*)src;
      }
      __syncthreads();
      #pragma unroll
      for (int kx = 0; kx < 7; kx++){
        short8 a[4];
        const bf16* wp = w3b + ((ky*2+kc)*7 + kx)*64*32;
        #pragma unroll
        for (int ot = 0; ot < 4; ot++)
          a[ot] = *(const short8*)(wp + (ot*16 + li)*32 + lg*8);
        int koff = ((kx&1)*24 + (kx>>1))*40 + lg*8;
        #pragma unroll
        for (int t = 0; t < 4; t++){
          short8 bfr = *(const short8*)(&in_s[poff[t] + koff]);
          #pragma unroll
          for (int ot = 0; ot < 4; ot++)
            acc[ot][t] = __builtin_amdgcn_mfma_f32_16x16x32_bf16(a[ot], bfr, acc[ot][t], 0, 0, 0);
        }
      }
    }
  }
  #pragma unroll
  for (int t = 0; t < 4; t++){
    if (!pmask[t]) continue;
    bf16* dst = conv3out + (((long)n*20 + pyv[t])*20 + pxv[t])*64 + lg*4;
    #pragma unroll
    for (int ot = 0; ot < 4; ot++){
      union { bf16 h[4]; uint2 u; } pk;
      #pragma unroll
      for (int v = 0; v < 4; v++)
        pk.h[v] = __float2bfloat16(fmaxf(acc[ot][t][v], 0.f));
      *(uint2*)(dst + ot*16) = pk.u;
    }
  }
}

// ---------- K5: in-LDS separable pool3. conv3out [256,20,20,64] -> feat [256,16384]
__global__ __launch_bounds__(256) void k5_pool3(
    const bf16* __restrict__ cin, bf16* __restrict__ feat)
{
  __shared__ int4 in_p[3200];
  __shared__ int4 ht[2560];
  const int n = blockIdx.x;
  const int4* src = (const int4*)(cin + (long)n*25600);
  for (int i = threadIdx.x; i < 3200; i += 256) in_p[i] = src[i];
  __syncthreads();
  for (int i = threadIdx.x; i < 2560; i += 256){
    int cg = i & 7; int t = i >> 3; int x = t & 15; int y = t >> 4;
    U8 m; m.v = make_int4(0,0,0,0);
    int lo = max(x-1, 0), hi = min(x+5, 19);
    for (int cx = lo; cx <= hi; cx++){ U8 v; v.v = in_p[(y*20+cx)*8 + cg]; umax8(m, v); }
    ht[(y*16+x)*8 + cg] = m.v;
  }
  __syncthreads();
  unsigned short* dst = (unsigned short*)(feat + (long)n*16384);
  for (int i = threadIdx.x; i < 2048; i += 256){
    int px = i & 15; int py = (i >> 4) & 15; int cg = i >> 8;
    U8 m; m.v = make_int4(0,0,0,0);
    int lo = max(py-1, 0), hi = min(py+5, 19);
    for (int cy = lo; cy <= hi; cy++){ U8 v; v.v = ht[(cy*16+px)*8 + cg]; umax8(m, v); }
    #pragma unroll
    for (int j = 0; j < 8; j++)
      dst[(cg*8+j)*256 + py*16 + px] = m.s[j];
  }
}

// ---------- K6a: init x[272,512]
__global__ __launch_bounds__(256) void k6_init_x(
    const float* __restrict__ cls, const float* __restrict__ pos,
    const float* __restrict__ flat_b, float* __restrict__ x)
{
  int idx = blockIdx.x*256 + threadIdx.x;
  int d = idx & 511; int row = idx >> 9;
  int tt = row % 17;
  x[idx] = (tt == 0) ? (cls[d] + pos[d]) : (flat_b[d] + pos[tt*512 + d]);
}

// ---------- K6b: feat @ flat_w via MFMA (hi+lo bf16 W). atomicAdd into x.
__global__ __launch_bounds__(256) void k6_flat_mfma(
    const bf16* __restrict__ feat, const bf16* __restrict__ Whi,
    const bf16* __restrict__ Wlo, float* __restrict__ x)
{
  const int wv = threadIdx.x >> 6, lane = threadIdx.x & 63;
  const int li = lane & 15, lg = lane >> 4;
  const int m0 = blockIdx.x*64 + wv*16;     // wave's 16-row tile
  const int nb = blockIdx.y*64;             // block's 64 cols
  const int kb = blockIdx.z*2048;           // k-range
  floatx4 acc[4];
  #pragma unroll
  for (int t = 0; t < 4; t++) acc[t] = (floatx4){0.f,0.f,0.f,0.f};

  const bf16* arow = feat + (size_t)(m0+li)*16384 + kb + lg*8;
  for (int k0 = 0; k0 < 2048; k0 += 32){
    short8 a = *(const short8*)(arow + k0);
    size_t wo = ((size_t)((kb + k0) >> 3) + lg)*512 + nb + li;  // in 8-elt units
    const bf16* wh = Whi + wo*8;
    const bf16* wl = Wlo + wo*8;
    #pragma unroll
    for (int t = 0; t < 4; t++){
      short8 bh = *(const short8*)(wh + t*128);
      acc[t] = __builtin_amdgcn_mfma_f32_16x16x32_bf16(a, bh, acc[t], 0, 0, 0);
    }
    #pragma unroll
    for (int t = 0; t < 4; t++){
      short8 bl = *(const short8*)(wl + t*128);
      acc[t] = __builtin_amdgcn_mfma_f32_16x16x32_bf16(a, bl, acc[t], 0, 0, 0);
    }
  }
  #pragma unroll
  for (int t = 0; t < 4; t++){
    int col = nb + t*16 + li;
    #pragma unroll
    for (int v = 0; v < 4; v++){
      int m = m0 + lg*4 + v;
      int row = (m>>4)*17 + 1 + (m&15);
      atomicAdd(&x[row*512 + col], acc[t][v]);
    }
  }
}

// ---------- LayerNorm over 512, fp32 out (head path)
__global__ __launch_bounds__(256) void ln_kernel(
    const float* __restrict__ in, const float* __restrict__ g,
    const float* __restrict__ b, float* __restrict__ out,
    int in_stride, int out_stride)
{
  int row = blockIdx.x;
  const float* p = in + (long)row*in_stride;
  float v0 = p[threadIdx.x], v1 = p[threadIdx.x+256];
  __shared__ float red[4]; __shared__ float stat;
  float s = v0+v1;
  #pragma unroll
  for (int o = 32; o >= 1; o >>= 1) s += __shfl_down(s, o);
  int lane = threadIdx.x & 63, wv = threadIdx.x >> 6;
  if (lane == 0) red[wv] = s;
  __syncthreads();
  if (threadIdx.x == 0) stat = (red[0]+red[1]+red[2]+red[3])*(1.0f/512.0f);
  __syncthreads();
  float m = stat;
  float d0 = v0-m, d1 = v1-m;
  float q = d0*d0 + d1*d1;
  #pragma unroll
  for (int o = 32; o >= 1; o >>= 1) q += __shfl_down(q, o);
  __syncthreads();
  if (lane == 0) red[wv] = q;
  __syncthreads();
  if (threadIdx.x == 0) stat = rsqrtf((red[0]+red[1]+red[2]+red[3])*(1.0f/512.0f) + 1e-5f);
  __syncthreads();
  float rstd = stat;
  out[(long)row*out_stride + threadIdx.x]     = d0*rstd*g[threadIdx.x]     + b[threadIdx.x];
  out[(long)row*out_stride + threadIdx.x+256] = d1*rstd*g[threadIdx.x+256] + b[threadIdx.x+256];
}

// ---------- LayerNorm over 512, bf16 out (MFMA tail activations)
__global__ __launch_bounds__(256) void ln_bf16(
    const float* __restrict__ in, const float* __restrict__ g,
    const float* __restrict__ b, bf16* __restrict__ out)
{
  int row = blockIdx.x;
  const float* p = in + (long)row*512;
  float v0 = p[threadIdx.x], v1 = p[threadIdx.x+256];
  __shared__ float red[4]; __shared__ float stat;
  float s = v0+v1;
  #pragma unroll
  for (int o = 32; o >= 1; o >>= 1) s += __shfl_down(s, o);
  int lane = threadIdx.x & 63, wv = threadIdx.x >> 6;
  if (lane == 0) red[wv] = s;
  __syncthreads();
  if (threadIdx.x == 0) stat = (red[0]+red[1]+red[2]+red[3])*(1.0f/512.0f);
  __syncthreads();
  float m = stat;
  float d0 = v0-m, d1 = v1-m;
  float q = d0*d0 + d1*d1;
  #pragma unroll
  for (int o = 32; o >= 1; o >>= 1) q += __shfl_down(q, o);
  __syncthreads();
  if (lane == 0) red[wv] = q;
  __syncthreads();
  if (threadIdx.x == 0) stat = rsqrtf((red[0]+red[1]+red[2]+red[3])*(1.0f/512.0f) + 1e-5f);
  __syncthreads();
  float rstd = stat;
  out[(long)row*512 + threadIdx.x]     = __float2bfloat16(d0*rstd*g[threadIdx.x]     + b[threadIdx.x]);
  out[(long)row*512 + threadIdx.x+256] = __float2bfloat16(d1*rstd*g[threadIdx.x+256] + b[threadIdx.x+256]);
}

// ---------- MFMA tail GEMM: out = [res +] act(A@W + bias)
template<int NT>
__global__ __launch_bounds__(256) void tail_gemm(
    const bf16* __restrict__ A, const bf16* __restrict__ Wp,
    const float* __restrict__ bias, const float* res,
    float* outf, bf16* outb, int N, int K, int dogelu)
{
  const int wv = threadIdx.x >> 6, lane = threadIdx.x & 63;
  const int li = lane & 15, lg = lane >> 4;
  const int m0 = blockIdx.x * 16;
  const int nb = blockIdx.y * (64*NT) + wv * (16*NT);
  floatx4 acc[NT];
  #pragma unroll
  for (int t = 0; t < NT; t++) acc[t] = (floatx4){0.f,0.f,0.f,0.f};
  const bf16* arow = A + (size_t)(m0+li)*K + lg*8;
  for (int k0 = 0; k0 < K; k0 += 32){
    short8 a = *(const short8*)(arow + k0);
    const bf16* wrow = Wp + ((size_t)((k0>>3) + lg) * N + nb + li) * 8;
    #pragma unroll
    for (int t = 0; t < NT; t++){
      short8 bfr = *(const short8*)(wrow + t*128);
      acc[t] = __builtin_amdgcn_mfma_f32_16x16x32_bf16(a, bfr, acc[t], 0, 0, 0);
    }
  }
  #pragma unroll
  for (int t = 0; t < NT; t++){
    int col = nb + t*16 + li;
    #pragma unroll
    for (int v = 0; v < 4; v++){
      int row = m0 + lg*4 + v;
      float val = acc[t][v];
      if (bias) val += bias[col];
      if (dogelu) val = 0.5f*val*(1.0f + erff(val*0.70710678118654752f));
      if (res) val += res[(size_t)row*N + col];
      if (outf) outf[(size_t)row*N + col] = val;
      else      outb[(size_t)row*N + col] = __float2bfloat16(val);
    }
  }
}

// ---------- Generic small GEMM (head only): out = act(A@W + bias)
__global__ __launch_bounds__(256) void gemm_rows(
    const float* __restrict__ A, const float* __restrict__ W,
    const float* __restrict__ bias, const float* __restrict__ res,
    float* __restrict__ out, int M, int N, int K, int dogelu)
{
  __shared__ float A_s[16][33];
  __shared__ __align__(16) float W_s[32][68];
  const int m0 = blockIdx.x*16, n0 = blockIdx.y*64;
  const int r = threadIdx.x>>4, c0 = (threadIdx.x&15)*4;
  float acc[4] = {};
  for (int k0 = 0; k0 < K; k0 += 32){
    __syncthreads();
    for (int i = 0; i < 2; i++){ int id = threadIdx.x + i*256; int rr = id>>5, kk = id&31;
      A_s[rr][kk] = (m0+rr < M) ? A[(long)(m0+rr)*K + k0+kk] : 0.f; }
    for (int i = 0; i < 8; i++){ int id = threadIdx.x + i*256; int kk = id>>6, c = id&63;
      W_s[kk][c] = (n0+c < N) ? W[(long)(k0+kk)*N + n0+c] : 0.f; }
    __syncthreads();
    #pragma unroll
    for (int kk = 0; kk < 32; kk++){
      float a = A_s[r][kk];
      float4 w4 = *(const float4*)&W_s[kk][c0];
      acc[0]+=a*w4.x; acc[1]+=a*w4.y; acc[2]+=a*w4.z; acc[3]+=a*w4.w;
    }
  }
  if (m0+r < M){
    int row = m0+r;
    for (int j = 0; j < 4; j++){
      int c = n0+c0+j;
      if (c < N){
        float v = acc[j];
        if (bias) v += bias[c];
        if (dogelu) v = 0.5f*v*(1.0f + erff(v*0.70710678118654752f));
        if (res) v += res[(long)row*N + c];
        out[(long)row*N + c] = v;
      }
    }
  }
}

// ---------- Attention: one block per (b,h). N=17, DH=64. Writes bf16 O.
__global__ __launch_bounds__(128) void attn_kernel(
    const float* __restrict__ qkv, bf16* __restrict__ obuf)
{
  const int b = blockIdx.x >> 3, h = blockIdx.x & 7;
  __shared__ float q_s[17][65], k_s[17][65], v_s[17][65], s_s[17][18];
  for (int idx = threadIdx.x; idx < 17*64; idx += 128){
    int i = idx>>6, d = idx&63;
    const float* base = qkv + (long)(b*17+i)*1536 + h*64 + d;
    q_s[i][d] = base[0]; k_s[i][d] = base[512]; v_s[i][d] = base[1024];
  }
  __syncthreads();
  for (int idx = threadIdx.x; idx < 289; idx += 128){
    int i = idx/17, j = idx - i*17;
    float s = 0.f;
    for (int d = 0; d < 64; d++) s += q_s[i][d]*k_s[j][d];
    s_s[i][j] = s*0.125f;
  }
  __syncthreads();
  if (threadIdx.x < 17){
    int i = threadIdx.x;
    float m = -1e30f;
    for (int j = 0; j < 17; j++) m = fmaxf(m, s_s[i][j]);
    float sum = 0.f;
    for (int j = 0; j < 17; j++){ float e = expf(s_s[i][j]-m); s_s[i][j] = e; sum += e; }
    float inv = 1.0f/sum;
    for (int j = 0; j < 17; j++) s_s[i][j] *= inv;
  }
  __syncthreads();
  for (int idx = threadIdx.x; idx < 17*64; idx += 128){
    int i = idx>>6, d = idx&63;
    float o = 0.f;
    for (int j = 0; j < 17; j++) o += s_s[i][j]*v_s[j][d];
    obuf[(long)(b*17+i)*512 + h*64 + d] = __float2bfloat16(o);
  }
}

// ============================================================================
extern "C" void kernel_launch(void* const* d_in, const int* in_sizes, int n_in,
                              void* d_out, int out_size, void* d_ws, size_t ws_size,
                              hipStream_t stream) {
  const float* img      = (const float*)d_in[0];
  const float* conv1_w  = (const float*)d_in[1];
  const float* conv2_w  = (const float*)d_in[2];
  const float* conv3_w  = (const float*)d_in[3];
  const float* flat_w   = (const float*)d_in[4];
  const float* flat_b   = (const float*)d_in[5];
  const float* cls_tok  = (const float*)d_in[6];
  const float* pos_emb  = (const float*)d_in[7];
  const float* ln1_g    = (const float*)d_in[8];
  const float* ln1_b    = (const float*)d_in[9];
  const float* qkv_w    = (const float*)d_in[10];
  const float* out_w    = (const float*)d_in[11];
  const float* out_b    = (const float*)d_in[12];
  const float* ln2_g    = (const float*)d_in[13];
  const float* ln2_b    = (const float*)d_in[14];
  const float* ff1_w    = (const float*)d_in[15];
  const float* ff1_b    = (const float*)d_in[16];
  const float* ff2_w    = (const float*)d_in[17];
  const float* ff2_b    = (const float*)d_in[18];
  const float* hln_g    = (const float*)d_in[19];
  const float* hln_b    = (const float*)d_in[20];
  const float* head_w   = (const float*)d_in[21];
  const float* head_b   = (const float*)d_in[22];

  char* ws = (char*)d_ws;
  size_t off = 0;
  auto alloc = [&](size_t bytes) -> void* {
    void* p = ws + off; off += (bytes + 255) & ~(size_t)255; return p;
  };
  bf16* pool1    = (bf16*)alloc((size_t)CHUNK*8*103*103*4*2); // 43.5 MB (chunk, [n][4][103][103][8])
  bf16* conv2out = (bf16*)alloc((size_t)CHUNK*49*49*64*2);    // 19.7 MB (chunk, NHWC)
  bf16* pool2    = (bf16*)alloc((size_t)256*45*45*64*2);      // 66.4 MB (full, NHWC)
  bf16* feat     = (bf16*)alloc((size_t)256*16384*2);         //  8.4 MB
  bf16* w2b      = (bf16*)alloc((size_t)49*64*32*2);
  bf16* w3b      = (bf16*)alloc((size_t)49*2*64*32*2);
  float* x       = (float*)alloc((size_t)139264*4);           // 272x512 fp32
  bf16*  hb      = (bf16*)alloc((size_t)139264*2);            // 272x512 bf16 (LN out)
  float* qkvb    = (float*)alloc((size_t)417792*4);           // 272x1536 fp32
  bf16*  obufb   = (bf16*)alloc((size_t)139264*2);            // 272x512 bf16
  bf16*  ffbufb  = (bf16*)alloc((size_t)557056*2);            // 272x2048 bf16
  float* hcls    = (float*)alloc((size_t)8192*4);             // 16x512
  // pool1 region reuse (dead at the noted points):
  bf16* tmp3     = pool1;            // k3 horizontal tmp (within chunk loop)
  bf16* conv3out = pool1;            // k4 output (after chunk loop)
  // packed transformer weights alias pool1 AFTER k5 (pool1 fully dead):
  bf16* qkvp  = pool1;               //  9.44 MB
  bf16* outwp = qkvp  + (size_t)6*512*1536;   // 3.15 MB
  bf16* ff1p  = outwp + (size_t)6*512*512;    // 12.58 MB
  bf16* ff2p  = ff1p  + (size_t)6*512*2048;   // 12.58 MB  (total 37.75 <= 43.5)
  // flat_w hi/lo packs alias conv2out (hi) and pool2 (lo) — dead after k5.
  bf16* fwhi  = conv2out;
  bf16* fwlo  = pool2;

  // conv1 intermediate (k1a -> k1b), sized adaptively against ws_size.
  const size_t cb_per_n = (size_t)8*107*107*4*2;   // 733,136 B per patch
  int SUB; bf16* cbuf;
  if (ws_size >= off + 64*cb_per_n)      { SUB = 64; cbuf = (bf16*)alloc(64*cb_per_n); }
  else if (ws_size >= off + 32*cb_per_n) { SUB = 32; cbuf = (bf16*)alloc(32*cb_per_n); }
  else { SUB = 16; cbuf = conv2out; }  // dead-region fallback (see round 7)
  (void)in_sizes; (void)n_in; (void)out_size;

  prep_w2<<<392, 256, 0, stream>>>(conv2_w, w2b);
  prep_w3<<<784, 256, 0, stream>>>(conv3_w, w3b);

  for (int cb = 0; cb < 256; cb += CHUNK){
    for (int sb = 0; sb < CHUNK; sb += SUB){
      k1a_conv1<<<dim3(22, SUB), 256, 0, stream>>>(img, conv1_w, cbuf, cb + sb);
      k1b_pool1<<<dim3(8, 8, SUB), 256, 0, stream>>>(cbuf, pool1, sb);
    }
    k2_conv2     <<<dim3(10,CHUNK), 256, 0, stream>>>(pool1, w2b, conv2out);
    k3a_hmax     <<<(CHUNK*49*45*8)/256, 256, 0, stream>>>(conv2out, tmp3);
    k3b_vmax     <<<(CHUNK*45*45*8)/256, 256, 0, stream>>>(tmp3, pool2, cb);
  }
  k4_conv3<<<dim3(2,256), 256, 0, stream>>>(pool2, w3b, conv3out);
  k5_pool3<<<256, 256, 0, stream>>>(conv3out, feat);

  // packs into dead regions (pool1 / conv2out / pool2 all dead after k5)
  prep_pack_flat<<<4096, 256, 0, stream>>>(flat_w, fwhi, fwlo);
  prep_pack<<<(6*64*1536+255)/256, 256, 0, stream>>>(qkv_w, qkvp, 64, 1536, 6*64*1536);
  prep_pack<<<(6*64*512 +255)/256, 256, 0, stream>>>(out_w, outwp, 64, 512,  6*64*512);
  prep_pack<<<(6*64*2048+255)/256, 256, 0, stream>>>(ff1_w, ff1p, 64, 2048, 6*64*2048);
  prep_pack<<<(6*256*512+255)/256, 256, 0, stream>>>(ff2_w, ff2p, 256, 512, 6*256*512);

  k6_init_x    <<<544,         256, 0, stream>>>(cls_tok, pos_emb, flat_b, x);
  k6_flat_mfma <<<dim3(4,8,8), 256, 0, stream>>>(feat, fwhi, fwlo, x);

  for (int l = 0; l < 6; l++){
    ln_bf16<<<272, 256, 0, stream>>>(x, ln1_g + l*512, ln1_b + l*512, hb);
    tail_gemm<4><<<dim3(17,6), 256, 0, stream>>>(hb, qkvp + (size_t)l*786432,
                                                 nullptr, nullptr, qkvb, nullptr, 1536, 512, 0);
    attn_kernel<<<128, 128, 0, stream>>>(qkvb, obufb);
    tail_gemm<1><<<dim3(17,8), 256, 0, stream>>>(obufb, outwp + (size_t)l*262144,
                                                 out_b + l*512, x, x, nullptr, 512, 512, 0);
    ln_bf16<<<272, 256, 0, stream>>>(x, ln2_g + l*512, ln2_b + l*512, hb);
    tail_gemm<4><<<dim3(17,8), 256, 0, stream>>>(hb, ff1p + (size_t)l*1048576,
                                                 ff1_b + l*2048, nullptr, nullptr, ffbufb, 2048, 512, 1);
    tail_gemm<1><<<dim3(17,8), 256, 0, stream>>>(ffbufb, ff2p + (size_t)l*1048576,
                                                 ff2_b + l*512, x, x, nullptr, 512, 2048, 0);
  }

  ln_kernel<<<16, 256, 0, stream>>>(x, hln_g, hln_b, hcls, 17*512, 512);
  gemm_rows<<<dim3(1,16), 256, 0, stream>>>(hcls, head_w, head_b, nullptr,
                                            (float*)d_out, 16, 1000, 512, 0);
}

// Round 6
// 1577.938 us; speedup vs baseline: 1.2025x; 1.0131x over previous
//
#include <hip/hip_runtime.h>
#include <hip/hip_bf16.h>

// ============================================================================
// HybridViT forward. Round 12: k4 parity-ordered circular row staging.
//  - Round-11 state: k4 = 100.6us (top dispatch), MfmaUtil 20.5%, FETCH
//    147.6MB vs 66.4MB unique pool2 (2.2x): 140 row-stagings/block vs 50
//    distinct (stride-2 conv, same disease k2 had).
//  - This round: kc outer, ky order {0,2,4,6,1,3,5}; 10-slot circular row
//    buffer, slot = (yy + ky/2) % 10. Full 10-row stage only at ks=0/4 per
//    kc; other 5 phases stage ONE row (<1 item/thread, hidden under 112
//    MFMA). 50 row-stagings (minimum). LDS unchanged (38400B, 4 blk/CU),
//    same barrier count, same per-position values (fp32 reorder only).
//  - WRITE_SIZE (12.8MB) and VGPR (~76) are the spill canaries.
// Rest unchanged from round 11.
// ============================================================================

typedef __hip_bfloat16 bf16;
typedef __attribute__((ext_vector_type(8))) short short8;
typedef __attribute__((ext_vector_type(4))) float floatx4;

#define CHUNK 64

union U8 { int4 v; unsigned short s[8]; };
__device__ inline void umax8(U8& a, const U8& b){
  #pragma unroll
  for (int j = 0; j < 8; j++) a.s[j] = (a.s[j] > b.s[j]) ? a.s[j] : b.s[j];
}
union U4 { uint2 v; unsigned short s[4]; };
__device__ inline void umax4(U4& a, const U4& b){
  #pragma unroll
  for (int j = 0; j < 4; j++) a.s[j] = (a.s[j] > b.s[j]) ? a.s[j] : b.s[j];
}

// ---------- weight prep: conv2_w fp32 [64][32][7][7] -> bf16 [ky*7+kx][64][32]
__global__ __launch_bounds__(256) void prep_w2(const float* __restrict__ w,
                                               bf16* __restrict__ w2b)
{
  int idx = blockIdx.x*256 + threadIdx.x;     // 49*64*32 = 100352
  if (idx >= 49*64*32) return;
  int ic = idx & 31; int t = idx >> 5; int oc = t & 63; int kk = t >> 6;
  int ky = kk/7, kx = kk - ky*7;
  w2b[idx] = __float2bfloat16(w[((oc*32+ic)*7+ky)*7+kx]);
}

// ---------- weight prep: conv3_w fp32 [64][64][7][7] -> bf16 [ky][kc][kx][64][32]
__global__ __launch_bounds__(256) void prep_w3(const float* __restrict__ w,
                                               bf16* __restrict__ w3b)
{
  int idx = blockIdx.x*256 + threadIdx.x;     // 49*2*64*32 = 200704
  if (idx >= 49*2*64*32) return;
  int ic_l = idx & 31; int t = idx >> 5; int oc = t & 63; int t2 = t >> 6;
  int kx = t2 % 7; int t3 = t2 / 7; int kc = t3 & 1; int ky = t3 >> 1;
  w3b[idx] = __float2bfloat16(w[((oc*64 + kc*32 + ic_l)*7+ky)*7+kx]);
}

// ---------- transformer weight pack: fp32 [L][K][N] -> bf16 [L][K/8][N][8]
__global__ __launch_bounds__(256) void prep_pack(
    const float* __restrict__ src, bf16* __restrict__ dst,
    int K8, int N, int total)
{
  int idx = blockIdx.x*256 + threadIdx.x;
  if (idx >= total) return;
  int n = idx % N; int t = idx / N; int k8 = t % K8; int l = t / K8;
  const float* s = src + ((size_t)l*K8*8 + (size_t)k8*8)*N + n;
  union { bf16 h[8]; int4 v; } pk;
  #pragma unroll
  for (int j = 0; j < 8; j++) pk.h[j] = __float2bfloat16(s[(size_t)j*N]);
  *(int4*)(dst + (((size_t)l*K8 + k8)*N + n)*8) = pk.v;
}

// ---------- flat_w pack: fp32 [16384][512] -> hi/lo bf16 [2048][512][8]
__global__ __launch_bounds__(256) void prep_pack_flat(
    const float* __restrict__ src, bf16* __restrict__ hi, bf16* __restrict__ lo)
{
  int idx = blockIdx.x*256 + threadIdx.x;   // 2048*512 = 1048576
  if (idx >= 2048*512) return;
  int n = idx & 511; int k8 = idx >> 9;
  const float* s = src + (size_t)k8*8*512 + n;
  union { bf16 h[8]; int4 v; } ph, pl;
  #pragma unroll
  for (int j = 0; j < 8; j++){
    float w = s[(size_t)j*512];
    bf16 h = __float2bfloat16(w);
    ph.h[j] = h;
    pl.h[j] = __float2bfloat16(w - __bfloat162float(h));
  }
  size_t o = (size_t)idx*8;
  *(int4*)(hi + o) = ph.v;
  *(int4*)(lo + o) = pl.v;
}

// ---------- K1a: patchify + conv1(1->32,7x7,s2) + ReLU
//   -> cbuf [SUB][8grp][107][107][4ch] bf16
__global__ __launch_bounds__(256) void k1a_conv1(
    const float* __restrict__ img, const float* __restrict__ w,
    bf16* __restrict__ cbuf, int n_base)
{
  __shared__ __align__(16) float in_s[15*224];  // input rows 2*r0 .. 2*r0+14
  __shared__ float w_s[32*58];                  // stride 58: 2-way-conflict reads
  const int band = blockIdx.x;                  // 0..21
  const int n = blockIdx.y;                     // 0..SUB-1 (cbuf-local)
  const int ng = n_base + n;                    // global patch for img
  const int r0 = band*5;                        // conv rows r0..r0+4
  const int ir0 = 2*r0;
  const int b = ng>>4, gh = (ng>>2)&3, gw = ng&3;
  const float* ibase = img + b*774400 + (gh*220)*880 + gw*220;

  for (int idx = threadIdx.x; idx < 15*56; idx += 256){
    int r = idx/56, cq = idx - r*56; int c = cq*4;
    int gr = ir0 + r;
    float4 v = (c < 220 && gr < 220) ? *(const float4*)(ibase + gr*880 + c)
                                     : make_float4(0.f,0.f,0.f,0.f);
    *(float4*)&in_s[r*224 + c] = v;
  }
  for (int idx = threadIdx.x; idx < 32*56; idx += 256){
    int oc = idx/56, k = idx - oc*56; int ky = k>>3, kx = k&7;
    w_s[oc*58 + k] = (kx < 7) ? w[oc*49 + ky*7 + kx] : 0.f;
  }
  __syncthreads();

  const int grp = threadIdx.x & 7;
  const int sp  = threadIdx.x >> 3;   // 0..31 col-group (cols 4sp..4sp+3)
  const int cgc = (sp < 26) ? sp : 26;
  const int nrows = (107 - r0 < 5) ? (107 - r0) : 5;

  float acc[5][4][4] = {};            // [row-item][oc][col]
  #pragma unroll 1
  for (int ky = 0; ky < 7; ky++){
    float wk[4][7];
    #pragma unroll
    for (int oc = 0; oc < 4; oc++)
      #pragma unroll
      for (int kx = 0; kx < 7; kx++)
        wk[oc][kx] = w_s[(grp*4+oc)*58 + ky*8 + kx];
    #pragma unroll
    for (int i = 0; i < 5; i++){
      if (i < nrows){
        const float* ip = &in_s[(2*i+ky)*224 + 8*cgc];
        float iv[13];
        *(float4*)&iv[0] = *(const float4*)ip;
        *(float4*)&iv[4] = *(const float4*)(ip+4);
        *(float4*)&iv[8] = *(const float4*)(ip+8);
        iv[12] = ip[12];
        #pragma unroll
        for (int oc = 0; oc < 4; oc++)
          #pragma unroll
          for (int kx = 0; kx < 7; kx++)
            #pragma unroll
            for (int j = 0; j < 4; j++)
              acc[i][oc][j] += iv[2*j+kx]*wk[oc][kx];
      }
    }
  }

  #pragma unroll
  for (int i = 0; i < 5; i++){
    if (i < nrows){
      int y = r0 + i;
      #pragma unroll
      for (int j = 0; j < 4; j++){
        int col = 4*sp + j;
        if (col < 107){
          union { unsigned short s[4]; uint2 u; } pk;
          #pragma unroll
          for (int oc = 0; oc < 4; oc++){
            bf16 hv = __float2bfloat16(fmaxf(acc[i][oc][j], 0.f));
            pk.s[oc] = *(unsigned short*)&hv;
          }
          *(uint2*)(cbuf + (((size_t)(n*8+grp)*107 + y)*107 + col)*4) = pk.u;
        }
      }
    }
  }
}

// ---------- K1b: separable 7x7 s1 p1 max-pool. cbuf -> pool1
//   layout: [n][q=4][103][103][8ch]; grp g -> plane q=g>>1, half h=g&1.
__global__ __launch_bounds__(256) void k1b_pool1(
    const bf16* __restrict__ cbuf, bf16* __restrict__ pool1, int n_pool_base)
{
  __shared__ uint2 in4[19*107];   // conv rows p0-1..p0+17 (clamped)
  __shared__ uint2 ht4[19*103];   // after horizontal 7-max
  const int s = blockIdx.x, g = blockIdx.y, n = blockIdx.z;
  const int p0 = s*13;
  const int PR = (103 - p0 < 13) ? (103 - p0) : 13;
  const int NR = PR + 6;
  const uint2* src = (const uint2*)cbuf + (size_t)(n*8+g)*107*107;

  for (int t = threadIdx.x; t < NR*107; t += 256){
    int r = t/107, c = t - r*107;
    int gr = p0 - 1 + r;
    gr = (gr < 0) ? 0 : ((gr > 106) ? 106 : gr);
    in4[t] = src[gr*107 + c];
  }
  __syncthreads();
  for (int t = threadIdx.x; t < NR*103; t += 256){
    int r = t/103, c = t - r*103;
    U4 m; m.v = in4[r*107 + ((c > 0) ? c-1 : 0)];
    #pragma unroll
    for (int d = 0; d < 6; d++){
      U4 v; v.v = in4[r*107 + ((c+d < 106) ? c+d : 106)];
      umax4(m, v);
    }
    ht4[r*103 + c] = m.v;
  }
  __syncthreads();
  uint2* dst = (uint2*)pool1;
  const size_t plane = ((size_t)(n_pool_base + n)*4 + (g>>1))*10609;
  const int h = g & 1;
  for (int t = threadIdx.x; t < PR*103; t += 256){
    int pr = t/103, c = t - pr*103;
    U4 m; m.v = ht4[pr*103 + c];
    #pragma unroll
    for (int d = 1; d < 7; d++){
      U4 v; v.v = ht4[(pr+d)*103 + c];
      umax4(m, v);
    }
    dst[(plane + (size_t)(p0+pr)*103 + c)*2 + h] = m.v;
  }
}

// ---------- K2: conv2 MFMA implicit GEMM, circular row staging.
// pool1 [CHUNK][4][103][103][8] -> conv2out NHWC [CHUNK,49,49,64]
__global__ __launch_bounds__(256) void k2_conv2(
    const bf16* __restrict__ pool1,
    const bf16* __restrict__ w2b,     // [49][64][32]
    bf16* __restrict__ conv2out)
{
  __shared__ __align__(16) bf16 in_s[7*2*52*36];   // 52416 B, 7 row-slots
  const int n = blockIdx.y, pb = blockIdx.x;       // pb 0..9
  const int wv = threadIdx.x >> 6, lane = threadIdx.x & 63;
  const int li = lane & 15, lg = lane >> 4;
  const int p0 = pb*256;
  const int y0 = p0/49;

  int pyv[4], pxv[4]; bool pmask[4];
  #pragma unroll
  for (int t = 0; t < 4; t++){
    int p = p0 + wv*64 + t*16 + li;
    pmask[t] = (p <= 2400);
    int pc = min(p, 2400);
    int yy = pc/49, xx = pc - yy*49;
    pyv[t] = yy; pxv[t] = xx;
  }
  floatx4 acc[4][4];
  #pragma unroll
  for (int a = 0; a < 4; a++)
    #pragma unroll
    for (int t = 0; t < 4; t++) acc[a][t] = (floatx4){0.f,0.f,0.f,0.f};

  const unsigned short* pbase = (const unsigned short*)pool1;

  auto stage_rows = [&](int e0, int cnt, int par){
    for (int idx = threadIdx.x; idx < cnt*103*4; idx += 256){
      int q = idx & 3; int t2 = idx >> 2; int ri = t2/103; int c = t2 - ri*103;
      int e = e0 + ri;
      int slot = e % 7;
      int gr = min(2*e + par, 102);
      *(int4*)&in_s[((slot*2 + (c&1))*52 + (c>>1))*36 + q*8] =
        *(const int4*)(pbase + (((size_t)n*4 + q)*10609 + (size_t)gr*103 + c)*8);
    }
  };

  const int kyseq[7] = {0,2,4,6,1,3,5};
  #pragma unroll 1
  for (int ks = 0; ks < 7; ks++){
    int ky = kyseq[ks];
    int kyh = ky >> 1, par = ky & 1;
    __syncthreads();
    if (ks == 0 || ks == 4) stage_rows(y0, 7, par);
    else                    stage_rows(y0 + 6 + kyh, 1, par);
    __syncthreads();
    int poff[4];
    #pragma unroll
    for (int t = 0; t < 4; t++){
      int e = pyv[t] + kyh;
      int slot = e % 7;
      poff[t] = (slot*2*52 + pxv[t])*36;
    }
    #pragma unroll
    for (int kx = 0; kx < 7; kx++){
      short8 a[4];
      const bf16* wp = w2b + (ky*7+kx)*64*32;
      #pragma unroll
      for (int ot = 0; ot < 4; ot++)
        a[ot] = *(const short8*)(wp + (ot*16 + li)*32 + lg*8);
      int koff = ((kx&1)*52 + (kx>>1))*36 + lg*8;
      #pragma unroll
      for (int t = 0; t < 4; t++){
        short8 bfr = *(const short8*)(&in_s[poff[t] + koff]);
        #pragma unroll
        for (int ot = 0; ot < 4; ot++)
          acc[ot][t] = __builtin_amdgcn_mfma_f32_16x16x32_bf16(a[ot], bfr, acc[ot][t], 0, 0, 0);
      }
    }
  }
  #pragma unroll
  for (int t = 0; t < 4; t++){
    if (!pmask[t]) continue;
    bf16* dst = conv2out + (((long)n*49 + pyv[t])*49 + pxv[t])*64 + lg*4;
    #pragma unroll
    for (int ot = 0; ot < 4; ot++){
      union { bf16 h[4]; uint2 u; } pk;
      #pragma unroll
      for (int v = 0; v < 4; v++)
        pk.h[v] = __float2bfloat16(fmaxf(acc[ot][t][v], 0.f));
      *(uint2*)(dst + ot*16) = pk.u;
    }
  }
}

// ---------- K3a: horizontal 7-max: conv2out [CHUNK,49,49,64] -> tmp [CHUNK,49,45,64]
__global__ __launch_bounds__(256) void k3a_hmax(
    const bf16* __restrict__ cin, bf16* __restrict__ tmp)
{
  int idx = blockIdx.x*256 + threadIdx.x;
  int cg = idx & 7; int t = idx >> 3; int x = t % 45; int t2 = t / 45;
  int y = t2 % 49; int n = t2 / 49;
  const int4* row = (const int4*)(cin + ((long)(n*49 + y)*49)*64) + cg;
  U8 m; m.v = make_int4(0,0,0,0);
  int lo = max(x-1, 0), hi = min(x+5, 48);
  for (int cx = lo; cx <= hi; cx++){ U8 v; v.v = row[cx*8]; umax8(m, v); }
  *((int4*)(tmp + ((long)(n*49 + y)*45 + x)*64) + cg) = m.v;
}

// ---------- K3b: vertical 7-max: tmp -> pool2 [256,45,45,64] at n_base
__global__ __launch_bounds__(256) void k3b_vmax(
    const bf16* __restrict__ tmp, bf16* __restrict__ pout, int n_base)
{
  int idx = blockIdx.x*256 + threadIdx.x;
  int cg = idx & 7; int t = idx >> 3; int x = t % 45; int t2 = t / 45;
  int y = t2 % 45; int n = t2 / 45;
  U8 m; m.v = make_int4(0,0,0,0);
  int lo = max(y-1, 0), hi = min(y+5, 48);
  for (int cy = lo; cy <= hi; cy++){
    U8 v; v.v = *((const int4*)(tmp + ((long)(n*49 + cy)*45 + x)*64) + cg);
    umax8(m, v);
  }
  *((int4*)(pout + (long)(n_base+n)*129600 + (y*45 + x)*64) + cg) = m.v;
}

// ---------- K4: conv3 MFMA implicit GEMM, circular row staging.
// pool2 NHWC -> conv3out NHWC [256,20,20,64]
// kc outer; ky order {0,2,4,6,1,3,5}; 10-slot circular row buffer,
// slot = (yy + ky/2) % 10. 50 row-stagings/block (was 140).
__global__ __launch_bounds__(256) void k4_conv3(
    const bf16* __restrict__ pool2,
    const bf16* __restrict__ w3b,     // [ky][kc][kx][64][32]
    bf16* __restrict__ conv3out)
{
  __shared__ __align__(16) bf16 in_s[10*2*24*40];  // 38400 B, 10 row-slots
  const int n = blockIdx.y, pb = blockIdx.x;       // pb 0..1
  const int wv = threadIdx.x >> 6, lane = threadIdx.x & 63;
  const int li = lane & 15, lg = lane >> 4;
  const int y0 = pb*10;

  int pyv[4], pxv[4]; bool pmask[4];
  #pragma unroll
  for (int t = 0; t < 4; t++){
    int pl = wv*64 + t*16 + li;
    pmask[t] = (pl < 200);
    int p = pb*200 + min(pl, 199);
    int yy = p/20, xx = p - yy*20;
    pyv[t] = yy; pxv[t] = xx;
  }
  floatx4 acc[4][4];
  #pragma unroll
  for (int a = 0; a < 4; a++)
    #pragma unroll
    for (int t = 0; t < 4; t++) acc[a][t] = (floatx4){0.f,0.f,0.f,0.f};

  // stage rows e0..e0+cnt-1 (e-space: gr = 2e+par) of channel-half kc
  auto stage_rows = [&](int e0, int cnt, int par, int kc){
    for (int idx = threadIdx.x; idx < cnt*45*4; idx += 256){
      int q = idx & 3; int t2 = idx >> 2; int ri = t2/45; int c = t2 - ri*45;
      int e = e0 + ri;
      int slot = e % 10;
      int gr = 2*e + par;
      *(int4*)&in_s[((slot*2 + (c&1))*24 + (c>>1))*40 + q*8] =
        *(const int4*)(pool2 + (((long)n*45 + gr)*45 + c)*64 + kc*32 + q*8);
    }
  };

  const int kyseq[7] = {0,2,4,6,1,3,5};
  #pragma unroll 1
  for (int kc = 0; kc < 2; kc++){
    #pragma unroll 1
    for (int ks = 0; ks < 7; ks++){
      int ky = kyseq[ks];
      int kyh = ky >> 1, par = ky & 1;
      __syncthreads();               // previous compute done reading in_s
      if (ks == 0 || ks == 4) stage_rows(y0 + kyh, 10, par, kc);   // kyh==0 here
      else                    stage_rows(y0 + 9 + kyh, 1, par, kc);
      __syncthreads();               // in_s ready
      int poff[4];
      #pragma unroll
      for (int t = 0; t < 4; t++){
        int e = pyv[t] + kyh;
        int slot = e % 10;
        poff[t] = (slot*2*24 + pxv[t])*40;
      }
      #pragma unroll
      for (int kx = 0; kx < 7; kx++){
        short8 a[4];
        const bf16* wp = w3b + ((ky*2+kc)*7 + kx)*64*32;
        #pragma unroll
        for (int ot = 0; ot < 4; ot++)
          a[ot] = *(const short8*)(wp + (ot*16 + li)*32 + lg*8);
        int koff = ((kx&1)*24 + (kx>>1))*40 + lg*8;
        #pragma unroll
        for (int t = 0; t < 4; t++){
          short8 bfr = *(const short8*)(&in_s[poff[t] + koff]);
          #pragma unroll
          for (int ot = 0; ot < 4; ot++)
            acc[ot][t] = __builtin_amdgcn_mfma_f32_16x16x32_bf16(a[ot], bfr, acc[ot][t], 0, 0, 0);
        }
      }
    }
  }
  #pragma unroll
  for (int t = 0; t < 4; t++){
    if (!pmask[t]) continue;
    bf16* dst = conv3out + (((long)n*20 + pyv[t])*20 + pxv[t])*64 + lg*4;
    #pragma unroll
    for (int ot = 0; ot < 4; ot++){
      union { bf16 h[4]; uint2 u; } pk;
      #pragma unroll
      for (int v = 0; v < 4; v++)
        pk.h[v] = __float2bfloat16(fmaxf(acc[ot][t][v], 0.f));
      *(uint2*)(dst + ot*16) = pk.u;
    }
  }
}

// ---------- K5: in-LDS separable pool3. conv3out [256,20,20,64] -> feat [256,16384]
__global__ __launch_bounds__(256) void k5_pool3(
    const bf16* __restrict__ cin, bf16* __restrict__ feat)
{
  __shared__ int4 in_p[3200];
  __shared__ int4 ht[2560];
  const int n = blockIdx.x;
  const int4* src = (const int4*)(cin + (long)n*25600);
  for (int i = threadIdx.x; i < 3200; i += 256) in_p[i] = src[i];
  __syncthreads();
  for (int i = threadIdx.x; i < 2560; i += 256){
    int cg = i & 7; int t = i >> 3; int x = t & 15; int y = t >> 4;
    U8 m; m.v = make_int4(0,0,0,0);
    int lo = max(x-1, 0), hi = min(x+5, 19);
    for (int cx = lo; cx <= hi; cx++){ U8 v; v.v = in_p[(y*20+cx)*8 + cg]; umax8(m, v); }
    ht[(y*16+x)*8 + cg] = m.v;
  }
  __syncthreads();
  unsigned short* dst = (unsigned short*)(feat + (long)n*16384);
  for (int i = threadIdx.x; i < 2048; i += 256){
    int px = i & 15; int py = (i >> 4) & 15; int cg = i >> 8;
    U8 m; m.v = make_int4(0,0,0,0);
    int lo = max(py-1, 0), hi = min(py+5, 19);
    for (int cy = lo; cy <= hi; cy++){ U8 v; v.v = ht[(cy*16+px)*8 + cg]; umax8(m, v); }
    #pragma unroll
    for (int j = 0; j < 8; j++)
      dst[(cg*8+j)*256 + py*16 + px] = m.s[j];
  }
}

// ---------- K6a: init x[272,512]
__global__ __launch_bounds__(256) void k6_init_x(
    const float* __restrict__ cls, const float* __restrict__ pos,
    const float* __restrict__ flat_b, float* __restrict__ x)
{
  int idx = blockIdx.x*256 + threadIdx.x;
  int d = idx & 511; int row = idx >> 9;
  int tt = row % 17;
  x[idx] = (tt == 0) ? (cls[d] + pos[d]) : (flat_b[d] + pos[tt*512 + d]);
}

// ---------- K6b: feat @ flat_w via MFMA (hi+lo bf16 W). atomicAdd into x.
__global__ __launch_bounds__(256) void k6_flat_mfma(
    const bf16* __restrict__ feat, const bf16* __restrict__ Whi,
    const bf16* __restrict__ Wlo, float* __restrict__ x)
{
  const int wv = threadIdx.x >> 6, lane = threadIdx.x & 63;
  const int li = lane & 15, lg = lane >> 4;
  const int m0 = blockIdx.x*64 + wv*16;     // wave's 16-row tile
  const int nb = blockIdx.y*64;             // block's 64 cols
  const int kb = blockIdx.z*2048;           // k-range
  floatx4 acc[4];
  #pragma unroll
  for (int t = 0; t < 4; t++) acc[t] = (floatx4){0.f,0.f,0.f,0.f};

  const bf16* arow = feat + (size_t)(m0+li)*16384 + kb + lg*8;
  for (int k0 = 0; k0 < 2048; k0 += 32){
    short8 a = *(const short8*)(arow + k0);
    size_t wo = ((size_t)((kb + k0) >> 3) + lg)*512 + nb + li;  // in 8-elt units
    const bf16* wh = Whi + wo*8;
    const bf16* wl = Wlo + wo*8;
    #pragma unroll
    for (int t = 0; t < 4; t++){
      short8 bh = *(const short8*)(wh + t*128);
      acc[t] = __builtin_amdgcn_mfma_f32_16x16x32_bf16(a, bh, acc[t], 0, 0, 0);
    }
    #pragma unroll
    for (int t = 0; t < 4; t++){
      short8 bl = *(const short8*)(wl + t*128);
      acc[t] = __builtin_amdgcn_mfma_f32_16x16x32_bf16(a, bl, acc[t], 0, 0, 0);
    }
  }
  #pragma unroll
  for (int t = 0; t < 4; t++){
    int col = nb + t*16 + li;
    #pragma unroll
    for (int v = 0; v < 4; v++){
      int m = m0 + lg*4 + v;
      int row = (m>>4)*17 + 1 + (m&15);
      atomicAdd(&x[row*512 + col], acc[t][v]);
    }
  }
}

// ---------- LayerNorm over 512, fp32 out (head path)
__global__ __launch_bounds__(256) void ln_kernel(
    const float* __restrict__ in, const float* __restrict__ g,
    const float* __restrict__ b, float* __restrict__ out,
    int in_stride, int out_stride)
{
  int row = blockIdx.x;
  const float* p = in + (long)row*in_stride;
  float v0 = p[threadIdx.x], v1 = p[threadIdx.x+256];
  __shared__ float red[4]; __shared__ float stat;
  float s = v0+v1;
  #pragma unroll
  for (int o = 32; o >= 1; o >>= 1) s += __shfl_down(s, o);
  int lane = threadIdx.x & 63, wv = threadIdx.x >> 6;
  if (lane == 0) red[wv] = s;
  __syncthreads();
  if (threadIdx.x == 0) stat = (red[0]+red[1]+red[2]+red[3])*(1.0f/512.0f);
  __syncthreads();
  float m = stat;
  float d0 = v0-m, d1 = v1-m;
  float q = d0*d0 + d1*d1;
  #pragma unroll
  for (int o = 32; o >= 1; o >>= 1) q += __shfl_down(q, o);
  __syncthreads();
  if (lane == 0) red[wv] = q;
  __syncthreads();
  if (threadIdx.x == 0) stat = rsqrtf((red[0]+red[1]+red[2]+red[3])*(1.0f/512.0f) + 1e-5f);
  __syncthreads();
  float rstd = stat;
  out[(long)row*out_stride + threadIdx.x]     = d0*rstd*g[threadIdx.x]     + b[threadIdx.x];
  out[(long)row*out_stride + threadIdx.x+256] = d1*rstd*g[threadIdx.x+256] + b[threadIdx.x+256];
}

// ---------- LayerNorm over 512, bf16 out (MFMA tail activations)
__global__ __launch_bounds__(256) void ln_bf16(
    const float* __restrict__ in, const float* __restrict__ g,
    const float* __restrict__ b, bf16* __restrict__ out)
{
  int row = blockIdx.x;
  const float* p = in + (long)row*512;
  float v0 = p[threadIdx.x], v1 = p[threadIdx.x+256];
  __shared__ float red[4]; __shared__ float stat;
  float s = v0+v1;
  #pragma unroll
  for (int o = 32; o >= 1; o >>= 1) s += __shfl_down(s, o);
  int lane = threadIdx.x & 63, wv = threadIdx.x >> 6;
  if (lane == 0) red[wv] = s;
  __syncthreads();
  if (threadIdx.x == 0) stat = (red[0]+red[1]+red[2]+red[3])*(1.0f/512.0f);
  __syncthreads();
  float m = stat;
  float d0 = v0-m, d1 = v1-m;
  float q = d0*d0 + d1*d1;
  #pragma unroll
  for (int o = 32; o >= 1; o >>= 1) q += __shfl_down(q, o);
  __syncthreads();
  if (lane == 0) red[wv] = q;
  __syncthreads();
  if (threadIdx.x == 0) stat = rsqrtf((red[0]+red[1]+red[2]+red[3])*(1.0f/512.0f) + 1e-5f);
  __syncthreads();
  float rstd = stat;
  out[(long)row*512 + threadIdx.x]     = __float2bfloat16(d0*rstd*g[threadIdx.x]     + b[threadIdx.x]);
  out[(long)row*512 + threadIdx.x+256] = __float2bfloat16(d1*rstd*g[threadIdx.x+256] + b[threadIdx.x+256]);
}

// ---------- MFMA tail GEMM: out = [res +] act(A@W + bias)
template<int NT>
__global__ __launch_bounds__(256) void tail_gemm(
    const bf16* __restrict__ A, const bf16* __restrict__ Wp,
    const float* __restrict__ bias, const float* res,
    float* outf, bf16* outb, int N, int K, int dogelu)
{
  const int wv = threadIdx.x >> 6, lane = threadIdx.x & 63;
  const int li = lane & 15, lg = lane >> 4;
  const int m0 = blockIdx.x * 16;
  const int nb = blockIdx.y * (64*NT) + wv * (16*NT);
  floatx4 acc[NT];
  #pragma unroll
  for (int t = 0; t < NT; t++) acc[t] = (floatx4){0.f,0.f,0.f,0.f};
  const bf16* arow = A + (size_t)(m0+li)*K + lg*8;
  for (int k0 = 0; k0 < K; k0 += 32){
    short8 a = *(const short8*)(arow + k0);
    const bf16* wrow = Wp + ((size_t)((k0>>3) + lg) * N + nb + li) * 8;
    #pragma unroll
    for (int t = 0; t < NT; t++){
      short8 bfr = *(const short8*)(wrow + t*128);
      acc[t] = __builtin_amdgcn_mfma_f32_16x16x32_bf16(a, bfr, acc[t], 0, 0, 0);
    }
  }
  #pragma unroll
  for (int t = 0; t < NT; t++){
    int col = nb + t*16 + li;
    #pragma unroll
    for (int v = 0; v < 4; v++){
      int row = m0 + lg*4 + v;
      float val = acc[t][v];
      if (bias) val += bias[col];
      if (dogelu) val = 0.5f*val*(1.0f + erff(val*0.70710678118654752f));
      if (res) val += res[(size_t)row*N + col];
      if (outf) outf[(size_t)row*N + col] = val;
      else      outb[(size_t)row*N + col] = __float2bfloat16(val);
    }
  }
}

// ---------- Generic small GEMM (head only): out = act(A@W + bias)
__global__ __launch_bounds__(256) void gemm_rows(
    const float* __restrict__ A, const float* __restrict__ W,
    const float* __restrict__ bias, const float* __restrict__ res,
    float* __restrict__ out, int M, int N, int K, int dogelu)
{
  __shared__ float A_s[16][33];
  __shared__ __align__(16) float W_s[32][68];
  const int m0 = blockIdx.x*16, n0 = blockIdx.y*64;
  const int r = threadIdx.x>>4, c0 = (threadIdx.x&15)*4;
  float acc[4] = {};
  for (int k0 = 0; k0 < K; k0 += 32){
    __syncthreads();
    for (int i = 0; i < 2; i++){ int id = threadIdx.x + i*256; int rr = id>>5, kk = id&31;
      A_s[rr][kk] = (m0+rr < M) ? A[(long)(m0+rr)*K + k0+kk] : 0.f; }
    for (int i = 0; i < 8; i++){ int id = threadIdx.x + i*256; int kk = id>>6, c = id&63;
      W_s[kk][c] = (n0+c < N) ? W[(long)(k0+kk)*N + n0+c] : 0.f; }
    __syncthreads();
    #pragma unroll
    for (int kk = 0; kk < 32; kk++){
      float a = A_s[r][kk];
      float4 w4 = *(const float4*)&W_s[kk][c0];
      acc[0]+=a*w4.x; acc[1]+=a*w4.y; acc[2]+=a*w4.z; acc[3]+=a*w4.w;
    }
  }
  if (m0+r < M){
    int row = m0+r;
    for (int j = 0; j < 4; j++){
      int c = n0+c0+j;
      if (c < N){
        float v = acc[j];
        if (bias) v += bias[c];
        if (dogelu) v = 0.5f*v*(1.0f + erff(v*0.70710678118654752f));
        if (res) v += res[(long)row*N + c];
        out[(long)row*N + c] = v;
      }
    }
  }
}

// ---------- Attention: one block per (b,h). N=17, DH=64. Writes bf16 O.
__global__ __launch_bounds__(128) void attn_kernel(
    const float* __restrict__ qkv, bf16* __restrict__ obuf)
{
  const int b = blockIdx.x >> 3, h = blockIdx.x & 7;
  __shared__ float q_s[17][65], k_s[17][65], v_s[17][65], s_s[17][18];
  for (int idx = threadIdx.x; idx < 17*64; idx += 128){
    int i = idx>>6, d = idx&63;
    const float* base = qkv + (long)(b*17+i)*1536 + h*64 + d;
    q_s[i][d] = base[0]; k_s[i][d] = base[512]; v_s[i][d] = base[1024];
  }
  __syncthreads();
  for (int idx = threadIdx.x; idx < 289; idx += 128){
    int i = idx/17, j = idx - i*17;
    float s = 0.f;
    for (int d = 0; d < 64; d++) s += q_s[i][d]*k_s[j][d];
    s_s[i][j] = s*0.125f;
  }
  __syncthreads();
  if (threadIdx.x < 17){
    int i = threadIdx.x;
    float m = -1e30f;
    for (int j = 0; j < 17; j++) m = fmaxf(m, s_s[i][j]);
    float sum = 0.f;
    for (int j = 0; j < 17; j++){ float e = expf(s_s[i][j]-m); s_s[i][j] = e; sum += e; }
    float inv = 1.0f/sum;
    for (int j = 0; j < 17; j++) s_s[i][j] *= inv;
  }
  __syncthreads();
  for (int idx = threadIdx.x; idx < 17*64; idx += 128){
    int i = idx>>6, d = idx&63;
    float o = 0.f;
    for (int j = 0; j < 17; j++) o += s_s[i][j]*v_s[j][d];
    obuf[(long)(b*17+i)*512 + h*64 + d] = __float2bfloat16(o);
  }
}

// ============================================================================
extern "C" void kernel_launch(void* const* d_in, const int* in_sizes, int n_in,
                              void* d_out, int out_size, void* d_ws, size_t ws_size,
                              hipStream_t stream) {
  const float* img      = (const float*)d_in[0];
  const float* conv1_w  = (const float*)d_in[1];
  const float* conv2_w  = (const float*)d_in[2];
  const float* conv3_w  = (const float*)d_in[3];
  const float* flat_w   = (const float*)d_in[4];
  const float* flat_b   = (const float*)d_in[5];
  const float* cls_tok  = (const float*)d_in[6];
  const float* pos_emb  = (const float*)d_in[7];
  const float* ln1_g    = (const float*)d_in[8];
  const float* ln1_b    = (const float*)d_in[9];
  const float* qkv_w    = (const float*)d_in[10];
  const float* out_w    = (const float*)d_in[11];
  const float* out_b    = (const float*)d_in[12];
  const float* ln2_g    = (const float*)d_in[13];
  const float* ln2_b    = (const float*)d_in[14];
  const float* ff1_w    = (const float*)d_in[15];
  const float* ff1_b    = (const float*)d_in[16];
  const float* ff2_w    = (const float*)d_in[17];
  const float* ff2_b    = (const float*)d_in[18];
  const float* hln_g    = (const float*)d_in[19];
  const float* hln_b    = (const float*)d_in[20];
  const float* head_w   = (const float*)d_in[21];
  const float* head_b   = (const float*)d_in[22];

  char* ws = (char*)d_ws;
  size_t off = 0;
  auto alloc = [&](size_t bytes) -> void* {
    void* p = ws + off; off += (bytes + 255) & ~(size_t)255; return p;
  };
  bf16* pool1    = (bf16*)alloc((size_t)CHUNK*8*103*103*4*2); // 43.5 MB (chunk, [n][4][103][103][8])
  bf16* conv2out = (bf16*)alloc((size_t)CHUNK*49*49*64*2);    // 19.7 MB (chunk, NHWC)
  bf16* pool2    = (bf16*)alloc((size_t)256*45*45*64*2);      // 66.4 MB (full, NHWC)
  bf16* feat     = (bf16*)alloc((size_t)256*16384*2);         //  8.4 MB
  bf16* w2b      = (bf16*)alloc((size_t)49*64*32*2);
  bf16* w3b      = (bf16*)alloc((size_t)49*2*64*32*2);
  float* x       = (float*)alloc((size_t)139264*4);           // 272x512 fp32
  bf16*  hb      = (bf16*)alloc((size_t)139264*2);            // 272x512 bf16 (LN out)
  float* qkvb    = (float*)alloc((size_t)417792*4);           // 272x1536 fp32
  bf16*  obufb   = (bf16*)alloc((size_t)139264*2);            // 272x512 bf16
  bf16*  ffbufb  = (bf16*)alloc((size_t)557056*2);            // 272x2048 bf16
  float* hcls    = (float*)alloc((size_t)8192*4);             // 16x512
  // pool1 region reuse (dead at the noted points):
  bf16* tmp3     = pool1;            // k3 horizontal tmp (within chunk loop)
  bf16* conv3out = pool1;            // k4 output (after chunk loop)
  // packed transformer weights alias pool1 AFTER k5 (pool1 fully dead):
  bf16* qkvp  = pool1;               //  9.44 MB
  bf16* outwp = qkvp  + (size_t)6*512*1536;   // 3.15 MB
  bf16* ff1p  = outwp + (size_t)6*512*512;    // 12.58 MB
  bf16* ff2p  = ff1p  + (size_t)6*512*2048;   // 12.58 MB  (total 37.75 <= 43.5)
  // flat_w hi/lo packs alias conv2out (hi) and pool2 (lo) — dead after k5.
  bf16* fwhi  = conv2out;
  bf16* fwlo  = pool2;

  // conv1 intermediate (k1a -> k1b), sized adaptively against ws_size.
  const size_t cb_per_n = (size_t)8*107*107*4*2;   // 733,136 B per patch
  int SUB; bf16* cbuf;
  if (ws_size >= off + 64*cb_per_n)      { SUB = 64; cbuf = (bf16*)alloc(64*cb_per_n); }
  else if (ws_size >= off + 32*cb_per_n) { SUB = 32; cbuf = (bf16*)alloc(32*cb_per_n); }
  else { SUB = 16; cbuf = conv2out; }  // dead-region fallback (see round 7)
  (void)in_sizes; (void)n_in; (void)out_size;

  prep_w2<<<392, 256, 0, stream>>>(conv2_w, w2b);
  prep_w3<<<784, 256, 0, stream>>>(conv3_w, w3b);

  for (int cb = 0; cb < 256; cb += CHUNK){
    for (int sb = 0; sb < CHUNK; sb += SUB){
      k1a_conv1<<<dim3(22, SUB), 256, 0, stream>>>(img, conv1_w, cbuf, cb + sb);
      k1b_pool1<<<dim3(8, 8, SUB), 256, 0, stream>>>(cbuf, pool1, sb);
    }
    k2_conv2     <<<dim3(10,CHUNK), 256, 0, stream>>>(pool1, w2b, conv2out);
    k3a_hmax     <<<(CHUNK*49*45*8)/256, 256, 0, stream>>>(conv2out, tmp3);
    k3b_vmax     <<<(CHUNK*45*45*8)/256, 256, 0, stream>>>(tmp3, pool2, cb);
  }
  k4_conv3<<<dim3(2,256), 256, 0, stream>>>(pool2, w3b, conv3out);
  k5_pool3<<<256, 256, 0, stream>>>(conv3out, feat);

  // packs into dead regions (pool1 / conv2out / pool2 all dead after k5)
  prep_pack_flat<<<4096, 256, 0, stream>>>(flat_w, fwhi, fwlo);
  prep_pack<<<(6*64*1536+255)/256, 256, 0, stream>>>(qkv_w, qkvp, 64, 1536, 6*64*1536);
  prep_pack<<<(6*64*512 +255)/256, 256, 0, stream>>>(out_w, outwp, 64, 512,  6*64*512);
  prep_pack<<<(6*64*2048+255)/256, 256, 0, stream>>>(ff1_w, ff1p, 64, 2048, 6*64*2048);
  prep_pack<<<(6*256*512+255)/256, 256, 0, stream>>>(ff2_w, ff2p, 256, 512, 6*256*512);

  k6_init_x    <<<544,         256, 0, stream>>>(cls_tok, pos_emb, flat_b, x);
  k6_flat_mfma <<<dim3(4,8,8), 256, 0, stream>>>(feat, fwhi, fwlo, x);

  for (int l = 0; l < 6; l++){
    ln_bf16<<<272, 256, 0, stream>>>(x, ln1_g + l*512, ln1_b + l*512, hb);
    tail_gemm<4><<<dim3(17,6), 256, 0, stream>>>(hb, qkvp + (size_t)l*786432,
                                                 nullptr, nullptr, qkvb, nullptr, 1536, 512, 0);
    attn_kernel<<<128, 128, 0, stream>>>(qkvb, obufb);
    tail_gemm<1><<<dim3(17,8), 256, 0, stream>>>(obufb, outwp + (size_t)l*262144,
                                                 out_b + l*512, x, x, nullptr, 512, 512, 0);
    ln_bf16<<<272, 256, 0, stream>>>(x, ln2_g + l*512, ln2_b + l*512, hb);
    tail_gemm<4><<<dim3(17,8), 256, 0, stream>>>(hb, ff1p + (size_t)l*1048576,
                                                 ff1_b + l*2048, nullptr, nullptr, ffbufb, 2048, 512, 1);
    tail_gemm<1><<<dim3(17,8), 256, 0, stream>>>(ffbufb, ff2p + (size_t)l*1048576,
                                                 ff2_b + l*512, x, x, nullptr, 512, 2048, 0);
  }

  ln_kernel<<<16, 256, 0, stream>>>(x, hln_g, hln_b, hcls, 17*512, 512);
  gemm_rows<<<dim3(1,16), 256, 0, stream>>>(hcls, head_w, head_b, nullptr,
                                            (float*)d_out, 16, 1000, 512, 0);
}

// Round 7
// 1547.810 us; speedup vs baseline: 1.2259x; 1.0195x over previous
//
#include <hip/hip_runtime.h>
#include <hip/hip_bf16.h>

// ============================================================================
// HybridViT forward. Round 13: k6_flat_mfma occupancy + load-balance fix.
//  - Round-12 state: k6_flat_mfma top dispatch, 82us, MfmaUtil 3.7%,
//    Occupancy 10% (grid 256 blocks = 1 blk/CU = 1 wave/SIMD), 9 dependent
//    loads per 8 MFMA (8 of them W, per-wave redundant).
//  - This round: (1) split-K 8->32: grid (4,8,32)=1024 blocks = 4 blk/CU =
//    4 waves/SIMD; (2) wave = 4 row-tiles x 1 col-tile (64r x 16c): per
//    k-step 4 independent A-loads + 2 W-loads (was 1+8); W loaded once per
//    block (per-wave distinct col-tile), A L1-broadcast across waves.
//    Same 8 MFMA/k-step, acc 16 VGPR. Numerics: fp32 order change only
//    (output already atomicAdd-nondeterministic).
// Rest unchanged from round 12.
// ============================================================================

typedef __hip_bfloat16 bf16;
typedef __attribute__((ext_vector_type(8))) short short8;
typedef __attribute__((ext_vector_type(4))) float floatx4;

#define CHUNK 64

union U8 { int4 v; unsigned short s[8]; };
__device__ inline void umax8(U8& a, const U8& b){
  #pragma unroll
  for (int j = 0; j < 8; j++) a.s[j] = (a.s[j] > b.s[j]) ? a.s[j] : b.s[j];
}
union U4 { uint2 v; unsigned short s[4]; };
__device__ inline void umax4(U4& a, const U4& b){
  #pragma unroll
  for (int j = 0; j < 4; j++) a.s[j] = (a.s[j] > b.s[j]) ? a.s[j] : b.s[j];
}

// ---------- weight prep: conv2_w fp32 [64][32][7][7] -> bf16 [ky*7+kx][64][32]
__global__ __launch_bounds__(256) void prep_w2(const float* __restrict__ w,
                                               bf16* __restrict__ w2b)
{
  int idx = blockIdx.x*256 + threadIdx.x;     // 49*64*32 = 100352
  if (idx >= 49*64*32) return;
  int ic = idx & 31; int t = idx >> 5; int oc = t & 63; int kk = t >> 6;
  int ky = kk/7, kx = kk - ky*7;
  w2b[idx] = __float2bfloat16(w[((oc*32+ic)*7+ky)*7+kx]);
}

// ---------- weight prep: conv3_w fp32 [64][64][7][7] -> bf16 [ky][kc][kx][64][32]
__global__ __launch_bounds__(256) void prep_w3(const float* __restrict__ w,
                                               bf16* __restrict__ w3b)
{
  int idx = blockIdx.x*256 + threadIdx.x;     // 49*2*64*32 = 200704
  if (idx >= 49*2*64*32) return;
  int ic_l = idx & 31; int t = idx >> 5; int oc = t & 63; int t2 = t >> 6;
  int kx = t2 % 7; int t3 = t2 / 7; int kc = t3 & 1; int ky = t3 >> 1;
  w3b[idx] = __float2bfloat16(w[((oc*64 + kc*32 + ic_l)*7+ky)*7+kx]);
}

// ---------- transformer weight pack: fp32 [L][K][N] -> bf16 [L][K/8][N][8]
__global__ __launch_bounds__(256) void prep_pack(
    const float* __restrict__ src, bf16* __restrict__ dst,
    int K8, int N, int total)
{
  int idx = blockIdx.x*256 + threadIdx.x;
  if (idx >= total) return;
  int n = idx % N; int t = idx / N; int k8 = t % K8; int l = t / K8;
  const float* s = src + ((size_t)l*K8*8 + (size_t)k8*8)*N + n;
  union { bf16 h[8]; int4 v; } pk;
  #pragma unroll
  for (int j = 0; j < 8; j++) pk.h[j] = __float2bfloat16(s[(size_t)j*N]);
  *(int4*)(dst + (((size_t)l*K8 + k8)*N + n)*8) = pk.v;
}

// ---------- flat_w pack: fp32 [16384][512] -> hi/lo bf16 [2048][512][8]
__global__ __launch_bounds__(256) void prep_pack_flat(
    const float* __restrict__ src, bf16* __restrict__ hi, bf16* __restrict__ lo)
{
  int idx = blockIdx.x*256 + threadIdx.x;   // 2048*512 = 1048576
  if (idx >= 2048*512) return;
  int n = idx & 511; int k8 = idx >> 9;
  const float* s = src + (size_t)k8*8*512 + n;
  union { bf16 h[8]; int4 v; } ph, pl;
  #pragma unroll
  for (int j = 0; j < 8; j++){
    float w = s[(size_t)j*512];
    bf16 h = __float2bfloat16(w);
    ph.h[j] = h;
    pl.h[j] = __float2bfloat16(w - __bfloat162float(h));
  }
  size_t o = (size_t)idx*8;
  *(int4*)(hi + o) = ph.v;
  *(int4*)(lo + o) = pl.v;
}

// ---------- K1a: patchify + conv1(1->32,7x7,s2) + ReLU
//   -> cbuf [SUB][8grp][107][107][4ch] bf16
__global__ __launch_bounds__(256) void k1a_conv1(
    const float* __restrict__ img, const float* __restrict__ w,
    bf16* __restrict__ cbuf, int n_base)
{
  __shared__ __align__(16) float in_s[15*224];  // input rows 2*r0 .. 2*r0+14
  __shared__ float w_s[32*58];                  // stride 58: 2-way-conflict reads
  const int band = blockIdx.x;                  // 0..21
  const int n = blockIdx.y;                     // 0..SUB-1 (cbuf-local)
  const int ng = n_base + n;                    // global patch for img
  const int r0 = band*5;                        // conv rows r0..r0+4
  const int ir0 = 2*r0;
  const int b = ng>>4, gh = (ng>>2)&3, gw = ng&3;
  const float* ibase = img + b*774400 + (gh*220)*880 + gw*220;

  for (int idx = threadIdx.x; idx < 15*56; idx += 256){
    int r = idx/56, cq = idx - r*56; int c = cq*4;
    int gr = ir0 + r;
    float4 v = (c < 220 && gr < 220) ? *(const float4*)(ibase + gr*880 + c)
                                     : make_float4(0.f,0.f,0.f,0.f);
    *(float4*)&in_s[r*224 + c] = v;
  }
  for (int idx = threadIdx.x; idx < 32*56; idx += 256){
    int oc = idx/56, k = idx - oc*56; int ky = k>>3, kx = k&7;
    w_s[oc*58 + k] = (kx < 7) ? w[oc*49 + ky*7 + kx] : 0.f;
  }
  __syncthreads();

  const int grp = threadIdx.x & 7;
  const int sp  = threadIdx.x >> 3;   // 0..31 col-group (cols 4sp..4sp+3)
  const int cgc = (sp < 26) ? sp : 26;
  const int nrows = (107 - r0 < 5) ? (107 - r0) : 5;

  float acc[5][4][4] = {};            // [row-item][oc][col]
  #pragma unroll 1
  for (int ky = 0; ky < 7; ky++){
    float wk[4][7];
    #pragma unroll
    for (int oc = 0; oc < 4; oc++)
      #pragma unroll
      for (int kx = 0; kx < 7; kx++)
        wk[oc][kx] = w_s[(grp*4+oc)*58 + ky*8 + kx];
    #pragma unroll
    for (int i = 0; i < 5; i++){
      if (i < nrows){
        const float* ip = &in_s[(2*i+ky)*224 + 8*cgc];
        float iv[13];
        *(float4*)&iv[0] = *(const float4*)ip;
        *(float4*)&iv[4] = *(const float4*)(ip+4);
        *(float4*)&iv[8] = *(const float4*)(ip+8);
        iv[12] = ip[12];
        #pragma unroll
        for (int oc = 0; oc < 4; oc++)
          #pragma unroll
          for (int kx = 0; kx < 7; kx++)
            #pragma unroll
            for (int j = 0; j < 4; j++)
              acc[i][oc][j] += iv[2*j+kx]*wk[oc][kx];
      }
    }
  }

  #pragma unroll
  for (int i = 0; i < 5; i++){
    if (i < nrows){
      int y = r0 + i;
      #pragma unroll
      for (int j = 0; j < 4; j++){
        int col = 4*sp + j;
        if (col < 107){
          union { unsigned short s[4]; uint2 u; } pk;
          #pragma unroll
          for (int oc = 0; oc < 4; oc++){
            bf16 hv = __float2bfloat16(fmaxf(acc[i][oc][j], 0.f));
            pk.s[oc] = *(unsigned short*)&hv;
          }
          *(uint2*)(cbuf + (((size_t)(n*8+grp)*107 + y)*107 + col)*4) = pk.u;
        }
      }
    }
  }
}

// ---------- K1b: separable 7x7 s1 p1 max-pool. cbuf -> pool1
//   layout: [n][q=4][103][103][8ch]; grp g -> plane q=g>>1, half h=g&1.
__global__ __launch_bounds__(256) void k1b_pool1(
    const bf16* __restrict__ cbuf, bf16* __restrict__ pool1, int n_pool_base)
{
  __shared__ uint2 in4[19*107];   // conv rows p0-1..p0+17 (clamped)
  __shared__ uint2 ht4[19*103];   // after horizontal 7-max
  const int s = blockIdx.x, g = blockIdx.y, n = blockIdx.z;
  const int p0 = s*13;
  const int PR = (103 - p0 < 13) ? (103 - p0) : 13;
  const int NR = PR + 6;
  const uint2* src = (const uint2*)cbuf + (size_t)(n*8+g)*107*107;

  for (int t = threadIdx.x; t < NR*107; t += 256){
    int r = t/107, c = t - r*107;
    int gr = p0 - 1 + r;
    gr = (gr < 0) ? 0 : ((gr > 106) ? 106 : gr);
    in4[t] = src[gr*107 + c];
  }
  __syncthreads();
  for (int t = threadIdx.x; t < NR*103; t += 256){
    int r = t/103, c = t - r*103;
    U4 m; m.v = in4[r*107 + ((c > 0) ? c-1 : 0)];
    #pragma unroll
    for (int d = 0; d < 6; d++){
      U4 v; v.v = in4[r*107 + ((c+d < 106) ? c+d : 106)];
      umax4(m, v);
    }
    ht4[r*103 + c] = m.v;
  }
  __syncthreads();
  uint2* dst = (uint2*)pool1;
  const size_t plane = ((size_t)(n_pool_base + n)*4 + (g>>1))*10609;
  const int h = g & 1;
  for (int t = threadIdx.x; t < PR*103; t += 256){
    int pr = t/103, c = t - pr*103;
    U4 m; m.v = ht4[pr*103 + c];
    #pragma unroll
    for (int d = 1; d < 7; d++){
      U4 v; v.v = ht4[(pr+d)*103 + c];
      umax4(m, v);
    }
    dst[(plane + (size_t)(p0+pr)*103 + c)*2 + h] = m.v;
  }
}

// ---------- K2: conv2 MFMA implicit GEMM, circular row staging.
// pool1 [CHUNK][4][103][103][8] -> conv2out NHWC [CHUNK,49,49,64]
__global__ __launch_bounds__(256) void k2_conv2(
    const bf16* __restrict__ pool1,
    const bf16* __restrict__ w2b,     // [49][64][32]
    bf16* __restrict__ conv2out)
{
  __shared__ __align__(16) bf16 in_s[7*2*52*36];   // 52416 B, 7 row-slots
  const int n = blockIdx.y, pb = blockIdx.x;       // pb 0..9
  const int wv = threadIdx.x >> 6, lane = threadIdx.x & 63;
  const int li = lane & 15, lg = lane >> 4;
  const int p0 = pb*256;
  const int y0 = p0/49;

  int pyv[4], pxv[4]; bool pmask[4];
  #pragma unroll
  for (int t = 0; t < 4; t++){
    int p = p0 + wv*64 + t*16 + li;
    pmask[t] = (p <= 2400);
    int pc = min(p, 2400);
    int yy = pc/49, xx = pc - yy*49;
    pyv[t] = yy; pxv[t] = xx;
  }
  floatx4 acc[4][4];
  #pragma unroll
  for (int a = 0; a < 4; a++)
    #pragma unroll
    for (int t = 0; t < 4; t++) acc[a][t] = (floatx4){0.f,0.f,0.f,0.f};

  const unsigned short* pbase = (const unsigned short*)pool1;

  auto stage_rows = [&](int e0, int cnt, int par){
    for (int idx = threadIdx.x; idx < cnt*103*4; idx += 256){
      int q = idx & 3; int t2 = idx >> 2; int ri = t2/103; int c = t2 - ri*103;
      int e = e0 + ri;
      int slot = e % 7;
      int gr = min(2*e + par, 102);
      *(int4*)&in_s[((slot*2 + (c&1))*52 + (c>>1))*36 + q*8] =
        *(const int4*)(pbase + (((size_t)n*4 + q)*10609 + (size_t)gr*103 + c)*8);
    }
  };

  const int kyseq[7] = {0,2,4,6,1,3,5};
  #pragma unroll 1
  for (int ks = 0; ks < 7; ks++){
    int ky = kyseq[ks];
    int kyh = ky >> 1, par = ky & 1;
    __syncthreads();
    if (ks == 0 || ks == 4) stage_rows(y0, 7, par);
    else                    stage_rows(y0 + 6 + kyh, 1, par);
    __syncthreads();
    int poff[4];
    #pragma unroll
    for (int t = 0; t < 4; t++){
      int e = pyv[t] + kyh;
      int slot = e % 7;
      poff[t] = (slot*2*52 + pxv[t])*36;
    }
    #pragma unroll
    for (int kx = 0; kx < 7; kx++){
      short8 a[4];
      const bf16* wp = w2b + (ky*7+kx)*64*32;
      #pragma unroll
      for (int ot = 0; ot < 4; ot++)
        a[ot] = *(const short8*)(wp + (ot*16 + li)*32 + lg*8);
      int koff = ((kx&1)*52 + (kx>>1))*36 + lg*8;
      #pragma unroll
      for (int t = 0; t < 4; t++){
        short8 bfr = *(const short8*)(&in_s[poff[t] + koff]);
        #pragma unroll
        for (int ot = 0; ot < 4; ot++)
          acc[ot][t] = __builtin_amdgcn_mfma_f32_16x16x32_bf16(a[ot], bfr, acc[ot][t], 0, 0, 0);
      }
    }
  }
  #pragma unroll
  for (int t = 0; t < 4; t++){
    if (!pmask[t]) continue;
    bf16* dst = conv2out + (((long)n*49 + pyv[t])*49 + pxv[t])*64 + lg*4;
    #pragma unroll
    for (int ot = 0; ot < 4; ot++){
      union { bf16 h[4]; uint2 u; } pk;
      #pragma unroll
      for (int v = 0; v < 4; v++)
        pk.h[v] = __float2bfloat16(fmaxf(acc[ot][t][v], 0.f));
      *(uint2*)(dst + ot*16) = pk.u;
    }
  }
}

// ---------- K3a: horizontal 7-max: conv2out [CHUNK,49,49,64] -> tmp [CHUNK,49,45,64]
__global__ __launch_bounds__(256) void k3a_hmax(
    const bf16* __restrict__ cin, bf16* __restrict__ tmp)
{
  int idx = blockIdx.x*256 + threadIdx.x;
  int cg = idx & 7; int t = idx >> 3; int x = t % 45; int t2 = t / 45;
  int y = t2 % 49; int n = t2 / 49;
  const int4* row = (const int4*)(cin + ((long)(n*49 + y)*49)*64) + cg;
  U8 m; m.v = make_int4(0,0,0,0);
  int lo = max(x-1, 0), hi = min(x+5, 48);
  for (int cx = lo; cx <= hi; cx++){ U8 v; v.v = row[cx*8]; umax8(m, v); }
  *((int4*)(tmp + ((long)(n*49 + y)*45 + x)*64) + cg) = m.v;
}

// ---------- K3b: vertical 7-max: tmp -> pool2 [256,45,45,64] at n_base
__global__ __launch_bounds__(256) void k3b_vmax(
    const bf16* __restrict__ tmp, bf16* __restrict__ pout, int n_base)
{
  int idx = blockIdx.x*256 + threadIdx.x;
  int cg = idx & 7; int t = idx >> 3; int x = t % 45; int t2 = t / 45;
  int y = t2 % 45; int n = t2 / 45;
  U8 m; m.v = make_int4(0,0,0,0);
  int lo = max(y-1, 0), hi = min(y+5, 48);
  for (int cy = lo; cy <= hi; cy++){
    U8 v; v.v = *((const int4*)(tmp + ((long)(n*49 + cy)*45 + x)*64) + cg);
    umax8(m, v);
  }
  *((int4*)(pout + (long)(n_base+n)*129600 + (y*45 + x)*64) + cg) = m.v;
}

// ---------- K4: conv3 MFMA implicit GEMM, circular row staging.
// pool2 NHWC -> conv3out NHWC [256,20,20,64]
__global__ __launch_bounds__(256) void k4_conv3(
    const bf16* __restrict__ pool2,
    const bf16* __restrict__ w3b,     // [ky][kc][kx][64][32]
    bf16* __restrict__ conv3out)
{
  __shared__ __align__(16) bf16 in_s[10*2*24*40];  // 38400 B, 10 row-slots
  const int n = blockIdx.y, pb = blockIdx.x;       // pb 0..1
  const int wv = threadIdx.x >> 6, lane = threadIdx.x & 63;
  const int li = lane & 15, lg = lane >> 4;
  const int y0 = pb*10;

  int pyv[4], pxv[4]; bool pmask[4];
  #pragma unroll
  for (int t = 0; t < 4; t++){
    int pl = wv*64 + t*16 + li;
    pmask[t] = (pl < 200);
    int p = pb*200 + min(pl, 199);
    int yy = p/20, xx = p - yy*20;
    pyv[t] = yy; pxv[t] = xx;
  }
  floatx4 acc[4][4];
  #pragma unroll
  for (int a = 0; a < 4; a++)
    #pragma unroll
    for (int t = 0; t < 4; t++) acc[a][t] = (floatx4){0.f,0.f,0.f,0.f};

  auto stage_rows = [&](int e0, int cnt, int par, int kc){
    for (int idx = threadIdx.x; idx < cnt*45*4; idx += 256){
      int q = idx & 3; int t2 = idx >> 2; int ri = t2/45; int c = t2 - ri*45;
      int e = e0 + ri;
      int slot = e % 10;
      int gr = 2*e + par;
      *(int4*)&in_s[((slot*2 + (c&1))*24 + (c>>1))*40 + q*8] =
        *(const int4*)(pool2 + (((long)n*45 + gr)*45 + c)*64 + kc*32 + q*8);
    }
  };

  const int kyseq[7] = {0,2,4,6,1,3,5};
  #pragma unroll 1
  for (int kc = 0; kc < 2; kc++){
    #pragma unroll 1
    for (int ks = 0; ks < 7; ks++){
      int ky = kyseq[ks];
      int kyh = ky >> 1, par = ky & 1;
      __syncthreads();
      if (ks == 0 || ks == 4) stage_rows(y0 + kyh, 10, par, kc);
      else                    stage_rows(y0 + 9 + kyh, 1, par, kc);
      __syncthreads();
      int poff[4];
      #pragma unroll
      for (int t = 0; t < 4; t++){
        int e = pyv[t] + kyh;
        int slot = e % 10;
        poff[t] = (slot*2*24 + pxv[t])*40;
      }
      #pragma unroll
      for (int kx = 0; kx < 7; kx++){
        short8 a[4];
        const bf16* wp = w3b + ((ky*2+kc)*7 + kx)*64*32;
        #pragma unroll
        for (int ot = 0; ot < 4; ot++)
          a[ot] = *(const short8*)(wp + (ot*16 + li)*32 + lg*8);
        int koff = ((kx&1)*24 + (kx>>1))*40 + lg*8;
        #pragma unroll
        for (int t = 0; t < 4; t++){
          short8 bfr = *(const short8*)(&in_s[poff[t] + koff]);
          #pragma unroll
          for (int ot = 0; ot < 4; ot++)
            acc[ot][t] = __builtin_amdgcn_mfma_f32_16x16x32_bf16(a[ot], bfr, acc[ot][t], 0, 0, 0);
        }
      }
    }
  }
  #pragma unroll
  for (int t = 0; t < 4; t++){
    if (!pmask[t]) continue;
    bf16* dst = conv3out + (((long)n*20 + pyv[t])*20 + pxv[t])*64 + lg*4;
    #pragma unroll
    for (int ot = 0; ot < 4; ot++){
      union { bf16 h[4]; uint2 u; } pk;
      #pragma unroll
      for (int v = 0; v < 4; v++)
        pk.h[v] = __float2bfloat16(fmaxf(acc[ot][t][v], 0.f));
      *(uint2*)(dst + ot*16) = pk.u;
    }
  }
}

// ---------- K5: in-LDS separable pool3. conv3out [256,20,20,64] -> feat [256,16384]
__global__ __launch_bounds__(256) void k5_pool3(
    const bf16* __restrict__ cin, bf16* __restrict__ feat)
{
  __shared__ int4 in_p[3200];
  __shared__ int4 ht[2560];
  const int n = blockIdx.x;
  const int4* src = (const int4*)(cin + (long)n*25600);
  for (int i = threadIdx.x; i < 3200; i += 256) in_p[i] = src[i];
  __syncthreads();
  for (int i = threadIdx.x; i < 2560; i += 256){
    int cg = i & 7; int t = i >> 3; int x = t & 15; int y = t >> 4;
    U8 m; m.v = make_int4(0,0,0,0);
    int lo = max(x-1, 0), hi = min(x+5, 19);
    for (int cx = lo; cx <= hi; cx++){ U8 v; v.v = in_p[(y*20+cx)*8 + cg]; umax8(m, v); }
    ht[(y*16+x)*8 + cg] = m.v;
  }
  __syncthreads();
  unsigned short* dst = (unsigned short*)(feat + (long)n*16384);
  for (int i = threadIdx.x; i < 2048; i += 256){
    int px = i & 15; int py = (i >> 4) & 15; int cg = i >> 8;
    U8 m; m.v = make_int4(0,0,0,0);
    int lo = max(py-1, 0), hi = min(py+5, 19);
    for (int cy = lo; cy <= hi; cy++){ U8 v; v.v = ht[(cy*16+px)*8 + cg]; umax8(m, v); }
    #pragma unroll
    for (int j = 0; j < 8; j++)
      dst[(cg*8+j)*256 + py*16 + px] = m.s[j];
  }
}

// ---------- K6a: init x[272,512]
__global__ __launch_bounds__(256) void k6_init_x(
    const float* __restrict__ cls, const float* __restrict__ pos,
    const float* __restrict__ flat_b, float* __restrict__ x)
{
  int idx = blockIdx.x*256 + threadIdx.x;
  int d = idx & 511; int row = idx >> 9;
  int tt = row % 17;
  x[idx] = (tt == 0) ? (cls[d] + pos[d]) : (flat_b[d] + pos[tt*512 + d]);
}

// ---------- K6b: feat @ flat_w via MFMA (hi+lo bf16 W). atomicAdd into x.
// grid (4, 8, 32): block = 64 rows x 64 cols, split-K 512.
// Wave = 4 row-tiles x 1 col-tile: per k-step 4 A-loads + 2 W-loads, 8 MFMA.
__global__ __launch_bounds__(256) void k6_flat_mfma(
    const bf16* __restrict__ feat, const bf16* __restrict__ Whi,
    const bf16* __restrict__ Wlo, float* __restrict__ x)
{
  const int wv = threadIdx.x >> 6, lane = threadIdx.x & 63;
  const int li = lane & 15, lg = lane >> 4;
  const int m0 = blockIdx.x*64;             // block's 64 rows
  const int nb = blockIdx.y*64 + wv*16;     // wave's 16 cols
  const int kb = blockIdx.z*512;            // k-range (16 k-steps)
  floatx4 acc[4];
  #pragma unroll
  for (int t = 0; t < 4; t++) acc[t] = (floatx4){0.f,0.f,0.f,0.f};

  const bf16* abase = feat + (size_t)(m0+li)*16384 + kb + lg*8;
  for (int k0 = 0; k0 < 512; k0 += 32){
    short8 a0 = *(const short8*)(abase + k0);
    short8 a1 = *(const short8*)(abase + (size_t)16*16384 + k0);
    short8 a2 = *(const short8*)(abase + (size_t)32*16384 + k0);
    short8 a3 = *(const short8*)(abase + (size_t)48*16384 + k0);
    size_t wo = ((size_t)((kb + k0) >> 3) + lg)*512 + nb + li;  // in 8-elt units
    short8 bh = *(const short8*)(Whi + wo*8);
    short8 bl = *(const short8*)(Wlo + wo*8);
    acc[0] = __builtin_amdgcn_mfma_f32_16x16x32_bf16(a0, bh, acc[0], 0, 0, 0);
    acc[1] = __builtin_amdgcn_mfma_f32_16x16x32_bf16(a1, bh, acc[1], 0, 0, 0);
    acc[2] = __builtin_amdgcn_mfma_f32_16x16x32_bf16(a2, bh, acc[2], 0, 0, 0);
    acc[3] = __builtin_amdgcn_mfma_f32_16x16x32_bf16(a3, bh, acc[3], 0, 0, 0);
    acc[0] = __builtin_amdgcn_mfma_f32_16x16x32_bf16(a0, bl, acc[0], 0, 0, 0);
    acc[1] = __builtin_amdgcn_mfma_f32_16x16x32_bf16(a1, bl, acc[1], 0, 0, 0);
    acc[2] = __builtin_amdgcn_mfma_f32_16x16x32_bf16(a2, bl, acc[2], 0, 0, 0);
    acc[3] = __builtin_amdgcn_mfma_f32_16x16x32_bf16(a3, bl, acc[3], 0, 0, 0);
  }
  int col = nb + li;
  #pragma unroll
  for (int t = 0; t < 4; t++){
    #pragma unroll
    for (int v = 0; v < 4; v++){
      int m = m0 + t*16 + lg*4 + v;
      int row = (m>>4)*17 + 1 + (m&15);
      atomicAdd(&x[row*512 + col], acc[t][v]);
    }
  }
}

// ---------- LayerNorm over 512, fp32 out (head path)
__global__ __launch_bounds__(256) void ln_kernel(
    const float* __restrict__ in, const float* __restrict__ g,
    const float* __restrict__ b, float* __restrict__ out,
    int in_stride, int out_stride)
{
  int row = blockIdx.x;
  const float* p = in + (long)row*in_stride;
  float v0 = p[threadIdx.x], v1 = p[threadIdx.x+256];
  __shared__ float red[4]; __shared__ float stat;
  float s = v0+v1;
  #pragma unroll
  for (int o = 32; o >= 1; o >>= 1) s += __shfl_down(s, o);
  int lane = threadIdx.x & 63, wv = threadIdx.x >> 6;
  if (lane == 0) red[wv] = s;
  __syncthreads();
  if (threadIdx.x == 0) stat = (red[0]+red[1]+red[2]+red[3])*(1.0f/512.0f);
  __syncthreads();
  float m = stat;
  float d0 = v0-m, d1 = v1-m;
  float q = d0*d0 + d1*d1;
  #pragma unroll
  for (int o = 32; o >= 1; o >>= 1) q += __shfl_down(q, o);
  __syncthreads();
  if (lane == 0) red[wv] = q;
  __syncthreads();
  if (threadIdx.x == 0) stat = rsqrtf((red[0]+red[1]+red[2]+red[3])*(1.0f/512.0f) + 1e-5f);
  __syncthreads();
  float rstd = stat;
  out[(long)row*out_stride + threadIdx.x]     = d0*rstd*g[threadIdx.x]     + b[threadIdx.x];
  out[(long)row*out_stride + threadIdx.x+256] = d1*rstd*g[threadIdx.x+256] + b[threadIdx.x+256];
}

// ---------- LayerNorm over 512, bf16 out (MFMA tail activations)
__global__ __launch_bounds__(256) void ln_bf16(
    const float* __restrict__ in, const float* __restrict__ g,
    const float* __restrict__ b, bf16* __restrict__ out)
{
  int row = blockIdx.x;
  const float* p = in + (long)row*512;
  float v0 = p[threadIdx.x], v1 = p[threadIdx.x+256];
  __shared__ float red[4]; __shared__ float stat;
  float s = v0+v1;
  #pragma unroll
  for (int o = 32; o >= 1; o >>= 1) s += __shfl_down(s, o);
  int lane = threadIdx.x & 63, wv = threadIdx.x >> 6;
  if (lane == 0) red[wv] = s;
  __syncthreads();
  if (threadIdx.x == 0) stat = (red[0]+red[1]+red[2]+red[3])*(1.0f/512.0f);
  __syncthreads();
  float m = stat;
  float d0 = v0-m, d1 = v1-m;
  float q = d0*d0 + d1*d1;
  #pragma unroll
  for (int o = 32; o >= 1; o >>= 1) q += __shfl_down(q, o);
  __syncthreads();
  if (lane == 0) red[wv] = q;
  __syncthreads();
  if (threadIdx.x == 0) stat = rsqrtf((red[0]+red[1]+red[2]+red[3])*(1.0f/512.0f) + 1e-5f);
  __syncthreads();
  float rstd = stat;
  out[(long)row*512 + threadIdx.x]     = __float2bfloat16(d0*rstd*g[threadIdx.x]     + b[threadIdx.x]);
  out[(long)row*512 + threadIdx.x+256] = __float2bfloat16(d1*rstd*g[threadIdx.x+256] + b[threadIdx.x+256]);
}

// ---------- MFMA tail GEMM: out = [res +] act(A@W + bias)
template<int NT>
__global__ __launch_bounds__(256) void tail_gemm(
    const bf16* __restrict__ A, const bf16* __restrict__ Wp,
    const float* __restrict__ bias, const float* res,
    float* outf, bf16* outb, int N, int K, int dogelu)
{
  const int wv = threadIdx.x >> 6, lane = threadIdx.x & 63;
  const int li = lane & 15, lg = lane >> 4;
  const int m0 = blockIdx.x * 16;
  const int nb = blockIdx.y * (64*NT) + wv * (16*NT);
  floatx4 acc[NT];
  #pragma unroll
  for (int t = 0; t < NT; t++) acc[t] = (floatx4){0.f,0.f,0.f,0.f};
  const bf16* arow = A + (size_t)(m0+li)*K + lg*8;
  for (int k0 = 0; k0 < K; k0 += 32){
    short8 a = *(const short8*)(arow + k0);
    const bf16* wrow = Wp + ((size_t)((k0>>3) + lg) * N + nb + li) * 8;
    #pragma unroll
    for (int t = 0; t < NT; t++){
      short8 bfr = *(const short8*)(wrow + t*128);
      acc[t] = __builtin_amdgcn_mfma_f32_16x16x32_bf16(a, bfr, acc[t], 0, 0, 0);
    }
  }
  #pragma unroll
  for (int t = 0; t < NT; t++){
    int col = nb + t*16 + li;
    #pragma unroll
    for (int v = 0; v < 4; v++){
      int row = m0 + lg*4 + v;
      float val = acc[t][v];
      if (bias) val += bias[col];
      if (dogelu) val = 0.5f*val*(1.0f + erff(val*0.70710678118654752f));
      if (res) val += res[(size_t)row*N + col];
      if (outf) outf[(size_t)row*N + col] = val;
      else      outb[(size_t)row*N + col] = __float2bfloat16(val);
    }
  }
}

// ---------- Generic small GEMM (head only): out = act(A@W + bias)
__global__ __launch_bounds__(256) void gemm_rows(
    const float* __restrict__ A, const float* __restrict__ W,
    const float* __restrict__ bias, const float* __restrict__ res,
    float* __restrict__ out, int M, int N, int K, int dogelu)
{
  __shared__ float A_s[16][33];
  __shared__ __align__(16) float W_s[32][68];
  const int m0 = blockIdx.x*16, n0 = blockIdx.y*64;
  const int r = threadIdx.x>>4, c0 = (threadIdx.x&15)*4;
  float acc[4] = {};
  for (int k0 = 0; k0 < K; k0 += 32){
    __syncthreads();
    for (int i = 0; i < 2; i++){ int id = threadIdx.x + i*256; int rr = id>>5, kk = id&31;
      A_s[rr][kk] = (m0+rr < M) ? A[(long)(m0+rr)*K + k0+kk] : 0.f; }
    for (int i = 0; i < 8; i++){ int id = threadIdx.x + i*256; int kk = id>>6, c = id&63;
      W_s[kk][c] = (n0+c < N) ? W[(long)(k0+kk)*N + n0+c] : 0.f; }
    __syncthreads();
    #pragma unroll
    for (int kk = 0; kk < 32; kk++){
      float a = A_s[r][kk];
      float4 w4 = *(const float4*)&W_s[kk][c0];
      acc[0]+=a*w4.x; acc[1]+=a*w4.y; acc[2]+=a*w4.z; acc[3]+=a*w4.w;
    }
  }
  if (m0+r < M){
    int row = m0+r;
    for (int j = 0; j < 4; j++){
      int c = n0+c0+j;
      if (c < N){
        float v = acc[j];
        if (bias) v += bias[c];
        if (dogelu) v = 0.5f*v*(1.0f + erff(v*0.70710678118654752f));
        if (res) v += res[(long)row*N + c];
        out[(long)row*N + c] = v;
      }
    }
  }
}

// ---------- Attention: one block per (b,h). N=17, DH=64. Writes bf16 O.
__global__ __launch_bounds__(128) void attn_kernel(
    const float* __restrict__ qkv, bf16* __restrict__ obuf)
{
  const int b = blockIdx.x >> 3, h = blockIdx.x & 7;
  __shared__ float q_s[17][65], k_s[17][65], v_s[17][65], s_s[17][18];
  for (int idx = threadIdx.x; idx < 17*64; idx += 128){
    int i = idx>>6, d = idx&63;
    const float* base = qkv + (long)(b*17+i)*1536 + h*64 + d;
    q_s[i][d] = base[0]; k_s[i][d] = base[512]; v_s[i][d] = base[1024];
  }
  __syncthreads();
  for (int idx = threadIdx.x; idx < 289; idx += 128){
    int i = idx/17, j = idx - i*17;
    float s = 0.f;
    for (int d = 0; d < 64; d++) s += q_s[i][d]*k_s[j][d];
    s_s[i][j] = s*0.125f;
  }
  __syncthreads();
  if (threadIdx.x < 17){
    int i = threadIdx.x;
    float m = -1e30f;
    for (int j = 0; j < 17; j++) m = fmaxf(m, s_s[i][j]);
    float sum = 0.f;
    for (int j = 0; j < 17; j++){ float e = expf(s_s[i][j]-m); s_s[i][j] = e; sum += e; }
    float inv = 1.0f/sum;
    for (int j = 0; j < 17; j++) s_s[i][j] *= inv;
  }
  __syncthreads();
  for (int idx = threadIdx.x; idx < 17*64; idx += 128){
    int i = idx>>6, d = idx&63;
    float o = 0.f;
    for (int j = 0; j < 17; j++) o += s_s[i][j]*v_s[j][d];
    obuf[(long)(b*17+i)*512 + h*64 + d] = __float2bfloat16(o);
  }
}

// ============================================================================
extern "C" void kernel_launch(void* const* d_in, const int* in_sizes, int n_in,
                              void* d_out, int out_size, void* d_ws, size_t ws_size,
                              hipStream_t stream) {
  const float* img      = (const float*)d_in[0];
  const float* conv1_w  = (const float*)d_in[1];
  const float* conv2_w  = (const float*)d_in[2];
  const float* conv3_w  = (const float*)d_in[3];
  const float* flat_w   = (const float*)d_in[4];
  const float* flat_b   = (const float*)d_in[5];
  const float* cls_tok  = (const float*)d_in[6];
  const float* pos_emb  = (const float*)d_in[7];
  const float* ln1_g    = (const float*)d_in[8];
  const float* ln1_b    = (const float*)d_in[9];
  const float* qkv_w    = (const float*)d_in[10];
  const float* out_w    = (const float*)d_in[11];
  const float* out_b    = (const float*)d_in[12];
  const float* ln2_g    = (const float*)d_in[13];
  const float* ln2_b    = (const float*)d_in[14];
  const float* ff1_w    = (const float*)d_in[15];
  const float* ff1_b    = (const float*)d_in[16];
  const float* ff2_w    = (const float*)d_in[17];
  const float* ff2_b    = (const float*)d_in[18];
  const float* hln_g    = (const float*)d_in[19];
  const float* hln_b    = (const float*)d_in[20];
  const float* head_w   = (const float*)d_in[21];
  const float* head_b   = (const float*)d_in[22];

  char* ws = (char*)d_ws;
  size_t off = 0;
  auto alloc = [&](size_t bytes) -> void* {
    void* p = ws + off; off += (bytes + 255) & ~(size_t)255; return p;
  };
  bf16* pool1    = (bf16*)alloc((size_t)CHUNK*8*103*103*4*2); // 43.5 MB (chunk, [n][4][103][103][8])
  bf16* conv2out = (bf16*)alloc((size_t)CHUNK*49*49*64*2);    // 19.7 MB (chunk, NHWC)
  bf16* pool2    = (bf16*)alloc((size_t)256*45*45*64*2);      // 66.4 MB (full, NHWC)
  bf16* feat     = (bf16*)alloc((size_t)256*16384*2);         //  8.4 MB
  bf16* w2b      = (bf16*)alloc((size_t)49*64*32*2);
  bf16* w3b      = (bf16*)alloc((size_t)49*2*64*32*2);
  float* x       = (float*)alloc((size_t)139264*4);           // 272x512 fp32
  bf16*  hb      = (bf16*)alloc((size_t)139264*2);            // 272x512 bf16 (LN out)
  float* qkvb    = (float*)alloc((size_t)417792*4);           // 272x1536 fp32
  bf16*  obufb   = (bf16*)alloc((size_t)139264*2);            // 272x512 bf16
  bf16*  ffbufb  = (bf16*)alloc((size_t)557056*2);            // 272x2048 bf16
  float* hcls    = (float*)alloc((size_t)8192*4);             // 16x512
  // pool1 region reuse (dead at the noted points):
  bf16* tmp3     = pool1;            // k3 horizontal tmp (within chunk loop)
  bf16* conv3out = pool1;            // k4 output (after chunk loop)
  // packed transformer weights alias pool1 AFTER k5 (pool1 fully dead):
  bf16* qkvp  = pool1;               //  9.44 MB
  bf16* outwp = qkvp  + (size_t)6*512*1536;   // 3.15 MB
  bf16* ff1p  = outwp + (size_t)6*512*512;    // 12.58 MB
  bf16* ff2p  = ff1p  + (size_t)6*512*2048;   // 12.58 MB  (total 37.75 <= 43.5)
  // flat_w hi/lo packs alias conv2out (hi) and pool2 (lo) — dead after k5.
  bf16* fwhi  = conv2out;
  bf16* fwlo  = pool2;

  // conv1 intermediate (k1a -> k1b), sized adaptively against ws_size.
  const size_t cb_per_n = (size_t)8*107*107*4*2;   // 733,136 B per patch
  int SUB; bf16* cbuf;
  if (ws_size >= off + 64*cb_per_n)      { SUB = 64; cbuf = (bf16*)alloc(64*cb_per_n); }
  else if (ws_size >= off + 32*cb_per_n) { SUB = 32; cbuf = (bf16*)alloc(32*cb_per_n); }
  else { SUB = 16; cbuf = conv2out; }  // dead-region fallback (see round 7)
  (void)in_sizes; (void)n_in; (void)out_size;

  prep_w2<<<392, 256, 0, stream>>>(conv2_w, w2b);
  prep_w3<<<784, 256, 0, stream>>>(conv3_w, w3b);

  for (int cb = 0; cb < 256; cb += CHUNK){
    for (int sb = 0; sb < CHUNK; sb += SUB){
      k1a_conv1<<<dim3(22, SUB), 256, 0, stream>>>(img, conv1_w, cbuf, cb + sb);
      k1b_pool1<<<dim3(8, 8, SUB), 256, 0, stream>>>(cbuf, pool1, sb);
    }
    k2_conv2     <<<dim3(10,CHUNK), 256, 0, stream>>>(pool1, w2b, conv2out);
    k3a_hmax     <<<(CHUNK*49*45*8)/256, 256, 0, stream>>>(conv2out, tmp3);
    k3b_vmax     <<<(CHUNK*45*45*8)/256, 256, 0, stream>>>(tmp3, pool2, cb);
  }
  k4_conv3<<<dim3(2,256), 256, 0, stream>>>(pool2, w3b, conv3out);
  k5_pool3<<<256, 256, 0, stream>>>(conv3out, feat);

  // packs into dead regions (pool1 / conv2out / pool2 all dead after k5)
  prep_pack_flat<<<4096, 256, 0, stream>>>(flat_w, fwhi, fwlo);
  prep_pack<<<(6*64*1536+255)/256, 256, 0, stream>>>(qkv_w, qkvp, 64, 1536, 6*64*1536);
  prep_pack<<<(6*64*512 +255)/256, 256, 0, stream>>>(out_w, outwp, 64, 512,  6*64*512);
  prep_pack<<<(6*64*2048+255)/256, 256, 0, stream>>>(ff1_w, ff1p, 64, 2048, 6*64*2048);
  prep_pack<<<(6*256*512+255)/256, 256, 0, stream>>>(ff2_w, ff2p, 256, 512, 6*256*512);

  k6_init_x    <<<544,          256, 0, stream>>>(cls_tok, pos_emb, flat_b, x);
  k6_flat_mfma <<<dim3(4,8,32), 256, 0, stream>>>(feat, fwhi, fwlo, x);

  for (int l = 0; l < 6; l++){
    ln_bf16<<<272, 256, 0, stream>>>(x, ln1_g + l*512, ln1_b + l*512, hb);
    tail_gemm<4><<<dim3(17,6), 256, 0, stream>>>(hb, qkvp + (size_t)l*786432,
                                                 nullptr, nullptr, qkvb, nullptr, 1536, 512, 0);
    attn_kernel<<<128, 128, 0, stream>>>(qkvb, obufb);
    tail_gemm<1><<<dim3(17,8), 256, 0, stream>>>(obufb, outwp + (size_t)l*262144,
                                                 out_b + l*512, x, x, nullptr, 512, 512, 0);
    ln_bf16<<<272, 256, 0, stream>>>(x, ln2_g + l*512, ln2_b + l*512, hb);
    tail_gemm<4><<<dim3(17,8), 256, 0, stream>>>(hb, ff1p + (size_t)l*1048576,
                                                 ff1_b + l*2048, nullptr, nullptr, ffbufb, 2048, 512, 1);
    tail_gemm<1><<<dim3(17,8), 256, 0, stream>>>(ffbufb, ff2p + (size_t)l*1048576,
                                                 ff2_b + l*512, x, x, nullptr, 512, 2048, 0);
  }

  ln_kernel<<<16, 256, 0, stream>>>(x, hln_g, hln_b, hcls, 17*512, 512);
  gemm_rows<<<dim3(1,16), 256, 0, stream>>>(hcls, head_w, head_b, nullptr,
                                            (float*)d_out, 16, 1000, 512, 0);
}

// Round 8
// 1535.303 us; speedup vs baseline: 1.2358x; 1.0081x over previous
//
#include <hip/hip_runtime.h>
#include <hip/hip_bf16.h>

// ============================================================================
// HybridViT forward. Round 14: k2 parity-batched two-stage staging.
//  - Round-13 state: k2 top again (81.4us x4). FETCH now minimal (39.6MB =
//    unique pool1), but MfmaUtil 15% / VALUBusy 12%: the 7 staging events x
//    2 barriers (each draining vmcnt(0) = full HBM round trip, congested)
//    are the remaining cost.
//  - This round: stage ALL even-tap rows at once (e in [y0,y0+9], 10 rows,
//    gr=2e), compute ky=0,2,4,6 back-to-back with NO barriers between; then
//    stage odd rows (9, gr=2e+1), compute ky=1,3,5. 3 barriers (was 14),
//    2 latency exposures (was 7). LDS 10 slots = 74,880B (2 blk/CU; >64KB
//    static proven by old k1's 74,752). Same 19 staged rows -> FETCH same.
//    Slot = e-y0 direct (no modulo). Identical per-position numerics.
//  - Canaries: WRITE_SIZE ~19.2MB, VGPR ~88 (spill); FETCH ~39.6MB.
// Rest unchanged from round 13. If confirmed, port to k4 next round.
// ============================================================================

typedef __hip_bfloat16 bf16;
typedef __attribute__((ext_vector_type(8))) short short8;
typedef __attribute__((ext_vector_type(4))) float floatx4;

#define CHUNK 64

union U8 { int4 v; unsigned short s[8]; };
__device__ inline void umax8(U8& a, const U8& b){
  #pragma unroll
  for (int j = 0; j < 8; j++) a.s[j] = (a.s[j] > b.s[j]) ? a.s[j] : b.s[j];
}
union U4 { uint2 v; unsigned short s[4]; };
__device__ inline void umax4(U4& a, const U4& b){
  #pragma unroll
  for (int j = 0; j < 4; j++) a.s[j] = (a.s[j] > b.s[j]) ? a.s[j] : b.s[j];
}

// ---------- weight prep: conv2_w fp32 [64][32][7][7] -> bf16 [ky*7+kx][64][32]
__global__ __launch_bounds__(256) void prep_w2(const float* __restrict__ w,
                                               bf16* __restrict__ w2b)
{
  int idx = blockIdx.x*256 + threadIdx.x;     // 49*64*32 = 100352
  if (idx >= 49*64*32) return;
  int ic = idx & 31; int t = idx >> 5; int oc = t & 63; int kk = t >> 6;
  int ky = kk/7, kx = kk - ky*7;
  w2b[idx] = __float2bfloat16(w[((oc*32+ic)*7+ky)*7+kx]);
}

// ---------- weight prep: conv3_w fp32 [64][64][7][7] -> bf16 [ky][kc][kx][64][32]
__global__ __launch_bounds__(256) void prep_w3(const float* __restrict__ w,
                                               bf16* __restrict__ w3b)
{
  int idx = blockIdx.x*256 + threadIdx.x;     // 49*2*64*32 = 200704
  if (idx >= 49*2*64*32) return;
  int ic_l = idx & 31; int t = idx >> 5; int oc = t & 63; int t2 = t >> 6;
  int kx = t2 % 7; int t3 = t2 / 7; int kc = t3 & 1; int ky = t3 >> 1;
  w3b[idx] = __float2bfloat16(w[((oc*64 + kc*32 + ic_l)*7+ky)*7+kx]);
}

// ---------- transformer weight pack: fp32 [L][K][N] -> bf16 [L][K/8][N][8]
__global__ __launch_bounds__(256) void prep_pack(
    const float* __restrict__ src, bf16* __restrict__ dst,
    int K8, int N, int total)
{
  int idx = blockIdx.x*256 + threadIdx.x;
  if (idx >= total) return;
  int n = idx % N; int t = idx / N; int k8 = t % K8; int l = t / K8;
  const float* s = src + ((size_t)l*K8*8 + (size_t)k8*8)*N + n;
  union { bf16 h[8]; int4 v; } pk;
  #pragma unroll
  for (int j = 0; j < 8; j++) pk.h[j] = __float2bfloat16(s[(size_t)j*N]);
  *(int4*)(dst + (((size_t)l*K8 + k8)*N + n)*8) = pk.v;
}

// ---------- flat_w pack: fp32 [16384][512] -> hi/lo bf16 [2048][512][8]
__global__ __launch_bounds__(256) void prep_pack_flat(
    const float* __restrict__ src, bf16* __restrict__ hi, bf16* __restrict__ lo)
{
  int idx = blockIdx.x*256 + threadIdx.x;   // 2048*512 = 1048576
  if (idx >= 2048*512) return;
  int n = idx & 511; int k8 = idx >> 9;
  const float* s = src + (size_t)k8*8*512 + n;
  union { bf16 h[8]; int4 v; } ph, pl;
  #pragma unroll
  for (int j = 0; j < 8; j++){
    float w = s[(size_t)j*512];
    bf16 h = __float2bfloat16(w);
    ph.h[j] = h;
    pl.h[j] = __float2bfloat16(w - __bfloat162float(h));
  }
  size_t o = (size_t)idx*8;
  *(int4*)(hi + o) = ph.v;
  *(int4*)(lo + o) = pl.v;
}

// ---------- K1a: patchify + conv1(1->32,7x7,s2) + ReLU
//   -> cbuf [SUB][8grp][107][107][4ch] bf16
__global__ __launch_bounds__(256) void k1a_conv1(
    const float* __restrict__ img, const float* __restrict__ w,
    bf16* __restrict__ cbuf, int n_base)
{
  __shared__ __align__(16) float in_s[15*224];  // input rows 2*r0 .. 2*r0+14
  __shared__ float w_s[32*58];                  // stride 58: 2-way-conflict reads
  const int band = blockIdx.x;                  // 0..21
  const int n = blockIdx.y;                     // 0..SUB-1 (cbuf-local)
  const int ng = n_base + n;                    // global patch for img
  const int r0 = band*5;                        // conv rows r0..r0+4
  const int ir0 = 2*r0;
  const int b = ng>>4, gh = (ng>>2)&3, gw = ng&3;
  const float* ibase = img + b*774400 + (gh*220)*880 + gw*220;

  for (int idx = threadIdx.x; idx < 15*56; idx += 256){
    int r = idx/56, cq = idx - r*56; int c = cq*4;
    int gr = ir0 + r;
    float4 v = (c < 220 && gr < 220) ? *(const float4*)(ibase + gr*880 + c)
                                     : make_float4(0.f,0.f,0.f,0.f);
    *(float4*)&in_s[r*224 + c] = v;
  }
  for (int idx = threadIdx.x; idx < 32*56; idx += 256){
    int oc = idx/56, k = idx - oc*56; int ky = k>>3, kx = k&7;
    w_s[oc*58 + k] = (kx < 7) ? w[oc*49 + ky*7 + kx] : 0.f;
  }
  __syncthreads();

  const int grp = threadIdx.x & 7;
  const int sp  = threadIdx.x >> 3;   // 0..31 col-group (cols 4sp..4sp+3)
  const int cgc = (sp < 26) ? sp : 26;
  const int nrows = (107 - r0 < 5) ? (107 - r0) : 5;

  float acc[5][4][4] = {};            // [row-item][oc][col]
  #pragma unroll 1
  for (int ky = 0; ky < 7; ky++){
    float wk[4][7];
    #pragma unroll
    for (int oc = 0; oc < 4; oc++)
      #pragma unroll
      for (int kx = 0; kx < 7; kx++)
        wk[oc][kx] = w_s[(grp*4+oc)*58 + ky*8 + kx];
    #pragma unroll
    for (int i = 0; i < 5; i++){
      if (i < nrows){
        const float* ip = &in_s[(2*i+ky)*224 + 8*cgc];
        float iv[13];
        *(float4*)&iv[0] = *(const float4*)ip;
        *(float4*)&iv[4] = *(const float4*)(ip+4);
        *(float4*)&iv[8] = *(const float4*)(ip+8);
        iv[12] = ip[12];
        #pragma unroll
        for (int oc = 0; oc < 4; oc++)
          #pragma unroll
          for (int kx = 0; kx < 7; kx++)
            #pragma unroll
            for (int j = 0; j < 4; j++)
              acc[i][oc][j] += iv[2*j+kx]*wk[oc][kx];
      }
    }
  }

  #pragma unroll
  for (int i = 0; i < 5; i++){
    if (i < nrows){
      int y = r0 + i;
      #pragma unroll
      for (int j = 0; j < 4; j++){
        int col = 4*sp + j;
        if (col < 107){
          union { unsigned short s[4]; uint2 u; } pk;
          #pragma unroll
          for (int oc = 0; oc < 4; oc++){
            bf16 hv = __float2bfloat16(fmaxf(acc[i][oc][j], 0.f));
            pk.s[oc] = *(unsigned short*)&hv;
          }
          *(uint2*)(cbuf + (((size_t)(n*8+grp)*107 + y)*107 + col)*4) = pk.u;
        }
      }
    }
  }
}

// ---------- K1b: separable 7x7 s1 p1 max-pool. cbuf -> pool1
//   layout: [n][q=4][103][103][8ch]; grp g -> plane q=g>>1, half h=g&1.
__global__ __launch_bounds__(256) void k1b_pool1(
    const bf16* __restrict__ cbuf, bf16* __restrict__ pool1, int n_pool_base)
{
  __shared__ uint2 in4[19*107];   // conv rows p0-1..p0+17 (clamped)
  __shared__ uint2 ht4[19*103];   // after horizontal 7-max
  const int s = blockIdx.x, g = blockIdx.y, n = blockIdx.z;
  const int p0 = s*13;
  const int PR = (103 - p0 < 13) ? (103 - p0) : 13;
  const int NR = PR + 6;
  const uint2* src = (const uint2*)cbuf + (size_t)(n*8+g)*107*107;

  for (int t = threadIdx.x; t < NR*107; t += 256){
    int r = t/107, c = t - r*107;
    int gr = p0 - 1 + r;
    gr = (gr < 0) ? 0 : ((gr > 106) ? 106 : gr);
    in4[t] = src[gr*107 + c];
  }
  __syncthreads();
  for (int t = threadIdx.x; t < NR*103; t += 256){
    int r = t/103, c = t - r*103;
    U4 m; m.v = in4[r*107 + ((c > 0) ? c-1 : 0)];
    #pragma unroll
    for (int d = 0; d < 6; d++){
      U4 v; v.v = in4[r*107 + ((c+d < 106) ? c+d : 106)];
      umax4(m, v);
    }
    ht4[r*103 + c] = m.v;
  }
  __syncthreads();
  uint2* dst = (uint2*)pool1;
  const size_t plane = ((size_t)(n_pool_base + n)*4 + (g>>1))*10609;
  const int h = g & 1;
  for (int t = threadIdx.x; t < PR*103; t += 256){
    int pr = t/103, c = t - pr*103;
    U4 m; m.v = ht4[pr*103 + c];
    #pragma unroll
    for (int d = 1; d < 7; d++){
      U4 v; v.v = ht4[(pr+d)*103 + c];
      umax4(m, v);
    }
    dst[(plane + (size_t)(p0+pr)*103 + c)*2 + h] = m.v;
  }
}

// ---------- K2: conv2 MFMA implicit GEMM, parity-batched two-stage staging.
// pool1 [CHUNK][4][103][103][8] -> conv2out NHWC [CHUNK,49,49,64]
// Stage even rows e=[y0,y0+9] (gr=2e) once, compute ky=0,2,4,6 barrier-free;
// stage odd rows e=[y0,y0+8] (gr=2e+1), compute ky=1,3,5. 3 barriers total.
__global__ __launch_bounds__(256) void k2_conv2(
    const bf16* __restrict__ pool1,
    const bf16* __restrict__ w2b,     // [49][64][32]
    bf16* __restrict__ conv2out)
{
  __shared__ __align__(16) bf16 in_s[10*2*52*36];  // 74,880 B, 10 row-slots
  const int n = blockIdx.y, pb = blockIdx.x;       // pb 0..9
  const int wv = threadIdx.x >> 6, lane = threadIdx.x & 63;
  const int li = lane & 15, lg = lane >> 4;
  const int p0 = pb*256;
  const int y0 = p0/49;

  int pyv[4], pxv[4], pbase_[4]; bool pmask[4];
  #pragma unroll
  for (int t = 0; t < 4; t++){
    int p = p0 + wv*64 + t*16 + li;
    pmask[t] = (p <= 2400);
    int pc = min(p, 2400);
    int yy = pc/49, xx = pc - yy*49;
    pyv[t] = yy; pxv[t] = xx;
    pbase_[t] = ((yy - y0)*104 + xx)*36;   // slot stride 2*52*36 = 3744
  }
  floatx4 acc[4][4];
  #pragma unroll
  for (int a = 0; a < 4; a++)
    #pragma unroll
    for (int t = 0; t < 4; t++) acc[a][t] = (floatx4){0.f,0.f,0.f,0.f};

  const unsigned short* pbase = (const unsigned short*)pool1;

  // stage rows e = y0+ri, ri in [0,cnt), slot = ri, input row gr = 2e+par
  auto stage_rows = [&](int cnt, int par){
    for (int idx = threadIdx.x; idx < cnt*103*4; idx += 256){
      int q = idx & 3; int t2 = idx >> 2; int ri = t2/103; int c = t2 - ri*103;
      int gr = min(2*(y0+ri) + par, 102);
      *(int4*)&in_s[((ri*2 + (c&1))*52 + (c>>1))*36 + q*8] =
        *(const int4*)(pbase + (((size_t)n*4 + q)*10609 + (size_t)gr*103 + c)*8);
    }
  };

  // one ky phase: poff[t] = pbase_[t] + kyh*3744
  auto compute_phase = [&](int ky, int kyh){
    int poff[4];
    #pragma unroll
    for (int t = 0; t < 4; t++) poff[t] = pbase_[t] + kyh*3744;
    #pragma unroll
    for (int kx = 0; kx < 7; kx++){
      short8 a[4];
      const bf16* wp = w2b + (ky*7+kx)*64*32;
      #pragma unroll
      for (int ot = 0; ot < 4; ot++)
        a[ot] = *(const short8*)(wp + (ot*16 + li)*32 + lg*8);
      int koff = ((kx&1)*52 + (kx>>1))*36 + lg*8;
      #pragma unroll
      for (int t = 0; t < 4; t++){
        short8 bfr = *(const short8*)(&in_s[poff[t] + koff]);
        #pragma unroll
        for (int ot = 0; ot < 4; ot++)
          acc[ot][t] = __builtin_amdgcn_mfma_f32_16x16x32_bf16(a[ot], bfr, acc[ot][t], 0, 0, 0);
      }
    }
  };

  stage_rows(10, 0);            // even-parity rows for ky = 0,2,4,6
  __syncthreads();
  #pragma unroll 1
  for (int kyh = 0; kyh < 4; kyh++) compute_phase(2*kyh, kyh);
  __syncthreads();              // all waves done reading even rows
  stage_rows(9, 1);             // odd-parity rows for ky = 1,3,5
  __syncthreads();
  #pragma unroll 1
  for (int kyh = 0; kyh < 3; kyh++) compute_phase(2*kyh+1, kyh);

  #pragma unroll
  for (int t = 0; t < 4; t++){
    if (!pmask[t]) continue;
    bf16* dst = conv2out + (((long)n*49 + pyv[t])*49 + pxv[t])*64 + lg*4;
    #pragma unroll
    for (int ot = 0; ot < 4; ot++){
      union { bf16 h[4]; uint2 u; } pk;
      #pragma unroll
      for (int v = 0; v < 4; v++)
        pk.h[v] = __float2bfloat16(fmaxf(acc[ot][t][v], 0.f));
      *(uint2*)(dst + ot*16) = pk.u;
    }
  }
}

// ---------- K3a: horizontal 7-max: conv2out [CHUNK,49,49,64] -> tmp [CHUNK,49,45,64]
__global__ __launch_bounds__(256) void k3a_hmax(
    const bf16* __restrict__ cin, bf16* __restrict__ tmp)
{
  int idx = blockIdx.x*256 + threadIdx.x;
  int cg = idx & 7; int t = idx >> 3; int x = t % 45; int t2 = t / 45;
  int y = t2 % 49; int n = t2 / 49;
  const int4* row = (const int4*)(cin + ((long)(n*49 + y)*49)*64) + cg;
  U8 m; m.v = make_int4(0,0,0,0);
  int lo = max(x-1, 0), hi = min(x+5, 48);
  for (int cx = lo; cx <= hi; cx++){ U8 v; v.v = row[cx*8]; umax8(m, v); }
  *((int4*)(tmp + ((long)(n*49 + y)*45 + x)*64) + cg) = m.v;
}

// ---------- K3b: vertical 7-max: tmp -> pool2 [256,45,45,64] at n_base
__global__ __launch_bounds__(256) void k3b_vmax(
    const bf16* __restrict__ tmp, bf16* __restrict__ pout, int n_base)
{
  int idx = blockIdx.x*256 + threadIdx.x;
  int cg = idx & 7; int t = idx >> 3; int x = t % 45; int t2 = t / 45;
  int y = t2 % 45; int n = t2 / 45;
  U8 m; m.v = make_int4(0,0,0,0);
  int lo = max(y-1, 0), hi = min(y+5, 48);
  for (int cy = lo; cy <= hi; cy++){
    U8 v; v.v = *((const int4*)(tmp + ((long)(n*49 + cy)*45 + x)*64) + cg);
    umax8(m, v);
  }
  *((int4*)(pout + (long)(n_base+n)*129600 + (y*45 + x)*64) + cg) = m.v;
}

// ---------- K4: conv3 MFMA implicit GEMM, circular row staging.
// pool2 NHWC -> conv3out NHWC [256,20,20,64]
__global__ __launch_bounds__(256) void k4_conv3(
    const bf16* __restrict__ pool2,
    const bf16* __restrict__ w3b,     // [ky][kc][kx][64][32]
    bf16* __restrict__ conv3out)
{
  __shared__ __align__(16) bf16 in_s[10*2*24*40];  // 38400 B, 10 row-slots
  const int n = blockIdx.y, pb = blockIdx.x;       // pb 0..1
  const int wv = threadIdx.x >> 6, lane = threadIdx.x & 63;
  const int li = lane & 15, lg = lane >> 4;
  const int y0 = pb*10;

  int pyv[4], pxv[4]; bool pmask[4];
  #pragma unroll
  for (int t = 0; t < 4; t++){
    int pl = wv*64 + t*16 + li;
    pmask[t] = (pl < 200);
    int p = pb*200 + min(pl, 199);
    int yy = p/20, xx = p - yy*20;
    pyv[t] = yy; pxv[t] = xx;
  }
  floatx4 acc[4][4];
  #pragma unroll
  for (int a = 0; a < 4; a++)
    #pragma unroll
    for (int t = 0; t < 4; t++) acc[a][t] = (floatx4){0.f,0.f,0.f,0.f};

  auto stage_rows = [&](int e0, int cnt, int par, int kc){
    for (int idx = threadIdx.x; idx < cnt*45*4; idx += 256){
      int q = idx & 3; int t2 = idx >> 2; int ri = t2/45; int c = t2 - ri*45;
      int e = e0 + ri;
      int slot = e % 10;
      int gr = 2*e + par;
      *(int4*)&in_s[((slot*2 + (c&1))*24 + (c>>1))*40 + q*8] =
        *(const int4*)(pool2 + (((long)n*45 + gr)*45 + c)*64 + kc*32 + q*8);
    }
  };

  const int kyseq[7] = {0,2,4,6,1,3,5};
  #pragma unroll 1
  for (int kc = 0; kc < 2; kc++){
    #pragma unroll 1
    for (int ks = 0; ks < 7; ks++){
      int ky = kyseq[ks];
      int kyh = ky >> 1, par = ky & 1;
      __syncthreads();
      if (ks == 0 || ks == 4) stage_rows(y0 + kyh, 10, par, kc);
      else                    stage_rows(y0 + 9 + kyh, 1, par, kc);
      __syncthreads();
      int poff[4];
      #pragma unroll
      for (int t = 0; t < 4; t++){
        int e = pyv[t] + kyh;
        int slot = e % 10;
        poff[t] = (slot*2*24 + pxv[t])*40;
      }
      #pragma unroll
      for (int kx = 0; kx < 7; kx++){
        short8 a[4];
        const bf16* wp = w3b + ((ky*2+kc)*7 + kx)*64*32;
        #pragma unroll
        for (int ot = 0; ot < 4; ot++)
          a[ot] = *(const short8*)(wp + (ot*16 + li)*32 + lg*8);
        int koff = ((kx&1)*24 + (kx>>1))*40 + lg*8;
        #pragma unroll
        for (int t = 0; t < 4; t++){
          short8 bfr = *(const short8*)(&in_s[poff[t] + koff]);
          #pragma unroll
          for (int ot = 0; ot < 4; ot++)
            acc[ot][t] = __builtin_amdgcn_mfma_f32_16x16x32_bf16(a[ot], bfr, acc[ot][t], 0, 0, 0);
        }
      }
    }
  }
  #pragma unroll
  for (int t = 0; t < 4; t++){
    if (!pmask[t]) continue;
    bf16* dst = conv3out + (((long)n*20 + pyv[t])*20 + pxv[t])*64 + lg*4;
    #pragma unroll
    for (int ot = 0; ot < 4; ot++){
      union { bf16 h[4]; uint2 u; } pk;
      #pragma unroll
      for (int v = 0; v < 4; v++)
        pk.h[v] = __float2bfloat16(fmaxf(acc[ot][t][v], 0.f));
      *(uint2*)(dst + ot*16) = pk.u;
    }
  }
}

// ---------- K5: in-LDS separable pool3. conv3out [256,20,20,64] -> feat [256,16384]
__global__ __launch_bounds__(256) void k5_pool3(
    const bf16* __restrict__ cin, bf16* __restrict__ feat)
{
  __shared__ int4 in_p[3200];
  __shared__ int4 ht[2560];
  const int n = blockIdx.x;
  const int4* src = (const int4*)(cin + (long)n*25600);
  for (int i = threadIdx.x; i < 3200; i += 256) in_p[i] = src[i];
  __syncthreads();
  for (int i = threadIdx.x; i < 2560; i += 256){
    int cg = i & 7; int t = i >> 3; int x = t & 15; int y = t >> 4;
    U8 m; m.v = make_int4(0,0,0,0);
    int lo = max(x-1, 0), hi = min(x+5, 19);
    for (int cx = lo; cx <= hi; cx++){ U8 v; v.v = in_p[(y*20+cx)*8 + cg]; umax8(m, v); }
    ht[(y*16+x)*8 + cg] = m.v;
  }
  __syncthreads();
  unsigned short* dst = (unsigned short*)(feat + (long)n*16384);
  for (int i = threadIdx.x; i < 2048; i += 256){
    int px = i & 15; int py = (i >> 4) & 15; int cg = i >> 8;
    U8 m; m.v = make_int4(0,0,0,0);
    int lo = max(py-1, 0), hi = min(py+5, 19);
    for (int cy = lo; cy <= hi; cy++){ U8 v; v.v = ht[(cy*16+px)*8 + cg]; umax8(m, v); }
    #pragma unroll
    for (int j = 0; j < 8; j++)
      dst[(cg*8+j)*256 + py*16 + px] = m.s[j];
  }
}

// ---------- K6a: init x[272,512]
__global__ __launch_bounds__(256) void k6_init_x(
    const float* __restrict__ cls, const float* __restrict__ pos,
    const float* __restrict__ flat_b, float* __restrict__ x)
{
  int idx = blockIdx.x*256 + threadIdx.x;
  int d = idx & 511; int row = idx >> 9;
  int tt = row % 17;
  x[idx] = (tt == 0) ? (cls[d] + pos[d]) : (flat_b[d] + pos[tt*512 + d]);
}

// ---------- K6b: feat @ flat_w via MFMA (hi+lo bf16 W). atomicAdd into x.
__global__ __launch_bounds__(256) void k6_flat_mfma(
    const bf16* __restrict__ feat, const bf16* __restrict__ Whi,
    const bf16* __restrict__ Wlo, float* __restrict__ x)
{
  const int wv = threadIdx.x >> 6, lane = threadIdx.x & 63;
  const int li = lane & 15, lg = lane >> 4;
  const int m0 = blockIdx.x*64;             // block's 64 rows
  const int nb = blockIdx.y*64 + wv*16;     // wave's 16 cols
  const int kb = blockIdx.z*512;            // k-range (16 k-steps)
  floatx4 acc[4];
  #pragma unroll
  for (int t = 0; t < 4; t++) acc[t] = (floatx4){0.f,0.f,0.f,0.f};

  const bf16* abase = feat + (size_t)(m0+li)*16384 + kb + lg*8;
  for (int k0 = 0; k0 < 512; k0 += 32){
    short8 a0 = *(const short8*)(abase + k0);
    short8 a1 = *(const short8*)(abase + (size_t)16*16384 + k0);
    short8 a2 = *(const short8*)(abase + (size_t)32*16384 + k0);
    short8 a3 = *(const short8*)(abase + (size_t)48*16384 + k0);
    size_t wo = ((size_t)((kb + k0) >> 3) + lg)*512 + nb + li;  // in 8-elt units
    short8 bh = *(const short8*)(Whi + wo*8);
    short8 bl = *(const short8*)(Wlo + wo*8);
    acc[0] = __builtin_amdgcn_mfma_f32_16x16x32_bf16(a0, bh, acc[0], 0, 0, 0);
    acc[1] = __builtin_amdgcn_mfma_f32_16x16x32_bf16(a1, bh, acc[1], 0, 0, 0);
    acc[2] = __builtin_amdgcn_mfma_f32_16x16x32_bf16(a2, bh, acc[2], 0, 0, 0);
    acc[3] = __builtin_amdgcn_mfma_f32_16x16x32_bf16(a3, bh, acc[3], 0, 0, 0);
    acc[0] = __builtin_amdgcn_mfma_f32_16x16x32_bf16(a0, bl, acc[0], 0, 0, 0);
    acc[1] = __builtin_amdgcn_mfma_f32_16x16x32_bf16(a1, bl, acc[1], 0, 0, 0);
    acc[2] = __builtin_amdgcn_mfma_f32_16x16x32_bf16(a2, bl, acc[2], 0, 0, 0);
    acc[3] = __builtin_amdgcn_mfma_f32_16x16x32_bf16(a3, bl, acc[3], 0, 0, 0);
  }
  int col = nb + li;
  #pragma unroll
  for (int t = 0; t < 4; t++){
    #pragma unroll
    for (int v = 0; v < 4; v++){
      int m = m0 + t*16 + lg*4 + v;
      int row = (m>>4)*17 + 1 + (m&15);
      atomicAdd(&x[row*512 + col], acc[t][v]);
    }
  }
}

// ---------- LayerNorm over 512, fp32 out (head path)
__global__ __launch_bounds__(256) void ln_kernel(
    const float* __restrict__ in, const float* __restrict__ g,
    const float* __restrict__ b, float* __restrict__ out,
    int in_stride, int out_stride)
{
  int row = blockIdx.x;
  const float* p = in + (long)row*in_stride;
  float v0 = p[threadIdx.x], v1 = p[threadIdx.x+256];
  __shared__ float red[4]; __shared__ float stat;
  float s = v0+v1;
  #pragma unroll
  for (int o = 32; o >= 1; o >>= 1) s += __shfl_down(s, o);
  int lane = threadIdx.x & 63, wv = threadIdx.x >> 6;
  if (lane == 0) red[wv] = s;
  __syncthreads();
  if (threadIdx.x == 0) stat = (red[0]+red[1]+red[2]+red[3])*(1.0f/512.0f);
  __syncthreads();
  float m = stat;
  float d0 = v0-m, d1 = v1-m;
  float q = d0*d0 + d1*d1;
  #pragma unroll
  for (int o = 32; o >= 1; o >>= 1) q += __shfl_down(q, o);
  __syncthreads();
  if (lane == 0) red[wv] = q;
  __syncthreads();
  if (threadIdx.x == 0) stat = rsqrtf((red[0]+red[1]+red[2]+red[3])*(1.0f/512.0f) + 1e-5f);
  __syncthreads();
  float rstd = stat;
  out[(long)row*out_stride + threadIdx.x]     = d0*rstd*g[threadIdx.x]     + b[threadIdx.x];
  out[(long)row*out_stride + threadIdx.x+256] = d1*rstd*g[threadIdx.x+256] + b[threadIdx.x+256];
}

// ---------- LayerNorm over 512, bf16 out (MFMA tail activations)
__global__ __launch_bounds__(256) void ln_bf16(
    const float* __restrict__ in, const float* __restrict__ g,
    const float* __restrict__ b, bf16* __restrict__ out)
{
  int row = blockIdx.x;
  const float* p = in + (long)row*512;
  float v0 = p[threadIdx.x], v1 = p[threadIdx.x+256];
  __shared__ float red[4]; __shared__ float stat;
  float s = v0+v1;
  #pragma unroll
  for (int o = 32; o >= 1; o >>= 1) s += __shfl_down(s, o);
  int lane = threadIdx.x & 63, wv = threadIdx.x >> 6;
  if (lane == 0) red[wv] = s;
  __syncthreads();
  if (threadIdx.x == 0) stat = (red[0]+red[1]+red[2]+red[3])*(1.0f/512.0f);
  __syncthreads();
  float m = stat;
  float d0 = v0-m, d1 = v1-m;
  float q = d0*d0 + d1*d1;
  #pragma unroll
  for (int o = 32; o >= 1; o >>= 1) q += __shfl_down(q, o);
  __syncthreads();
  if (lane == 0) red[wv] = q;
  __syncthreads();
  if (threadIdx.x == 0) stat = rsqrtf((red[0]+red[1]+red[2]+red[3])*(1.0f/512.0f) + 1e-5f);
  __syncthreads();
  float rstd = stat;
  out[(long)row*512 + threadIdx.x]     = __float2bfloat16(d0*rstd*g[threadIdx.x]     + b[threadIdx.x]);
  out[(long)row*512 + threadIdx.x+256] = __float2bfloat16(d1*rstd*g[threadIdx.x+256] + b[threadIdx.x+256]);
}

// ---------- MFMA tail GEMM: out = [res +] act(A@W + bias)
template<int NT>
__global__ __launch_bounds__(256) void tail_gemm(
    const bf16* __restrict__ A, const bf16* __restrict__ Wp,
    const float* __restrict__ bias, const float* res,
    float* outf, bf16* outb, int N, int K, int dogelu)
{
  const int wv = threadIdx.x >> 6, lane = threadIdx.x & 63;
  const int li = lane & 15, lg = lane >> 4;
  const int m0 = blockIdx.x * 16;
  const int nb = blockIdx.y * (64*NT) + wv * (16*NT);
  floatx4 acc[NT];
  #pragma unroll
  for (int t = 0; t < NT; t++) acc[t] = (floatx4){0.f,0.f,0.f,0.f};
  const bf16* arow = A + (size_t)(m0+li)*K + lg*8;
  for (int k0 = 0; k0 < K; k0 += 32){
    short8 a = *(const short8*)(arow + k0);
    const bf16* wrow = Wp + ((size_t)((k0>>3) + lg) * N + nb + li) * 8;
    #pragma unroll
    for (int t = 0; t < NT; t++){
      short8 bfr = *(const short8*)(wrow + t*128);
      acc[t] = __builtin_amdgcn_mfma_f32_16x16x32_bf16(a, bfr, acc[t], 0, 0, 0);
    }
  }
  #pragma unroll
  for (int t = 0; t < NT; t++){
    int col = nb + t*16 + li;
    #pragma unroll
    for (int v = 0; v < 4; v++){
      int row = m0 + lg*4 + v;
      float val = acc[t][v];
      if (bias) val += bias[col];
      if (dogelu) val = 0.5f*val*(1.0f + erff(val*0.70710678118654752f));
      if (res) val += res[(size_t)row*N + col];
      if (outf) outf[(size_t)row*N + col] = val;
      else      outb[(size_t)row*N + col] = __float2bfloat16(val);
    }
  }
}

// ---------- Generic small GEMM (head only): out = act(A@W + bias)
__global__ __launch_bounds__(256) void gemm_rows(
    const float* __restrict__ A, const float* __restrict__ W,
    const float* __restrict__ bias, const float* __restrict__ res,
    float* __restrict__ out, int M, int N, int K, int dogelu)
{
  __shared__ float A_s[16][33];
  __shared__ __align__(16) float W_s[32][68];
  const int m0 = blockIdx.x*16, n0 = blockIdx.y*64;
  const int r = threadIdx.x>>4, c0 = (threadIdx.x&15)*4;
  float acc[4] = {};
  for (int k0 = 0; k0 < K; k0 += 32){
    __syncthreads();
    for (int i = 0; i < 2; i++){ int id = threadIdx.x + i*256; int rr = id>>5, kk = id&31;
      A_s[rr][kk] = (m0+rr < M) ? A[(long)(m0+rr)*K + k0+kk] : 0.f; }
    for (int i = 0; i < 8; i++){ int id = threadIdx.x + i*256; int kk = id>>6, c = id&63;
      W_s[kk][c] = (n0+c < N) ? W[(long)(k0+kk)*N + n0+c] : 0.f; }
    __syncthreads();
    #pragma unroll
    for (int kk = 0; kk < 32; kk++){
      float a = A_s[r][kk];
      float4 w4 = *(const float4*)&W_s[kk][c0];
      acc[0]+=a*w4.x; acc[1]+=a*w4.y; acc[2]+=a*w4.z; acc[3]+=a*w4.w;
    }
  }
  if (m0+r < M){
    int row = m0+r;
    for (int j = 0; j < 4; j++){
      int c = n0+c0+j;
      if (c < N){
        float v = acc[j];
        if (bias) v += bias[c];
        if (dogelu) v = 0.5f*v*(1.0f + erff(v*0.70710678118654752f));
        if (res) v += res[(long)row*N + c];
        out[(long)row*N + c] = v;
      }
    }
  }
}

// ---------- Attention: one block per (b,h). N=17, DH=64. Writes bf16 O.
__global__ __launch_bounds__(128) void attn_kernel(
    const float* __restrict__ qkv, bf16* __restrict__ obuf)
{
  const int b = blockIdx.x >> 3, h = blockIdx.x & 7;
  __shared__ float q_s[17][65], k_s[17][65], v_s[17][65], s_s[17][18];
  for (int idx = threadIdx.x; idx < 17*64; idx += 128){
    int i = idx>>6, d = idx&63;
    const float* base = qkv + (long)(b*17+i)*1536 + h*64 + d;
    q_s[i][d] = base[0]; k_s[i][d] = base[512]; v_s[i][d] = base[1024];
  }
  __syncthreads();
  for (int idx = threadIdx.x; idx < 289; idx += 128){
    int i = idx/17, j = idx - i*17;
    float s = 0.f;
    for (int d = 0; d < 64; d++) s += q_s[i][d]*k_s[j][d];
    s_s[i][j] = s*0.125f;
  }
  __syncthreads();
  if (threadIdx.x < 17){
    int i = threadIdx.x;
    float m = -1e30f;
    for (int j = 0; j < 17; j++) m = fmaxf(m, s_s[i][j]);
    float sum = 0.f;
    for (int j = 0; j < 17; j++){ float e = expf(s_s[i][j]-m); s_s[i][j] = e; sum += e; }
    float inv = 1.0f/sum;
    for (int j = 0; j < 17; j++) s_s[i][j] *= inv;
  }
  __syncthreads();
  for (int idx = threadIdx.x; idx < 17*64; idx += 128){
    int i = idx>>6, d = idx&63;
    float o = 0.f;
    for (int j = 0; j < 17; j++) o += s_s[i][j]*v_s[j][d];
    obuf[(long)(b*17+i)*512 + h*64 + d] = __float2bfloat16(o);
  }
}

// ============================================================================
extern "C" void kernel_launch(void* const* d_in, const int* in_sizes, int n_in,
                              void* d_out, int out_size, void* d_ws, size_t ws_size,
                              hipStream_t stream) {
  const float* img      = (const float*)d_in[0];
  const float* conv1_w  = (const float*)d_in[1];
  const float* conv2_w  = (const float*)d_in[2];
  const float* conv3_w  = (const float*)d_in[3];
  const float* flat_w   = (const float*)d_in[4];
  const float* flat_b   = (const float*)d_in[5];
  const float* cls_tok  = (const float*)d_in[6];
  const float* pos_emb  = (const float*)d_in[7];
  const float* ln1_g    = (const float*)d_in[8];
  const float* ln1_b    = (const float*)d_in[9];
  const float* qkv_w    = (const float*)d_in[10];
  const float* out_w    = (const float*)d_in[11];
  const float* out_b    = (const float*)d_in[12];
  const float* ln2_g    = (const float*)d_in[13];
  const float* ln2_b    = (const float*)d_in[14];
  const float* ff1_w    = (const float*)d_in[15];
  const float* ff1_b    = (const float*)d_in[16];
  const float* ff2_w    = (const float*)d_in[17];
  const float* ff2_b    = (const float*)d_in[18];
  const float* hln_g    = (const float*)d_in[19];
  const float* hln_b    = (const float*)d_in[20];
  const float* head_w   = (const float*)d_in[21];
  const float* head_b   = (const float*)d_in[22];

  char* ws = (char*)d_ws;
  size_t off = 0;
  auto alloc = [&](size_t bytes) -> void* {
    void* p = ws + off; off += (bytes + 255) & ~(size_t)255; return p;
  };
  bf16* pool1    = (bf16*)alloc((size_t)CHUNK*8*103*103*4*2); // 43.5 MB (chunk, [n][4][103][103][8])
  bf16* conv2out = (bf16*)alloc((size_t)CHUNK*49*49*64*2);    // 19.7 MB (chunk, NHWC)
  bf16* pool2    = (bf16*)alloc((size_t)256*45*45*64*2);      // 66.4 MB (full, NHWC)
  bf16* feat     = (bf16*)alloc((size_t)256*16384*2);         //  8.4 MB
  bf16* w2b      = (bf16*)alloc((size_t)49*64*32*2);
  bf16* w3b      = (bf16*)alloc((size_t)49*2*64*32*2);
  float* x       = (float*)alloc((size_t)139264*4);           // 272x512 fp32
  bf16*  hb      = (bf16*)alloc((size_t)139264*2);            // 272x512 bf16 (LN out)
  float* qkvb    = (float*)alloc((size_t)417792*4);           // 272x1536 fp32
  bf16*  obufb   = (bf16*)alloc((size_t)139264*2);            // 272x512 bf16
  bf16*  ffbufb  = (bf16*)alloc((size_t)557056*2);            // 272x2048 bf16
  float* hcls    = (float*)alloc((size_t)8192*4);             // 16x512
  // pool1 region reuse (dead at the noted points):
  bf16* tmp3     = pool1;            // k3 horizontal tmp (within chunk loop)
  bf16* conv3out = pool1;            // k4 output (after chunk loop)
  // packed transformer weights alias pool1 AFTER k5 (pool1 fully dead):
  bf16* qkvp  = pool1;               //  9.44 MB
  bf16* outwp = qkvp  + (size_t)6*512*1536;   // 3.15 MB
  bf16* ff1p  = outwp + (size_t)6*512*512;    // 12.58 MB
  bf16* ff2p  = ff1p  + (size_t)6*512*2048;   // 12.58 MB  (total 37.75 <= 43.5)
  // flat_w hi/lo packs alias conv2out (hi) and pool2 (lo) — dead after k5.
  bf16* fwhi  = conv2out;
  bf16* fwlo  = pool2;

  // conv1 intermediate (k1a -> k1b), sized adaptively against ws_size.
  const size_t cb_per_n = (size_t)8*107*107*4*2;   // 733,136 B per patch
  int SUB; bf16* cbuf;
  if (ws_size >= off + 64*cb_per_n)      { SUB = 64; cbuf = (bf16*)alloc(64*cb_per_n); }
  else if (ws_size >= off + 32*cb_per_n) { SUB = 32; cbuf = (bf16*)alloc(32*cb_per_n); }
  else { SUB = 16; cbuf = conv2out; }  // dead-region fallback (see round 7)
  (void)in_sizes; (void)n_in; (void)out_size;

  prep_w2<<<392, 256, 0, stream>>>(conv2_w, w2b);
  prep_w3<<<784, 256, 0, stream>>>(conv3_w, w3b);

  for (int cb = 0; cb < 256; cb += CHUNK){
    for (int sb = 0; sb < CHUNK; sb += SUB){
      k1a_conv1<<<dim3(22, SUB), 256, 0, stream>>>(img, conv1_w, cbuf, cb + sb);
      k1b_pool1<<<dim3(8, 8, SUB), 256, 0, stream>>>(cbuf, pool1, sb);
    }
    k2_conv2     <<<dim3(10,CHUNK), 256, 0, stream>>>(pool1, w2b, conv2out);
    k3a_hmax     <<<(CHUNK*49*45*8)/256, 256, 0, stream>>>(conv2out, tmp3);
    k3b_vmax     <<<(CHUNK*45*45*8)/256, 256, 0, stream>>>(tmp3, pool2, cb);
  }
  k4_conv3<<<dim3(2,256), 256, 0, stream>>>(pool2, w3b, conv3out);
  k5_pool3<<<256, 256, 0, stream>>>(conv3out, feat);

  // packs into dead regions (pool1 / conv2out / pool2 all dead after k5)
  prep_pack_flat<<<4096, 256, 0, stream>>>(flat_w, fwhi, fwlo);
  prep_pack<<<(6*64*1536+255)/256, 256, 0, stream>>>(qkv_w, qkvp, 64, 1536, 6*64*1536);
  prep_pack<<<(6*64*512 +255)/256, 256, 0, stream>>>(out_w, outwp, 64, 512,  6*64*512);
  prep_pack<<<(6*64*2048+255)/256, 256, 0, stream>>>(ff1_w, ff1p, 64, 2048, 6*64*2048);
  prep_pack<<<(6*256*512+255)/256, 256, 0, stream>>>(ff2_w, ff2p, 256, 512, 6*256*512);

  k6_init_x    <<<544,          256, 0, stream>>>(cls_tok, pos_emb, flat_b, x);
  k6_flat_mfma <<<dim3(4,8,32), 256, 0, stream>>>(feat, fwhi, fwlo, x);

  for (int l = 0; l < 6; l++){
    ln_bf16<<<272, 256, 0, stream>>>(x, ln1_g + l*512, ln1_b + l*512, hb);
    tail_gemm<4><<<dim3(17,6), 256, 0, stream>>>(hb, qkvp + (size_t)l*786432,
                                                 nullptr, nullptr, qkvb, nullptr, 1536, 512, 0);
    attn_kernel<<<128, 128, 0, stream>>>(qkvb, obufb);
    tail_gemm<1><<<dim3(17,8), 256, 0, stream>>>(obufb, outwp + (size_t)l*262144,
                                                 out_b + l*512, x, x, nullptr, 512, 512, 0);
    ln_bf16<<<272, 256, 0, stream>>>(x, ln2_g + l*512, ln2_b + l*512, hb);
    tail_gemm<4><<<dim3(17,8), 256, 0, stream>>>(hb, ff1p + (size_t)l*1048576,
                                                 ff1_b + l*2048, nullptr, nullptr, ffbufb, 2048, 512, 1);
    tail_gemm<1><<<dim3(17,8), 256, 0, stream>>>(ffbufb, ff2p + (size_t)l*1048576,
                                                 ff2_b + l*512, x, x, nullptr, 512, 2048, 0);
  }

  ln_kernel<<<16, 256, 0, stream>>>(x, hln_g, hln_b, hcls, 17*512, 512);
  gemm_rows<<<dim3(1,16), 256, 0, stream>>>(hcls, head_w, head_b, nullptr,
                                            (float*)d_out, 16, 1000, 512, 0);
}